// Round 18
// baseline (312.094 us; speedup 1.0000x reference)
//
#include <hip/hip_runtime.h>
#include <math.h>

// ---------------------------------------------------------------------------
// Upnet_v3 pipeline, round 18:
//  - conv3x3: A-operand bypasses LDS (direct global->fragment-register loads,
//    1-step ping-pong prefetch; layout == MFMA fragment). B stays LDS-staged.
//    LDS traffic/step 72->48KB, LDS 48->32KB. Conv was LDS-BW-bound.
//  - everything else unchanged from round 17 (281.8us baseline).
// ---------------------------------------------------------------------------

namespace {
constexpr int kS   = 6;
constexpr int kHP  = 37;
constexpr int kWP  = 37;
constexpr int kN   = 1369;      // HP*WP
constexpr int kCIN = 1536;
constexpr int kCO  = 256;
constexpr int kDS  = 16;
constexpr int kDI  = 512;
constexpr int kHID = 384;
constexpr int kOH  = 148;
constexpr int kOW  = 148;
constexpr int kNP  = kOH * kOW; // 21904
constexpr int kXPW = 545;       // 2*DS + DI + 1
constexpr long kXPS = 746112;   // padded kN*kXPW per dir
constexpr int kNC  = 48;        // scan chunks
constexpr int kCH  = 29;        // chunk length (48*29 = 1392 >= 1369)

// ---- workspace ledger (f32 units, total <= 13,911,040 = 55.6 MB) ----------
constexpr long OFF_PF      = 0;
constexpr long OFF_Z2B     = 0;
constexpr long OFF_YGB     = 0;
constexpr long OFF_UPB     = 0;
constexpr long OFF_SCANP   = 700928;    // chunkP 48*16384 (hin in-place)
constexpr long OFF_SCANH   = 1487360;   // chunkH (ends 2,273,792)
constexpr long OFF_COLPART = 2102784;   // dead before scans
constexpr long OFF_WFIN    = 2119680;
constexpr long OFF_ATTNP   = 2119696;
constexpr long OFF_PROJWB  = 2200000;
constexpr long OFF_INWT    = 2200000;
constexpr long OFF_FUSEDB  = 2462144;
constexpr long OFF_ZG      = 2820624;
constexpr long OFF_Z       = 5760000;
constexpr long OFF_WCONVB  = 6000000;
constexpr long OFF_FEATB   = 7161856;
constexpr long OFF_XP      = 7161856;
constexpr long OFF_DELTA   = 8654080;
constexpr long OFF_OUTWT   = 10055936;
constexpr long OFF_GT      = 11457792;
constexpr long OFF_XPWT    = 11457792;
constexpr long OFF_FUSED2  = 12158720;
constexpr long OFF_CAT     = 12859648;
constexpr long OFF_MERGEWT = 13210112;
constexpr long OFF_MERGED  = 13560576;
} // namespace

typedef __attribute__((ext_vector_type(8))) short bf16x8;
typedef __attribute__((ext_vector_type(4))) float f32x4;

__device__ __forceinline__ short f2bf(float x) {
    unsigned u = __builtin_bit_cast(unsigned, x);
    unsigned r = u + 0x7fffu + ((u >> 16) & 1u);
    return (short)(r >> 16);
}

__device__ __forceinline__ bf16x8 cvt8(float4 x, float4 y) {
    union { short s[8]; bf16x8 v; } u;
    u.s[0] = f2bf(x.x); u.s[1] = f2bf(x.y); u.s[2] = f2bf(x.z); u.s[3] = f2bf(x.w);
    u.s[4] = f2bf(y.x); u.s[5] = f2bf(y.y); u.s[6] = f2bf(y.z); u.s[7] = f2bf(y.w);
    return u.v;
}

// cast 8 consecutive f32 -> bf16x8 per thread
__global__ __launch_bounds__(256)
void cast8_kernel(const float* __restrict__ in, short* __restrict__ out, long n8)
{
    long i = (long)blockIdx.x * 256 + threadIdx.x;
    if (i >= n8) return;
    const float4* p = (const float4*)(in + i * 8);
    *(bf16x8*)(out + i * 8) = cvt8(p[0], p[1]);
}

// tiled transpose+cast: w (K x N f32) -> wt (N x K bf16)
__global__ __launch_bounds__(256)
void transpose_cast_kernel(const float* __restrict__ w0, const float* __restrict__ w1,
                           short* __restrict__ wt, int K, int N)
{
    __shared__ float tile[32][33];
    int dir = blockIdx.z;
    const float* w = dir ? w1 : w0;
    short* o = wt + (long)dir * K * N;
    int k0 = blockIdx.x * 32, n0 = blockIdx.y * 32;
    int tx = threadIdx.x & 31, ty = threadIdx.x >> 5; // 32 x 8
    #pragma unroll
    for (int r = 0; r < 32; r += 8) {
        int k = k0 + ty + r, n = n0 + tx;
        tile[ty + r][tx] = (k < K && n < N) ? w[(long)k * N + n] : 0.f;
    }
    __syncthreads();
    #pragma unroll
    for (int r = 0; r < 32; r += 8) {
        int n = n0 + ty + r, k = k0 + tx;
        if (n < N && k < K) o[(long)n * K + k] = f2bf(tile[tx][ty + r]);
    }
}

// ---------------------------------------------------------------------------
// generic bf16 MFMA GEMM, NT form, LDS dbuf, K-step 64 (unchanged)
// ---------------------------------------------------------------------------
__global__ __launch_bounds__(256)
void mfma_nt(const short* __restrict__ A, long sA,
             const short* __restrict__ B, long sB,
             float* __restrict__ C, long sC,
             int M, int N, int K)
{
    __shared__ short smem[2][8192];  // per buf bytes: A [0,8192), B [8192,16384)
    const int bz = blockIdx.z;
    const short* Ab = A + (long)bz * sA;
    const short* Bb = B + (long)bz * sB;
    float* Cb = C + (long)bz * sC;
    const int t = threadIdx.x, w = t >> 6, l = t & 63;
    const int lr = l & 15, sg = l >> 4;
    const int m0 = blockIdx.x * 64, n0 = blockIdx.y * 64;

    const int srow = t >> 3, qa = t & 7;   // 32 base rows x 8 k-segs
    long gA[2]; int woffA[2];
    #pragma unroll
    for (int j = 0; j < 2; ++j) {
        int ar = srow + j * 32;
        int am = m0 + ar; if (am >= M) am = M - 1;
        gA[j] = (long)am * K + qa * 8;
        woffA[j] = ar * 128 + ((qa ^ (ar & 7)) << 4);
    }
    long gB[2]; int woffB[2];
    #pragma unroll
    for (int j = 0; j < 2; ++j) {
        int br = srow + j * 32;
        int bn = n0 + br; if (bn >= N) bn = N - 1;
        gB[j] = (long)bn * K + qa * 8;
        woffB[j] = 8192 + br * 128 + ((qa ^ (br & 7)) << 4);
    }

    int aoff[2][2], boff[2][2];
    #pragma unroll
    for (int mi = 0; mi < 2; ++mi) {
        int r = (w >> 1) * 32 + mi * 16 + lr;
        #pragma unroll
        for (int kk = 0; kk < 2; ++kk)
            aoff[mi][kk] = r * 128 + (((kk * 4 + sg) ^ (r & 7)) << 4);
    }
    #pragma unroll
    for (int ni = 0; ni < 2; ++ni) {
        int r = (w & 1) * 32 + ni * 16 + lr;
        #pragma unroll
        for (int kk = 0; kk < 2; ++kk)
            boff[ni][kk] = 8192 + r * 128 + (((kk * 4 + sg) ^ (r & 7)) << 4);
    }

    f32x4 acc[2][2] = {};
    const int NT = K >> 6;
    {
        char* lb = (char*)&smem[0][0];
        #pragma unroll
        for (int j = 0; j < 2; ++j)
            *(bf16x8*)(lb + woffA[j]) = *(const bf16x8*)(Ab + gA[j]);
        #pragma unroll
        for (int j = 0; j < 2; ++j)
            *(bf16x8*)(lb + woffB[j]) = *(const bf16x8*)(Bb + gB[j]);
    }
    __syncthreads();
    for (int tt = 0; tt < NT; ++tt) {
        bf16x8 nsa[2], nsb[2];
        if (tt + 1 < NT) {
            long o = (long)(tt + 1) * 64;
            #pragma unroll
            for (int j = 0; j < 2; ++j) nsa[j] = *(const bf16x8*)(Ab + gA[j] + o);
            #pragma unroll
            for (int j = 0; j < 2; ++j) nsb[j] = *(const bf16x8*)(Bb + gB[j] + o);
        }
        char* lb = (char*)&smem[tt & 1][0];
        #pragma unroll
        for (int kk = 0; kk < 2; ++kk) {
            bf16x8 a[2], b[2];
            #pragma unroll
            for (int mi = 0; mi < 2; ++mi) a[mi] = *(const bf16x8*)(lb + aoff[mi][kk]);
            #pragma unroll
            for (int ni = 0; ni < 2; ++ni) b[ni] = *(const bf16x8*)(lb + boff[ni][kk]);
            #pragma unroll
            for (int mi = 0; mi < 2; ++mi)
                #pragma unroll
                for (int ni = 0; ni < 2; ++ni)
                    acc[mi][ni] = __builtin_amdgcn_mfma_f32_16x16x32_bf16(a[mi], b[ni], acc[mi][ni], 0, 0, 0);
        }
        if (tt + 1 < NT) {
            char* nb = (char*)&smem[(tt + 1) & 1][0];
            #pragma unroll
            for (int j = 0; j < 2; ++j) *(bf16x8*)(nb + woffA[j]) = nsa[j];
            #pragma unroll
            for (int j = 0; j < 2; ++j) *(bf16x8*)(nb + woffB[j]) = nsb[j];
        }
        __syncthreads();
    }
    const int q = l >> 4;
    const int wm0 = m0 + (w >> 1) * 32, wn0 = n0 + (w & 1) * 32;
    #pragma unroll
    for (int mi = 0; mi < 2; ++mi)
        #pragma unroll
        for (int ni = 0; ni < 2; ++ni)
            #pragma unroll
            for (int r = 0; r < 4; ++r) {
                int m = wm0 + mi * 16 + q * 4 + r;
                int n = wn0 + ni * 16 + lr;
                if (m < M && n < N)
                    Cb[(long)m * N + n] = acc[mi][ni][r];
            }
}

// ---------------------------------------------------------------------------
// proj MFMA: bf16 64x64 tile, K-step 64, s-grouped XCD swizzle (unchanged)
// ---------------------------------------------------------------------------
__global__ __launch_bounds__(256)
void proj_mfma_kernel(const short* __restrict__ Ab16, const short* __restrict__ Bb16,
                      float* __restrict__ pf)
{
    __shared__ short smem[2][8192];
    const int bid = blockIdx.x;                     // 0..527
    const int slot = (bid & 7) * 66 + (bid >> 3);   // bijective, XCD-chunked
    const int s = slot / 88, rem = slot - s * 88;
    const int m0 = (rem >> 2) * 64, n0 = (rem & 3) * 64;
    const short* A = Ab16 + (long)s * kN * kCIN;
    const short* B = Bb16 + (long)s * kCO * kCIN;
    float* C = pf + (long)s * kN * kCO;
    const int t = threadIdx.x, w = t >> 6, l = t & 63;
    const int lr = l & 15, sg = l >> 4;

    const int srow = t >> 3, qa = t & 7;
    long gA[2]; int woffA[2];
    #pragma unroll
    for (int j = 0; j < 2; ++j) {
        int ar = srow + j * 32;
        int am = m0 + ar; if (am >= kN) am = kN - 1;
        gA[j] = (long)am * kCIN + qa * 8;
        woffA[j] = ar * 128 + ((qa ^ (ar & 7)) << 4);
    }
    long gB[2]; int woffB[2];
    #pragma unroll
    for (int j = 0; j < 2; ++j) {
        int br = srow + j * 32;
        gB[j] = (long)(n0 + br) * kCIN + qa * 8;
        woffB[j] = 8192 + br * 128 + ((qa ^ (br & 7)) << 4);
    }

    int aoff[2][2], boff[2][2];
    #pragma unroll
    for (int mi = 0; mi < 2; ++mi) {
        int r = (w >> 1) * 32 + mi * 16 + lr;
        #pragma unroll
        for (int kk = 0; kk < 2; ++kk)
            aoff[mi][kk] = r * 128 + (((kk * 4 + sg) ^ (r & 7)) << 4);
    }
    #pragma unroll
    for (int ni = 0; ni < 2; ++ni) {
        int r = (w & 1) * 32 + ni * 16 + lr;
        #pragma unroll
        for (int kk = 0; kk < 2; ++kk)
            boff[ni][kk] = 8192 + r * 128 + (((kk * 4 + sg) ^ (r & 7)) << 4);
    }

    f32x4 acc[2][2] = {};
    const int NT = kCIN >> 6;  // 24
    {
        char* lb = (char*)&smem[0][0];
        #pragma unroll
        for (int j = 0; j < 2; ++j)
            *(bf16x8*)(lb + woffA[j]) = *(const bf16x8*)(A + gA[j]);
        #pragma unroll
        for (int j = 0; j < 2; ++j)
            *(bf16x8*)(lb + woffB[j]) = *(const bf16x8*)(B + gB[j]);
    }
    __syncthreads();
    for (int tt = 0; tt < NT; ++tt) {
        bf16x8 nsa[2], nsb[2];
        if (tt + 1 < NT) {
            long o = (long)(tt + 1) * 64;
            #pragma unroll
            for (int j = 0; j < 2; ++j) nsa[j] = *(const bf16x8*)(A + gA[j] + o);
            #pragma unroll
            for (int j = 0; j < 2; ++j) nsb[j] = *(const bf16x8*)(B + gB[j] + o);
        }
        char* lb = (char*)&smem[tt & 1][0];
        #pragma unroll
        for (int kk = 0; kk < 2; ++kk) {
            bf16x8 a[2], b[2];
            #pragma unroll
            for (int mi = 0; mi < 2; ++mi) a[mi] = *(const bf16x8*)(lb + aoff[mi][kk]);
            #pragma unroll
            for (int ni = 0; ni < 2; ++ni) b[ni] = *(const bf16x8*)(lb + boff[ni][kk]);
            #pragma unroll
            for (int mi = 0; mi < 2; ++mi)
                #pragma unroll
                for (int ni = 0; ni < 2; ++ni)
                    acc[mi][ni] = __builtin_amdgcn_mfma_f32_16x16x32_bf16(a[mi], b[ni], acc[mi][ni], 0, 0, 0);
        }
        if (tt + 1 < NT) {
            char* nb = (char*)&smem[(tt + 1) & 1][0];
            #pragma unroll
            for (int j = 0; j < 2; ++j) *(bf16x8*)(nb + woffA[j]) = nsa[j];
            #pragma unroll
            for (int j = 0; j < 2; ++j) *(bf16x8*)(nb + woffB[j]) = nsb[j];
        }
        __syncthreads();
    }
    const int q = l >> 4;
    const int wm0 = m0 + (w >> 1) * 32, wn0 = n0 + (w & 1) * 32;
    #pragma unroll
    for (int mi = 0; mi < 2; ++mi)
        #pragma unroll
        for (int ni = 0; ni < 2; ++ni)
            #pragma unroll
            for (int r = 0; r < 4; ++r) {
                int m = wm0 + mi * 16 + q * 4 + r;
                if (m < kN)
                    C[(long)m * kCO + wn0 + ni * 16 + lr] = acc[mi][ni][r];
            }
}

// ---------------------------------------------------------------------------
// conv3x3 MFMA: 64px x 128co, K-step 64. A bypasses LDS (direct global->
// fragment registers, 1-step ping-pong). B LDS-staged (2x16KB), depth-2
// prefetch, lgkm barriers, setprio, bijective XCD swizzle.
// ---------------------------------------------------------------------------
__global__ __launch_bounds__(256)
void conv_mfma_kernel(const short* __restrict__ up, const short* __restrict__ wt,
                      const float* __restrict__ bias, float* __restrict__ out)
{
    __shared__ short smem[2][8192];   // per buf: B only, 128 rows x 64k x 2B = 16KB
    const int t = threadIdx.x, w = t >> 6, l = t & 63;
    const int lr = l & 15, sg = l >> 4;
    // bijective XCD-chunked swizzle: nwg=686, q=85, r=6
    const int bid = blockIdx.x;
    const int xcd = bid & 7, slot = bid >> 3;
    const int wgid = (xcd < 6 ? xcd * 86 : 6 * 86 + (xcd - 6) * 85) + slot;
    const int pm0 = (wgid >> 1) * 64;
    const int bn0 = (wgid & 1) * 128;
    const int wr = w >> 1, wc = w & 1;

    // A-fragment global bases: lane lr = row, sg*8 = k-offset within 32-chunk
    long gAF[2];
    #pragma unroll
    for (int mi = 0; mi < 2; ++mi) {
        int p = pm0 + wr * 32 + mi * 16 + lr; if (p >= kNP) p = kNP - 1;
        int oy = p / kOW, ox = p - oy * kOW;
        gAF[mi] = ((long)oy * 150 + ox) * kCO + sg * 8;
    }

    // B staging: thread stages 4 rows x 16B
    const int srow = t >> 3, qa = t & 7;
    long gB[4]; int woffB[4];
    #pragma unroll
    for (int j = 0; j < 4; ++j) {
        int br = srow + j * 32;
        gB[j] = (long)(bn0 + br) * 2304 + qa * 8;
        woffB[j] = br * 128 + ((qa ^ (br & 7)) << 4);
    }

    int boff[4][2];
    #pragma unroll
    for (int ni = 0; ni < 4; ++ni) {
        int r = wc * 64 + ni * 16 + lr;
        #pragma unroll
        for (int kk = 0; kk < 2; ++kk)
            boff[ni][kk] = r * 128 + (((kk * 4 + sg) ^ (r & 7)) << 4);
    }

    f32x4 acc[2][4] = {};
    const int NT = 36;

#define CONV_BAR() { \
        asm volatile("s_waitcnt lgkmcnt(0)" ::: "memory"); \
        __builtin_amdgcn_sched_barrier(0); \
        __builtin_amdgcn_s_barrier(); }

#define CONV_TADDR(tn, ta, tb) { \
        int _tap = (tn) >> 2, _c0 = ((tn) & 3) << 6; \
        int _ky = _tap / 3, _kx = _tap - _ky * 3; \
        ta = ((long)_ky * 150 + _kx) * kCO + _c0; \
        tb = (long)(tn) * 64; }

#define CONV_LOADB(Pb_, tn) { \
        long _ta, _tb; CONV_TADDR(tn, _ta, _tb); (void)_ta; \
        _Pragma("unroll") \
        for (int j = 0; j < 4; ++j) Pb_[j] = *(const bf16x8*)(wt + gB[j] + _tb); }

#define CONV_LOADA(F_, tn) { \
        long _ta, _tb; CONV_TADDR(tn, _ta, _tb); (void)_tb; \
        _Pragma("unroll") \
        for (int mi = 0; mi < 2; ++mi) \
            _Pragma("unroll") \
            for (int kk = 0; kk < 2; ++kk) \
                F_[mi][kk] = *(const bf16x8*)(up + gAF[mi] + _ta + kk * 32); }

#define CONV_WRITEB(buf, Pb_) { \
        char* _nb = (char*)&smem[buf][0]; \
        _Pragma("unroll") \
        for (int j = 0; j < 4; ++j) *(bf16x8*)(_nb + woffB[j]) = Pb_[j]; }

#define CONV_COMPUTE(buf, F_) { \
        char* _lb = (char*)&smem[buf][0]; \
        _Pragma("unroll") \
        for (int kk = 0; kk < 2; ++kk) { \
            bf16x8 _b[4]; \
            _Pragma("unroll") \
            for (int ni = 0; ni < 4; ++ni) _b[ni] = *(const bf16x8*)(_lb + boff[ni][kk]); \
            __builtin_amdgcn_s_setprio(1); \
            _Pragma("unroll") \
            for (int mi = 0; mi < 2; ++mi) \
                _Pragma("unroll") \
                for (int ni = 0; ni < 4; ++ni) \
                    acc[mi][ni] = __builtin_amdgcn_mfma_f32_16x16x32_bf16(F_[mi][kk], _b[ni], acc[mi][ni], 0, 0, 0); \
            __builtin_amdgcn_s_setprio(0); \
        } }

    bf16x8 PaB[4], PbB[4];        // B staging reg sets
    bf16x8 FaA[2][2], FbA[2][2];  // A fragment reg sets (static idx via unroll)

    CONV_LOADB(PbB, 0);
    CONV_WRITEB(0, PbB);
    CONV_LOADB(PaB, 1);
    CONV_LOADA(FaA, 0);
    CONV_BAR();

    for (int tt = 0; tt < NT; tt += 2) {
        if (tt + 2 < NT) CONV_LOADB(PbB, tt + 2);
        CONV_LOADA(FbA, tt + 1);
        CONV_COMPUTE(0, FaA);
        CONV_WRITEB(1, PaB);
        CONV_BAR();
        if (tt + 3 < NT) CONV_LOADB(PaB, tt + 3);
        if (tt + 2 < NT) CONV_LOADA(FaA, tt + 2);
        CONV_COMPUTE(1, FbA);
        if (tt + 2 < NT) CONV_WRITEB(0, PbB);
        CONV_BAR();
    }
#undef CONV_BAR
#undef CONV_TADDR
#undef CONV_LOADB
#undef CONV_LOADA
#undef CONV_WRITEB
#undef CONV_COMPUTE

    const int q = l >> 4;
    const int m0 = pm0 + wr * 32;
    const int n0 = bn0 + wc * 64;
    #pragma unroll
    for (int mi = 0; mi < 2; ++mi)
        #pragma unroll
        for (int ni = 0; ni < 4; ++ni) {
            const int co = n0 + ni * 16 + lr;
            const float bv = bias[co];
            #pragma unroll
            for (int r = 0; r < 4; ++r) {
                int p = m0 + mi * 16 + q * 4 + r;
                if (p < kNP)
                    out[(long)co * kNP + p] = acc[mi][ni][r] + bv;
            }
        }
}

// partial column sums of pf over n
__global__ __launch_bounds__(256)
void colmean_kernel(const float* __restrict__ pf, float* __restrict__ colpart)
{
    int s = blockIdx.x, ch = blockIdx.y, o = threadIdx.x;
    int n0 = ch * 128, n1 = n0 + 128 > kN ? kN : n0 + 128;
    float a = 0.f;
    for (int n = n0; n < n1; ++n) a += pf[((long)s * kN + n) * kCO + o];
    colpart[ch * kS * kCO + s * kCO + o] = a;
}

// attn stage 1
__global__ __launch_bounds__(384)
void attn_part1(const float* __restrict__ colpart, const float* __restrict__ w1,
                float* __restrict__ partial)
{
    __shared__ float cm[128];
    int b = blockIdx.x, t = threadIdx.x;
    int c0 = b * 128;
    if (t < 128) {
        float a = 0.f;
        #pragma unroll
        for (int ch = 0; ch < 11; ++ch) a += colpart[ch * kS * kCO + c0 + t];
        cm[t] = a * (1.f / kN);
    }
    __syncthreads();
    float acc = 0.f;
    #pragma unroll 4
    for (int c = 0; c < 128; ++c) acc += cm[c] * w1[(long)(c0 + c) * kHID + t];
    partial[b * kHID + t] = acc;
}

// attn stage 2
__global__ __launch_bounds__(384)
void attn_part2(const float* __restrict__ partial, const float* __restrict__ b1,
                const float* __restrict__ w2, const float* __restrict__ b2,
                const float* __restrict__ ss, float* __restrict__ wfin)
{
    __shared__ float h[kHID];
    __shared__ float logits[8];
    int t = threadIdx.x;
    float acc = b1[t];
    #pragma unroll
    for (int b = 0; b < 12; ++b) acc += partial[b * kHID + t];
    h[t] = fmaxf(acc, 0.f);
    __syncthreads();
    if (t < kS) {
        float lg = b2[t];
        for (int j = 0; j < kHID; ++j) lg += h[j] * w2[j * kS + t];
        logits[t] = lg;
    }
    __syncthreads();
    if (t == 0) {
        float w[kS], mx = -1e30f, sum = 0.f;
        for (int s = 0; s < kS; ++s) mx = fmaxf(mx, logits[s]);
        for (int s = 0; s < kS; ++s) { w[s] = expf(logits[s] - mx); sum += w[s]; }
        for (int s = 0; s < kS; ++s) w[s] /= sum;
        mx = -1e30f;
        for (int s = 0; s < kS; ++s) { w[s] *= ss[s]; mx = fmaxf(mx, w[s]); }
        sum = 0.f;
        float e[kS];
        for (int s = 0; s < kS; ++s) { e[s] = expf(w[s] - mx); sum += e[s]; }
        for (int s = 0; s < kS; ++s) wfin[s] = e[s] / sum;
    }
}

// fused = sum_s wfin[s]*pf[s]; writes f32 fwd+rev and bf16 fwd+rev
__global__ __launch_bounds__(256)
void fuse_kernel(const float* __restrict__ pf, const float* __restrict__ wfin,
                 float* __restrict__ fused2, short* __restrict__ fusedb2)
{
    long idx = (long)blockIdx.x * 256 + threadIdx.x;
    if (idx >= (long)kN * kCO) return;
    float acc = 0.f;
    #pragma unroll
    for (int s = 0; s < kS; ++s) acc += wfin[s] * pf[(long)s * kN * kCO + idx];
    long n = idx / kCO; int c = (int)(idx % kCO);
    long ridx = (long)kN * kCO + (kN - 1 - n) * kCO + c;
    short bv = f2bf(acc);
    fused2[idx] = acc;
    fused2[ridx] = acc;
    fusedb2[idx] = bv;
    fusedb2[ridx] = bv;
}

// causal depthwise conv (K=4) + silu; writes f32 z2 and bf16 z2b
__global__ __launch_bounds__(256)
void dwconv_kernel(const float* __restrict__ zg2,
                   const float* __restrict__ wf, const float* __restrict__ bf,
                   const float* __restrict__ wb, const float* __restrict__ bb,
                   float* __restrict__ z2, short* __restrict__ z2b)
{
    long idx = (long)blockIdx.x * 256 + threadIdx.x;
    int dir = blockIdx.y;
    if (idx >= (long)kN * kDI) return;
    long n = idx >> 9; int i = (int)(idx & (kDI - 1));
    const float* zg = zg2 + (long)dir * kN * 2 * kDI;
    const float* w  = dir ? wb : wf;
    const float* b  = dir ? bb : bf;
    float acc = b[i];
    #pragma unroll
    for (int k = 0; k < 4; ++k) {
        long m = n - 3 + k;
        if (m >= 0) acc += w[k * kDI + i] * zg[m * 2 * kDI + i];
    }
    float sg = 1.f / (1.f + expf(-acc));
    float v = acc * sg;
    z2 [(long)dir * kN * kDI + idx] = v;
    z2b[(long)dir * kN * kDI + idx] = f2bf(v);
}

// delta = softplus(xp[:,32+i] + xp[:,544])  -- once per (n,i)
__global__ __launch_bounds__(256)
void delta_kernel(const float* __restrict__ xp2, float* __restrict__ delta2)
{
    long idx = (long)blockIdx.x * 256 + threadIdx.x;
    int dir = blockIdx.y;
    if (idx >= (long)kN * kDI) return;
    long n = idx >> 9; int i = (int)(idx & (kDI - 1));
    const float* xp = xp2 + (long)dir * kXPS + n * kXPW;
    float x = xp[2 * kDS + i] + xp[kXPW - 1];
    float sp = fmaxf(x, 0.f) + log1pf(expf(-fabsf(x)));
    delta2[(long)dir * kN * kDI + idx] = sp;
}

// ---- chunk-parallel scan: pass A (depth-2 register prefetch) ---------------
__global__ __launch_bounds__(256)
void scan_partA(const float* __restrict__ delta2, const float* __restrict__ z2,
                const float* __restrict__ xp2,
                const float* __restrict__ Alogf, const float* __restrict__ Alogb,
                float* __restrict__ chunkP, float* __restrict__ chunkH)
{
    int bx = blockIdx.x;
    int c  = blockIdx.y;
    int dir = bx >> 5, iblk = bx & 31;
    int t = threadIdx.x;
    int s = t & 15, il = t >> 4;
    int i = iblk * 16 + il;
    int gid = dir * 8192 + iblk * 256 + t;
    const float* Alog = dir ? Alogb : Alogf;
    float A = expf(Alog[i * kDS + s]);
    int n0 = c * kCH, n1 = n0 + kCH; if (n1 > kN) n1 = kN;
    const int cnt = n1 - n0;
    const float* dp = delta2 + (long)dir * kN * kDI + (long)n0 * kDI + i;
    const float* zp = z2     + (long)dir * kN * kDI + (long)n0 * kDI + i;
    const float* xpp = xp2   + (long)dir * kXPS     + (long)n0 * kXPW;

    float d0 = *dp, v0 = *zp, b0 = xpp[s];
    dp += kDI; zp += kDI; xpp += kXPW;
    float d1 = 0.f, v1 = 0.f, b1 = 0.f;
    if (cnt > 1) { d1 = *dp; v1 = *zp; b1 = xpp[s]; }

    float h = 0.f, P = 1.f;
    for (int k = 0; k < cnt; ++k) {
        dp += kDI; zp += kDI; xpp += kXPW;   // now at k+2
        float d2 = 0.f, v2 = 0.f, b2 = 0.f;
        if (k + 2 < cnt) { d2 = *dp; v2 = *zp; b2 = xpp[s]; }
        float dA = __expf(-d0 * A);
        h = dA * h + d0 * b0 * v0;
        P *= dA;
        d0 = d1; v0 = v1; b0 = b1;
        d1 = d2; v1 = v2; b1 = b2;
    }
    chunkP[(long)c * 16384 + gid] = P;
    chunkH[(long)c * 16384 + gid] = h;
}

// ---- pass B (hin in-place; depth-2 prefetch) --------------------------------
__global__ __launch_bounds__(256)
void scan_partB(float* __restrict__ chunkP, const float* __restrict__ chunkH)
{
    int gid = blockIdx.x * 256 + threadIdx.x;
    float P0 = chunkP[gid];
    float Q0 = chunkH[gid];
    float P1 = chunkP[16384L + gid];
    float Q1 = chunkH[16384L + gid];
    float H = 0.f;
    for (int c = 0; c < kNC; ++c) {
        float P2 = 0.f, Q2 = 0.f;
        if (c + 2 < kNC) {
            P2 = chunkP[(long)(c + 2) * 16384 + gid];
            Q2 = chunkH[(long)(c + 2) * 16384 + gid];
        }
        chunkP[(long)c * 16384 + gid] = H;   // hin for chunk c
        H = P0 * H + Q0;
        P0 = P1; Q0 = Q1;
        P1 = P2; Q1 = Q2;
    }
}

// ---- pass C (depth-2 prefetch; gate-silu fused via __expf; bf16 ygb) -------
__global__ __launch_bounds__(256)
void scan_partC(const float* __restrict__ delta2, const float* __restrict__ z2,
                const float* __restrict__ xp2, const float* __restrict__ zg2,
                const float* __restrict__ Df, const float* __restrict__ Db,
                const float* __restrict__ Alogf, const float* __restrict__ Alogb,
                const float* __restrict__ hin, short* __restrict__ ygb)
{
    int bx = blockIdx.x;
    int c  = blockIdx.y;
    int dir = bx >> 5, iblk = bx & 31;
    int t = threadIdx.x;
    int s = t & 15, il = t >> 4;
    int i = iblk * 16 + il;
    int gid = dir * 8192 + iblk * 256 + t;
    const float* D    = dir ? Db : Df;
    const float* Alog = dir ? Alogb : Alogf;
    float A  = expf(Alog[i * kDS + s]);
    float Dv = D[i];
    int n0 = c * kCH, n1 = n0 + kCH; if (n1 > kN) n1 = kN;
    const int cnt = n1 - n0;
    const float* dp  = delta2 + (long)dir * kN * kDI + (long)n0 * kDI + i;
    const float* zp  = z2     + (long)dir * kN * kDI + (long)n0 * kDI + i;
    const float* xpp = xp2    + (long)dir * kXPS     + (long)n0 * kXPW;
    const float* gp  = zg2    + (long)dir * kN * 2 * kDI + (long)n0 * 2 * kDI + kDI + i;
    short* yp        = ygb    + (long)dir * kN * kDI + (long)n0 * kDI + i;

    float d0 = *dp, v0 = *zp, b0 = xpp[s], c0 = xpp[kDS + s];
    float g0 = 0.f; if (s == 0) g0 = *gp;
    dp += kDI; zp += kDI; xpp += kXPW; gp += 2 * kDI;
    float d1 = 0.f, v1 = 0.f, b1 = 0.f, c1 = 0.f, g1 = 0.f;
    if (cnt > 1) {
        d1 = *dp; v1 = *zp; b1 = xpp[s]; c1 = xpp[kDS + s];
        if (s == 0) g1 = *gp;
    }

    float h = hin[(long)c * 16384 + gid];
    for (int k = 0; k < cnt; ++k) {
        dp += kDI; zp += kDI; xpp += kXPW; gp += 2 * kDI;   // now at k+2
        float d2 = 0.f, v2 = 0.f, b2 = 0.f, c2 = 0.f, g2 = 0.f;
        if (k + 2 < cnt) {
            d2 = *dp; v2 = *zp; b2 = xpp[s]; c2 = xpp[kDS + s];
            if (s == 0) g2 = *gp;
        }
        float dA = __expf(-d0 * A);
        h = dA * h + d0 * b0 * v0;
        float cc = h * c0;
        cc += __shfl_xor(cc, 1, 16);
        cc += __shfl_xor(cc, 2, 16);
        cc += __shfl_xor(cc, 4, 16);
        cc += __shfl_xor(cc, 8, 16);
        if (s == 0) {
            float sgm = 1.f / (1.f + __expf(-g0));
            float v = (cc + Dv * v0) * g0 * sgm;
            *yp = f2bf(v);
        }
        yp += kDI;
        d0 = d1; v0 = v1; b0 = b1; c0 = c1; g0 = g1;
        d1 = d2; v1 = v2; b1 = b2; c1 = c2; g1 = g2;
    }
}

// r = gemm_out + x; layernorm; write bf16 cat
__global__ __launch_bounds__(256)
void resid_ln_cat_kernel(const float* __restrict__ gt2, const float* __restrict__ x2,
                         const float* __restrict__ gf, const float* __restrict__ betf,
                         const float* __restrict__ gb, const float* __restrict__ betb,
                         short* __restrict__ catb)
{
    int n = blockIdx.x, dir = blockIdx.y, t = threadIdx.x;
    const float* gt = gt2 + ((long)dir * kN + n) * kCO;
    const float* x  = x2  + ((long)dir * kN + n) * kCO;
    const float* g  = dir ? gb : gf;
    const float* be = dir ? betb : betf;
    float r = gt[t] + x[t];
    float s1 = r, s2 = r * r;
    #pragma unroll
    for (int m = 32; m >= 1; m >>= 1) {
        s1 += __shfl_xor(s1, m, 64);
        s2 += __shfl_xor(s2, m, 64);
    }
    __shared__ float red[8];
    int w = t >> 6;
    if ((t & 63) == 0) { red[w] = s1; red[4 + w] = s2; }
    __syncthreads();
    float S1 = red[0] + red[1] + red[2] + red[3];
    float S2 = red[4] + red[5] + red[6] + red[7];
    float mu  = S1 * (1.f / kCO);
    float var = S2 * (1.f / kCO) - mu * mu;
    float inv = rsqrtf(var + 1e-5f);
    float v = g[t] * (r - mu) * inv + be[t];
    int row = dir ? (kN - 1 - n) : n;
    catb[(long)row * (2 * kCO) + dir * kCO + t] = f2bf(v);
}

// bilinear 4x upsample -> bf16 into padded (150,150,256) buffer, border zeros
__global__ __launch_bounds__(256)
void upsample_kernel(const float* __restrict__ merged, short* __restrict__ up)
{
    int p = blockIdx.x;               // 0..22499 over 150x150
    int y = p / 150, x = p - y * 150;
    int c = threadIdx.x;
    if (y == 0 || y == 149 || x == 0 || x == 149) {
        up[((long)y * 150 + x) * kCO + c] = 0;
        return;
    }
    int oy = y - 1, ox = x - 1;
    float sy = (oy + 0.5f) * ((float)kHP / (float)kOH) - 0.5f;
    float sx = (ox + 0.5f) * ((float)kWP / (float)kOW) - 0.5f;
    int iy0 = (int)floorf(sy); float fy = sy - (float)iy0;
    int ix0 = (int)floorf(sx); float fx = sx - (float)ix0;
    float wy0 = 1.f - fy, wy1 = fy, wx0 = 1.f - fx, wx1 = fx;
    int iy1 = iy0 + 1, ix1 = ix0 + 1;
    if (iy0 < 0)       { iy0 = 0;       wy0 = 0.f; }
    if (iy1 > kHP - 1) { iy1 = kHP - 1; wy1 = 0.f; }
    if (ix0 < 0)       { ix0 = 0;       wx0 = 0.f; }
    if (ix1 > kWP - 1) { ix1 = kWP - 1; wx1 = 0.f; }
    float wys = wy0 + wy1; wy0 /= wys; wy1 /= wys;
    float wxs = wx0 + wx1; wx0 /= wxs; wx1 /= wxs;
    const float* M00 = merged + (long)(iy0 * kWP + ix0) * kCO;
    const float* M01 = merged + (long)(iy0 * kWP + ix1) * kCO;
    const float* M10 = merged + (long)(iy1 * kWP + ix0) * kCO;
    const float* M11 = merged + (long)(iy1 * kWP + ix1) * kCO;
    float v = wy0 * (wx0 * M00[c] + wx1 * M01[c]) + wy1 * (wx0 * M10[c] + wx1 * M11[c]);
    up[((long)y * 150 + x) * kCO + c] = f2bf(v);
}

extern "C" void kernel_launch(void* const* d_in, const int* in_sizes, int n_in,
                              void* d_out, int out_size, void* d_ws, size_t ws_size,
                              hipStream_t stream)
{
    (void)in_sizes; (void)n_in; (void)out_size; (void)ws_size;
    const float* features  = (const float*)d_in[0];
    const float* proj_w    = (const float*)d_in[1];
    const float* attn_w1   = (const float*)d_in[2];
    const float* attn_b1   = (const float*)d_in[3];
    const float* attn_w2   = (const float*)d_in[4];
    const float* attn_b2   = (const float*)d_in[5];
    const float* src_scale = (const float*)d_in[6];
    const float* f_in_w    = (const float*)d_in[7];
    const float* f_conv_w  = (const float*)d_in[8];
    const float* f_conv_b  = (const float*)d_in[9];
    const float* f_xp_w    = (const float*)d_in[10];
    const float* f_Alog    = (const float*)d_in[11];
    const float* f_D       = (const float*)d_in[12];
    const float* f_out_w   = (const float*)d_in[13];
    const float* f_ln_g    = (const float*)d_in[14];
    const float* f_ln_b    = (const float*)d_in[15];
    const float* b_in_w    = (const float*)d_in[16];
    const float* b_conv_w  = (const float*)d_in[17];
    const float* b_conv_b  = (const float*)d_in[18];
    const float* b_xp_w    = (const float*)d_in[19];
    const float* b_Alog    = (const float*)d_in[20];
    const float* b_D       = (const float*)d_in[21];
    const float* b_out_w   = (const float*)d_in[22];
    const float* b_ln_g    = (const float*)d_in[23];
    const float* b_ln_b    = (const float*)d_in[24];
    const float* merge_w   = (const float*)d_in[25];
    const float* co1_w     = (const float*)d_in[26];
    const float* co1_b     = (const float*)d_in[27];

    float* ws      = (float*)d_ws;
    float* outp    = (float*)d_out;
    float* pf      = ws + OFF_PF;
    float* colpart = ws + OFF_COLPART;
    float* wfin    = ws + OFF_WFIN;
    float* attnp   = ws + OFF_ATTNP;
    float* fused2  = ws + OFF_FUSED2;
    float* zg2     = ws + OFF_ZG;
    float* z2      = ws + OFF_Z;
    float* xp2     = ws + OFF_XP;
    float* delta2  = ws + OFF_DELTA;
    float* gt2     = ws + OFF_GT;
    float* merged  = ws + OFF_MERGED;
    float* chunkP  = ws + OFF_SCANP;
    float* chunkH  = ws + OFF_SCANH;
    short* featb   = (short*)(ws + OFF_FEATB);
    short* projwb  = (short*)(ws + OFF_PROJWB);
    short* in_wt   = (short*)(ws + OFF_INWT);
    short* xp_wt   = (short*)(ws + OFF_XPWT);
    short* out_wt  = (short*)(ws + OFF_OUTWT);
    short* mrg_wt  = (short*)(ws + OFF_MERGEWT);
    short* fusedb2 = (short*)(ws + OFF_FUSEDB);
    short* z2b     = (short*)(ws + OFF_Z2B);
    short* ygb     = (short*)(ws + OFF_YGB);
    short* catb    = (short*)(ws + OFF_CAT);
    short* upb     = (short*)(ws + OFF_UPB);
    short* wconvb  = (short*)(ws + OFF_WCONVB);

    // 0. bf16 casts for proj
    cast8_kernel<<<dim3(6161), 256, 0, stream>>>(features, featb, 1577088L);
    cast8_kernel<<<dim3(1152), 256, 0, stream>>>(proj_w, projwb, 294912L);
    // 1. pf[s] = feats[s] @ proj_w[s]^T
    proj_mfma_kernel<<<dim3(528), 256, 0, stream>>>(featb, projwb, pf);
    // 2. weight transposes
    transpose_cast_kernel<<<dim3(8, 32, 2), 256, 0, stream>>>(f_in_w, b_in_w, in_wt, 256, 1024);
    transpose_cast_kernel<<<dim3(16, 18, 2), 256, 0, stream>>>(f_xp_w, b_xp_w, xp_wt, 512, 545);
    transpose_cast_kernel<<<dim3(16, 8, 1), 256, 0, stream>>>(merge_w, merge_w, mrg_wt, 512, 256);
    // 3. column sums + attention weights
    colmean_kernel<<<dim3(6, 11), 256, 0, stream>>>(pf, colpart);
    attn_part1<<<dim3(12), 384, 0, stream>>>(colpart, attn_w1, attnp);
    attn_part2<<<1, 384, 0, stream>>>(attnp, attn_b1, attn_w2, attn_b2, src_scale, wfin);
    // 4. fuse sources (+ reversed)
    fuse_kernel<<<dim3(1369), 256, 0, stream>>>(pf, wfin, fused2, fusedb2);
    // 4b. out_w transpose
    transpose_cast_kernel<<<dim3(16, 8, 2), 256, 0, stream>>>(f_out_w, b_out_w, out_wt, 512, 256);
    // 5. zg = fused @ in_w
    mfma_nt<<<dim3(22, 16, 2), 256, 0, stream>>>(
        fusedb2, (long)kN * kCO, in_wt, (long)2 * kDI * kCO,
        zg2, (long)kN * 2 * kDI, kN, 2 * kDI, kCO);
    // 6. causal dwconv + silu
    dwconv_kernel<<<dim3(2738, 2), 256, 0, stream>>>(zg2, f_conv_w, f_conv_b,
                                                     b_conv_w, b_conv_b, z2, z2b);
    // 7. xp = z @ xp_w
    mfma_nt<<<dim3(22, 9, 2), 256, 0, stream>>>(
        z2b, (long)kN * kDI, xp_wt, (long)kXPW * kDI,
        xp2, kXPS, kN, kXPW, kDI);
    // 8. delta
    delta_kernel<<<dim3(2738, 2), 256, 0, stream>>>(xp2, delta2);
    // 9. chunk-parallel selective scan (48 chunks, depth-2 prefetch)
    scan_partA<<<dim3(64, kNC), 256, 0, stream>>>(delta2, z2, xp2, f_Alog, b_Alog,
                                                  chunkP, chunkH);
    scan_partB<<<dim3(64), 256, 0, stream>>>(chunkP, chunkH);
    scan_partC<<<dim3(64, kNC), 256, 0, stream>>>(delta2, z2, xp2, zg2, f_D, b_D,
                                                  f_Alog, b_Alog, chunkP, ygb);
    // 10. gt = yg @ out_w
    mfma_nt<<<dim3(22, 4, 2), 256, 0, stream>>>(
        ygb, (long)kN * kDI, out_wt, (long)kCO * kDI,
        gt2, (long)kN * kCO, kN, kCO, kDI);
    // 11. residual + LN + cat
    resid_ln_cat_kernel<<<dim3(1369, 2), 256, 0, stream>>>(gt2, fused2, f_ln_g, f_ln_b,
                                                           b_ln_g, b_ln_b, catb);
    // 12. merged = cat @ merge_w
    mfma_nt<<<dim3(22, 4, 1), 256, 0, stream>>>(
        catb, 0, mrg_wt, 0,
        merged, 0, kN, kCO, 2 * kCO);
    // 13. conv weight -> bf16 transposed
    transpose_cast_kernel<<<dim3(72, 8, 1), 256, 0, stream>>>(co1_w, co1_w, wconvb, 2304, 256);
    // 14. bilinear upsample (border zeros fused)
    upsample_kernel<<<dim3(150 * 150), 256, 0, stream>>>(merged, upb);
    // 15. 3x3 conv (A-in-register hybrid, lgkm barriers, XCD swizzle)
    conv_mfma_kernel<<<dim3(686), 256, 0, stream>>>(upb, wconvb, co1_b, outp);
}

// Round 19
// 282.203 us; speedup vs baseline: 1.1059x; 1.1059x over previous
//
#include <hip/hip_runtime.h>
#include <math.h>

// ---------------------------------------------------------------------------
// Upnet_v3 pipeline, round 19:
//  - conv3x3: REVERT to round-17 kernel (A-bypass gather regressed 50->81us;
//    LDS-staged both-operand version restored).
//  - fuse_kernel: drop f32 reversed copy (resid_ln_cat indexes forward buf
//    with row = dir ? kN-1-n : n). ~2us less traffic.
// ---------------------------------------------------------------------------

namespace {
constexpr int kS   = 6;
constexpr int kHP  = 37;
constexpr int kWP  = 37;
constexpr int kN   = 1369;      // HP*WP
constexpr int kCIN = 1536;
constexpr int kCO  = 256;
constexpr int kDS  = 16;
constexpr int kDI  = 512;
constexpr int kHID = 384;
constexpr int kOH  = 148;
constexpr int kOW  = 148;
constexpr int kNP  = kOH * kOW; // 21904
constexpr int kXPW = 545;       // 2*DS + DI + 1
constexpr long kXPS = 746112;   // padded kN*kXPW per dir
constexpr int kNC  = 48;        // scan chunks
constexpr int kCH  = 29;        // chunk length (48*29 = 1392 >= 1369)

// ---- workspace ledger (f32 units, total <= 13,911,040 = 55.6 MB) ----------
constexpr long OFF_PF      = 0;
constexpr long OFF_Z2B     = 0;
constexpr long OFF_YGB     = 0;
constexpr long OFF_UPB     = 0;
constexpr long OFF_SCANP   = 700928;    // chunkP 48*16384 (hin in-place)
constexpr long OFF_SCANH   = 1487360;   // chunkH (ends 2,273,792)
constexpr long OFF_COLPART = 2102784;   // dead before scans
constexpr long OFF_WFIN    = 2119680;
constexpr long OFF_ATTNP   = 2119696;
constexpr long OFF_PROJWB  = 2200000;
constexpr long OFF_INWT    = 2200000;
constexpr long OFF_FUSEDB  = 2462144;
constexpr long OFF_ZG      = 2820624;
constexpr long OFF_Z       = 5760000;
constexpr long OFF_WCONVB  = 6000000;
constexpr long OFF_FEATB   = 7161856;
constexpr long OFF_XP      = 7161856;
constexpr long OFF_DELTA   = 8654080;
constexpr long OFF_OUTWT   = 10055936;
constexpr long OFF_GT      = 11457792;
constexpr long OFF_XPWT    = 11457792;
constexpr long OFF_FUSED2  = 12158720;  // f32 fused FORWARD only: 350,464
constexpr long OFF_CAT     = 12859648;
constexpr long OFF_MERGEWT = 13210112;
constexpr long OFF_MERGED  = 13560576;
} // namespace

typedef __attribute__((ext_vector_type(8))) short bf16x8;
typedef __attribute__((ext_vector_type(4))) float f32x4;

__device__ __forceinline__ short f2bf(float x) {
    unsigned u = __builtin_bit_cast(unsigned, x);
    unsigned r = u + 0x7fffu + ((u >> 16) & 1u);
    return (short)(r >> 16);
}

__device__ __forceinline__ bf16x8 cvt8(float4 x, float4 y) {
    union { short s[8]; bf16x8 v; } u;
    u.s[0] = f2bf(x.x); u.s[1] = f2bf(x.y); u.s[2] = f2bf(x.z); u.s[3] = f2bf(x.w);
    u.s[4] = f2bf(y.x); u.s[5] = f2bf(y.y); u.s[6] = f2bf(y.z); u.s[7] = f2bf(y.w);
    return u.v;
}

// cast 8 consecutive f32 -> bf16x8 per thread
__global__ __launch_bounds__(256)
void cast8_kernel(const float* __restrict__ in, short* __restrict__ out, long n8)
{
    long i = (long)blockIdx.x * 256 + threadIdx.x;
    if (i >= n8) return;
    const float4* p = (const float4*)(in + i * 8);
    *(bf16x8*)(out + i * 8) = cvt8(p[0], p[1]);
}

// tiled transpose+cast: w (K x N f32) -> wt (N x K bf16)
__global__ __launch_bounds__(256)
void transpose_cast_kernel(const float* __restrict__ w0, const float* __restrict__ w1,
                           short* __restrict__ wt, int K, int N)
{
    __shared__ float tile[32][33];
    int dir = blockIdx.z;
    const float* w = dir ? w1 : w0;
    short* o = wt + (long)dir * K * N;
    int k0 = blockIdx.x * 32, n0 = blockIdx.y * 32;
    int tx = threadIdx.x & 31, ty = threadIdx.x >> 5; // 32 x 8
    #pragma unroll
    for (int r = 0; r < 32; r += 8) {
        int k = k0 + ty + r, n = n0 + tx;
        tile[ty + r][tx] = (k < K && n < N) ? w[(long)k * N + n] : 0.f;
    }
    __syncthreads();
    #pragma unroll
    for (int r = 0; r < 32; r += 8) {
        int n = n0 + ty + r, k = k0 + tx;
        if (n < N && k < K) o[(long)n * K + k] = f2bf(tile[tx][ty + r]);
    }
}

// ---------------------------------------------------------------------------
// generic bf16 MFMA GEMM, NT form, LDS dbuf, K-step 64 (unchanged)
// ---------------------------------------------------------------------------
__global__ __launch_bounds__(256)
void mfma_nt(const short* __restrict__ A, long sA,
             const short* __restrict__ B, long sB,
             float* __restrict__ C, long sC,
             int M, int N, int K)
{
    __shared__ short smem[2][8192];  // per buf bytes: A [0,8192), B [8192,16384)
    const int bz = blockIdx.z;
    const short* Ab = A + (long)bz * sA;
    const short* Bb = B + (long)bz * sB;
    float* Cb = C + (long)bz * sC;
    const int t = threadIdx.x, w = t >> 6, l = t & 63;
    const int lr = l & 15, sg = l >> 4;
    const int m0 = blockIdx.x * 64, n0 = blockIdx.y * 64;

    const int srow = t >> 3, qa = t & 7;   // 32 base rows x 8 k-segs
    long gA[2]; int woffA[2];
    #pragma unroll
    for (int j = 0; j < 2; ++j) {
        int ar = srow + j * 32;
        int am = m0 + ar; if (am >= M) am = M - 1;
        gA[j] = (long)am * K + qa * 8;
        woffA[j] = ar * 128 + ((qa ^ (ar & 7)) << 4);
    }
    long gB[2]; int woffB[2];
    #pragma unroll
    for (int j = 0; j < 2; ++j) {
        int br = srow + j * 32;
        int bn = n0 + br; if (bn >= N) bn = N - 1;
        gB[j] = (long)bn * K + qa * 8;
        woffB[j] = 8192 + br * 128 + ((qa ^ (br & 7)) << 4);
    }

    int aoff[2][2], boff[2][2];
    #pragma unroll
    for (int mi = 0; mi < 2; ++mi) {
        int r = (w >> 1) * 32 + mi * 16 + lr;
        #pragma unroll
        for (int kk = 0; kk < 2; ++kk)
            aoff[mi][kk] = r * 128 + (((kk * 4 + sg) ^ (r & 7)) << 4);
    }
    #pragma unroll
    for (int ni = 0; ni < 2; ++ni) {
        int r = (w & 1) * 32 + ni * 16 + lr;
        #pragma unroll
        for (int kk = 0; kk < 2; ++kk)
            boff[ni][kk] = 8192 + r * 128 + (((kk * 4 + sg) ^ (r & 7)) << 4);
    }

    f32x4 acc[2][2] = {};
    const int NT = K >> 6;
    {
        char* lb = (char*)&smem[0][0];
        #pragma unroll
        for (int j = 0; j < 2; ++j)
            *(bf16x8*)(lb + woffA[j]) = *(const bf16x8*)(Ab + gA[j]);
        #pragma unroll
        for (int j = 0; j < 2; ++j)
            *(bf16x8*)(lb + woffB[j]) = *(const bf16x8*)(Bb + gB[j]);
    }
    __syncthreads();
    for (int tt = 0; tt < NT; ++tt) {
        bf16x8 nsa[2], nsb[2];
        if (tt + 1 < NT) {
            long o = (long)(tt + 1) * 64;
            #pragma unroll
            for (int j = 0; j < 2; ++j) nsa[j] = *(const bf16x8*)(Ab + gA[j] + o);
            #pragma unroll
            for (int j = 0; j < 2; ++j) nsb[j] = *(const bf16x8*)(Bb + gB[j] + o);
        }
        char* lb = (char*)&smem[tt & 1][0];
        #pragma unroll
        for (int kk = 0; kk < 2; ++kk) {
            bf16x8 a[2], b[2];
            #pragma unroll
            for (int mi = 0; mi < 2; ++mi) a[mi] = *(const bf16x8*)(lb + aoff[mi][kk]);
            #pragma unroll
            for (int ni = 0; ni < 2; ++ni) b[ni] = *(const bf16x8*)(lb + boff[ni][kk]);
            #pragma unroll
            for (int mi = 0; mi < 2; ++mi)
                #pragma unroll
                for (int ni = 0; ni < 2; ++ni)
                    acc[mi][ni] = __builtin_amdgcn_mfma_f32_16x16x32_bf16(a[mi], b[ni], acc[mi][ni], 0, 0, 0);
        }
        if (tt + 1 < NT) {
            char* nb = (char*)&smem[(tt + 1) & 1][0];
            #pragma unroll
            for (int j = 0; j < 2; ++j) *(bf16x8*)(nb + woffA[j]) = nsa[j];
            #pragma unroll
            for (int j = 0; j < 2; ++j) *(bf16x8*)(nb + woffB[j]) = nsb[j];
        }
        __syncthreads();
    }
    const int q = l >> 4;
    const int wm0 = m0 + (w >> 1) * 32, wn0 = n0 + (w & 1) * 32;
    #pragma unroll
    for (int mi = 0; mi < 2; ++mi)
        #pragma unroll
        for (int ni = 0; ni < 2; ++ni)
            #pragma unroll
            for (int r = 0; r < 4; ++r) {
                int m = wm0 + mi * 16 + q * 4 + r;
                int n = wn0 + ni * 16 + lr;
                if (m < M && n < N)
                    Cb[(long)m * N + n] = acc[mi][ni][r];
            }
}

// ---------------------------------------------------------------------------
// proj MFMA: bf16 64x64 tile, K-step 64, s-grouped XCD swizzle (unchanged)
// ---------------------------------------------------------------------------
__global__ __launch_bounds__(256)
void proj_mfma_kernel(const short* __restrict__ Ab16, const short* __restrict__ Bb16,
                      float* __restrict__ pf)
{
    __shared__ short smem[2][8192];
    const int bid = blockIdx.x;                     // 0..527
    const int slot = (bid & 7) * 66 + (bid >> 3);   // bijective, XCD-chunked
    const int s = slot / 88, rem = slot - s * 88;
    const int m0 = (rem >> 2) * 64, n0 = (rem & 3) * 64;
    const short* A = Ab16 + (long)s * kN * kCIN;
    const short* B = Bb16 + (long)s * kCO * kCIN;
    float* C = pf + (long)s * kN * kCO;
    const int t = threadIdx.x, w = t >> 6, l = t & 63;
    const int lr = l & 15, sg = l >> 4;

    const int srow = t >> 3, qa = t & 7;
    long gA[2]; int woffA[2];
    #pragma unroll
    for (int j = 0; j < 2; ++j) {
        int ar = srow + j * 32;
        int am = m0 + ar; if (am >= kN) am = kN - 1;
        gA[j] = (long)am * kCIN + qa * 8;
        woffA[j] = ar * 128 + ((qa ^ (ar & 7)) << 4);
    }
    long gB[2]; int woffB[2];
    #pragma unroll
    for (int j = 0; j < 2; ++j) {
        int br = srow + j * 32;
        gB[j] = (long)(n0 + br) * kCIN + qa * 8;
        woffB[j] = 8192 + br * 128 + ((qa ^ (br & 7)) << 4);
    }

    int aoff[2][2], boff[2][2];
    #pragma unroll
    for (int mi = 0; mi < 2; ++mi) {
        int r = (w >> 1) * 32 + mi * 16 + lr;
        #pragma unroll
        for (int kk = 0; kk < 2; ++kk)
            aoff[mi][kk] = r * 128 + (((kk * 4 + sg) ^ (r & 7)) << 4);
    }
    #pragma unroll
    for (int ni = 0; ni < 2; ++ni) {
        int r = (w & 1) * 32 + ni * 16 + lr;
        #pragma unroll
        for (int kk = 0; kk < 2; ++kk)
            boff[ni][kk] = 8192 + r * 128 + (((kk * 4 + sg) ^ (r & 7)) << 4);
    }

    f32x4 acc[2][2] = {};
    const int NT = kCIN >> 6;  // 24
    {
        char* lb = (char*)&smem[0][0];
        #pragma unroll
        for (int j = 0; j < 2; ++j)
            *(bf16x8*)(lb + woffA[j]) = *(const bf16x8*)(A + gA[j]);
        #pragma unroll
        for (int j = 0; j < 2; ++j)
            *(bf16x8*)(lb + woffB[j]) = *(const bf16x8*)(B + gB[j]);
    }
    __syncthreads();
    for (int tt = 0; tt < NT; ++tt) {
        bf16x8 nsa[2], nsb[2];
        if (tt + 1 < NT) {
            long o = (long)(tt + 1) * 64;
            #pragma unroll
            for (int j = 0; j < 2; ++j) nsa[j] = *(const bf16x8*)(A + gA[j] + o);
            #pragma unroll
            for (int j = 0; j < 2; ++j) nsb[j] = *(const bf16x8*)(B + gB[j] + o);
        }
        char* lb = (char*)&smem[tt & 1][0];
        #pragma unroll
        for (int kk = 0; kk < 2; ++kk) {
            bf16x8 a[2], b[2];
            #pragma unroll
            for (int mi = 0; mi < 2; ++mi) a[mi] = *(const bf16x8*)(lb + aoff[mi][kk]);
            #pragma unroll
            for (int ni = 0; ni < 2; ++ni) b[ni] = *(const bf16x8*)(lb + boff[ni][kk]);
            #pragma unroll
            for (int mi = 0; mi < 2; ++mi)
                #pragma unroll
                for (int ni = 0; ni < 2; ++ni)
                    acc[mi][ni] = __builtin_amdgcn_mfma_f32_16x16x32_bf16(a[mi], b[ni], acc[mi][ni], 0, 0, 0);
        }
        if (tt + 1 < NT) {
            char* nb = (char*)&smem[(tt + 1) & 1][0];
            #pragma unroll
            for (int j = 0; j < 2; ++j) *(bf16x8*)(nb + woffA[j]) = nsa[j];
            #pragma unroll
            for (int j = 0; j < 2; ++j) *(bf16x8*)(nb + woffB[j]) = nsb[j];
        }
        __syncthreads();
    }
    const int q = l >> 4;
    const int wm0 = m0 + (w >> 1) * 32, wn0 = n0 + (w & 1) * 32;
    #pragma unroll
    for (int mi = 0; mi < 2; ++mi)
        #pragma unroll
        for (int ni = 0; ni < 2; ++ni)
            #pragma unroll
            for (int r = 0; r < 4; ++r) {
                int m = wm0 + mi * 16 + q * 4 + r;
                if (m < kN)
                    C[(long)m * kCO + wn0 + ni * 16 + lr] = acc[mi][ni][r];
            }
}

// ---------------------------------------------------------------------------
// conv3x3 MFMA: 64px x 128co, K-step 64, depth-2 prefetch, lgkmcnt-only
// barriers, setprio, bijective XCD-chunked swizzle (round-17 proven version)
// ---------------------------------------------------------------------------
__global__ __launch_bounds__(256)
void conv_mfma_kernel(const short* __restrict__ up, const short* __restrict__ wt,
                      const float* __restrict__ bias, float* __restrict__ out)
{
    __shared__ short smem[2][12288];   // per buf: A bytes [0,8192), B [8192,24576)
    const int t = threadIdx.x, w = t >> 6, l = t & 63;
    const int lr = l & 15, sg = l >> 4;
    // bijective XCD-chunked swizzle: nwg=686, q=85, r=6
    const int bid = blockIdx.x;
    const int xcd = bid & 7, slot = bid >> 3;
    const int wgid = (xcd < 6 ? xcd * 86 : 6 * 86 + (xcd - 6) * 85) + slot;
    const int pm0 = (wgid >> 1) * 64;
    const int bn0 = (wgid & 1) * 128;

    const int srow = t >> 3, qa = t & 7;
    long gA[2]; int woffA[2];
    #pragma unroll
    for (int j = 0; j < 2; ++j) {
        int ar = srow + j * 32;
        int p = pm0 + ar; if (p >= kNP) p = kNP - 1;
        int oy = p / kOW, ox = p - oy * kOW;
        gA[j] = ((long)oy * 150 + ox) * kCO + qa * 8;
        woffA[j] = ar * 128 + ((qa ^ (ar & 7)) << 4);
    }
    long gB[4]; int woffB[4];
    #pragma unroll
    for (int j = 0; j < 4; ++j) {
        int br = srow + j * 32;
        gB[j] = (long)(bn0 + br) * 2304 + qa * 8;
        woffB[j] = 8192 + br * 128 + ((qa ^ (br & 7)) << 4);
    }

    int aoff[2][2], boff[4][2];
    #pragma unroll
    for (int mi = 0; mi < 2; ++mi) {
        int r = (w >> 1) * 32 + mi * 16 + lr;
        #pragma unroll
        for (int kk = 0; kk < 2; ++kk)
            aoff[mi][kk] = r * 128 + (((kk * 4 + sg) ^ (r & 7)) << 4);
    }
    #pragma unroll
    for (int ni = 0; ni < 4; ++ni) {
        int r = (w & 1) * 64 + ni * 16 + lr;
        #pragma unroll
        for (int kk = 0; kk < 2; ++kk)
            boff[ni][kk] = 8192 + r * 128 + (((kk * 4 + sg) ^ (r & 7)) << 4);
    }

    f32x4 acc[2][4] = {};
    const int NT = 36;

#define CONV_BAR() { \
        asm volatile("s_waitcnt lgkmcnt(0)" ::: "memory"); \
        __builtin_amdgcn_sched_barrier(0); \
        __builtin_amdgcn_s_barrier(); }

#define CONV_TADDR(tn, ta, tb) { \
        int _tap = (tn) >> 2, _c0 = ((tn) & 3) << 6; \
        int _ky = _tap / 3, _kx = _tap - _ky * 3; \
        ta = ((long)_ky * 150 + _kx) * kCO + _c0; \
        tb = (long)(tn) * 64; }

#define CONV_LOAD(Pa_, Pb_, tn) { \
        long _ta, _tb; CONV_TADDR(tn, _ta, _tb); \
        _Pragma("unroll") \
        for (int j = 0; j < 2; ++j) Pa_[j] = *(const bf16x8*)(up + gA[j] + _ta); \
        _Pragma("unroll") \
        for (int j = 0; j < 4; ++j) Pb_[j] = *(const bf16x8*)(wt + gB[j] + _tb); }

#define CONV_WRITE(buf, Pa_, Pb_) { \
        char* _nb = (char*)&smem[buf][0]; \
        _Pragma("unroll") \
        for (int j = 0; j < 2; ++j) *(bf16x8*)(_nb + woffA[j]) = Pa_[j]; \
        _Pragma("unroll") \
        for (int j = 0; j < 4; ++j) *(bf16x8*)(_nb + woffB[j]) = Pb_[j]; }

#define CONV_COMPUTE(buf) { \
        char* _lb = (char*)&smem[buf][0]; \
        _Pragma("unroll") \
        for (int kk = 0; kk < 2; ++kk) { \
            bf16x8 _a[2], _b[4]; \
            _Pragma("unroll") \
            for (int mi = 0; mi < 2; ++mi) _a[mi] = *(const bf16x8*)(_lb + aoff[mi][kk]); \
            _Pragma("unroll") \
            for (int ni = 0; ni < 4; ++ni) _b[ni] = *(const bf16x8*)(_lb + boff[ni][kk]); \
            __builtin_amdgcn_s_setprio(1); \
            _Pragma("unroll") \
            for (int mi = 0; mi < 2; ++mi) \
                _Pragma("unroll") \
                for (int ni = 0; ni < 4; ++ni) \
                    acc[mi][ni] = __builtin_amdgcn_mfma_f32_16x16x32_bf16(_a[mi], _b[ni], acc[mi][ni], 0, 0, 0); \
            __builtin_amdgcn_s_setprio(0); \
        } }

    bf16x8 PaA[2], PaB[4];
    bf16x8 PbA[2], PbB[4];

    CONV_LOAD(PaA, PaB, 0);
    CONV_WRITE(0, PaA, PaB);
    CONV_LOAD(PbA, PbB, 1);
    CONV_BAR();

    for (int tt = 0; tt < NT; tt += 2) {
        if (tt + 2 < NT) CONV_LOAD(PaA, PaB, tt + 2);
        CONV_COMPUTE(0);
        CONV_WRITE(1, PbA, PbB);
        CONV_BAR();
        if (tt + 3 < NT) CONV_LOAD(PbA, PbB, tt + 3);
        CONV_COMPUTE(1);
        if (tt + 2 < NT) CONV_WRITE(0, PaA, PaB);
        CONV_BAR();
    }
#undef CONV_BAR
#undef CONV_TADDR
#undef CONV_LOAD
#undef CONV_WRITE
#undef CONV_COMPUTE

    const int q = l >> 4;
    const int m0 = pm0 + (w >> 1) * 32;
    const int n0 = bn0 + (w & 1) * 64;
    #pragma unroll
    for (int mi = 0; mi < 2; ++mi)
        #pragma unroll
        for (int ni = 0; ni < 4; ++ni) {
            const int co = n0 + ni * 16 + lr;
            const float bv = bias[co];
            #pragma unroll
            for (int r = 0; r < 4; ++r) {
                int p = m0 + mi * 16 + q * 4 + r;
                if (p < kNP)
                    out[(long)co * kNP + p] = acc[mi][ni][r] + bv;
            }
        }
}

// partial column sums of pf over n
__global__ __launch_bounds__(256)
void colmean_kernel(const float* __restrict__ pf, float* __restrict__ colpart)
{
    int s = blockIdx.x, ch = blockIdx.y, o = threadIdx.x;
    int n0 = ch * 128, n1 = n0 + 128 > kN ? kN : n0 + 128;
    float a = 0.f;
    for (int n = n0; n < n1; ++n) a += pf[((long)s * kN + n) * kCO + o];
    colpart[ch * kS * kCO + s * kCO + o] = a;
}

// attn stage 1
__global__ __launch_bounds__(384)
void attn_part1(const float* __restrict__ colpart, const float* __restrict__ w1,
                float* __restrict__ partial)
{
    __shared__ float cm[128];
    int b = blockIdx.x, t = threadIdx.x;
    int c0 = b * 128;
    if (t < 128) {
        float a = 0.f;
        #pragma unroll
        for (int ch = 0; ch < 11; ++ch) a += colpart[ch * kS * kCO + c0 + t];
        cm[t] = a * (1.f / kN);
    }
    __syncthreads();
    float acc = 0.f;
    #pragma unroll 4
    for (int c = 0; c < 128; ++c) acc += cm[c] * w1[(long)(c0 + c) * kHID + t];
    partial[b * kHID + t] = acc;
}

// attn stage 2
__global__ __launch_bounds__(384)
void attn_part2(const float* __restrict__ partial, const float* __restrict__ b1,
                const float* __restrict__ w2, const float* __restrict__ b2,
                const float* __restrict__ ss, float* __restrict__ wfin)
{
    __shared__ float h[kHID];
    __shared__ float logits[8];
    int t = threadIdx.x;
    float acc = b1[t];
    #pragma unroll
    for (int b = 0; b < 12; ++b) acc += partial[b * kHID + t];
    h[t] = fmaxf(acc, 0.f);
    __syncthreads();
    if (t < kS) {
        float lg = b2[t];
        for (int j = 0; j < kHID; ++j) lg += h[j] * w2[j * kS + t];
        logits[t] = lg;
    }
    __syncthreads();
    if (t == 0) {
        float w[kS], mx = -1e30f, sum = 0.f;
        for (int s = 0; s < kS; ++s) mx = fmaxf(mx, logits[s]);
        for (int s = 0; s < kS; ++s) { w[s] = expf(logits[s] - mx); sum += w[s]; }
        for (int s = 0; s < kS; ++s) w[s] /= sum;
        mx = -1e30f;
        for (int s = 0; s < kS; ++s) { w[s] *= ss[s]; mx = fmaxf(mx, w[s]); }
        sum = 0.f;
        float e[kS];
        for (int s = 0; s < kS; ++s) { e[s] = expf(w[s] - mx); sum += e[s]; }
        for (int s = 0; s < kS; ++s) wfin[s] = e[s] / sum;
    }
}

// fused = sum_s wfin[s]*pf[s]; writes f32 FORWARD only + bf16 fwd+rev
__global__ __launch_bounds__(256)
void fuse_kernel(const float* __restrict__ pf, const float* __restrict__ wfin,
                 float* __restrict__ fused, short* __restrict__ fusedb2)
{
    long idx = (long)blockIdx.x * 256 + threadIdx.x;
    if (idx >= (long)kN * kCO) return;
    float acc = 0.f;
    #pragma unroll
    for (int s = 0; s < kS; ++s) acc += wfin[s] * pf[(long)s * kN * kCO + idx];
    long n = idx / kCO; int c = (int)(idx % kCO);
    long ridx = (long)kN * kCO + (kN - 1 - n) * kCO + c;
    short bv = f2bf(acc);
    fused[idx] = acc;
    fusedb2[idx] = bv;
    fusedb2[ridx] = bv;
}

// causal depthwise conv (K=4) + silu; writes f32 z2 and bf16 z2b
__global__ __launch_bounds__(256)
void dwconv_kernel(const float* __restrict__ zg2,
                   const float* __restrict__ wf, const float* __restrict__ bf,
                   const float* __restrict__ wb, const float* __restrict__ bb,
                   float* __restrict__ z2, short* __restrict__ z2b)
{
    long idx = (long)blockIdx.x * 256 + threadIdx.x;
    int dir = blockIdx.y;
    if (idx >= (long)kN * kDI) return;
    long n = idx >> 9; int i = (int)(idx & (kDI - 1));
    const float* zg = zg2 + (long)dir * kN * 2 * kDI;
    const float* w  = dir ? wb : wf;
    const float* b  = dir ? bb : bf;
    float acc = b[i];
    #pragma unroll
    for (int k = 0; k < 4; ++k) {
        long m = n - 3 + k;
        if (m >= 0) acc += w[k * kDI + i] * zg[m * 2 * kDI + i];
    }
    float sg = 1.f / (1.f + expf(-acc));
    float v = acc * sg;
    z2 [(long)dir * kN * kDI + idx] = v;
    z2b[(long)dir * kN * kDI + idx] = f2bf(v);
}

// delta = softplus(xp[:,32+i] + xp[:,544])  -- once per (n,i)
__global__ __launch_bounds__(256)
void delta_kernel(const float* __restrict__ xp2, float* __restrict__ delta2)
{
    long idx = (long)blockIdx.x * 256 + threadIdx.x;
    int dir = blockIdx.y;
    if (idx >= (long)kN * kDI) return;
    long n = idx >> 9; int i = (int)(idx & (kDI - 1));
    const float* xp = xp2 + (long)dir * kXPS + n * kXPW;
    float x = xp[2 * kDS + i] + xp[kXPW - 1];
    float sp = fmaxf(x, 0.f) + log1pf(expf(-fabsf(x)));
    delta2[(long)dir * kN * kDI + idx] = sp;
}

// ---- chunk-parallel scan: pass A (depth-2 register prefetch) ---------------
__global__ __launch_bounds__(256)
void scan_partA(const float* __restrict__ delta2, const float* __restrict__ z2,
                const float* __restrict__ xp2,
                const float* __restrict__ Alogf, const float* __restrict__ Alogb,
                float* __restrict__ chunkP, float* __restrict__ chunkH)
{
    int bx = blockIdx.x;
    int c  = blockIdx.y;
    int dir = bx >> 5, iblk = bx & 31;
    int t = threadIdx.x;
    int s = t & 15, il = t >> 4;
    int i = iblk * 16 + il;
    int gid = dir * 8192 + iblk * 256 + t;
    const float* Alog = dir ? Alogb : Alogf;
    float A = expf(Alog[i * kDS + s]);
    int n0 = c * kCH, n1 = n0 + kCH; if (n1 > kN) n1 = kN;
    const int cnt = n1 - n0;
    const float* dp = delta2 + (long)dir * kN * kDI + (long)n0 * kDI + i;
    const float* zp = z2     + (long)dir * kN * kDI + (long)n0 * kDI + i;
    const float* xpp = xp2   + (long)dir * kXPS     + (long)n0 * kXPW;

    float d0 = *dp, v0 = *zp, b0 = xpp[s];
    dp += kDI; zp += kDI; xpp += kXPW;
    float d1 = 0.f, v1 = 0.f, b1 = 0.f;
    if (cnt > 1) { d1 = *dp; v1 = *zp; b1 = xpp[s]; }

    float h = 0.f, P = 1.f;
    for (int k = 0; k < cnt; ++k) {
        dp += kDI; zp += kDI; xpp += kXPW;   // now at k+2
        float d2 = 0.f, v2 = 0.f, b2 = 0.f;
        if (k + 2 < cnt) { d2 = *dp; v2 = *zp; b2 = xpp[s]; }
        float dA = __expf(-d0 * A);
        h = dA * h + d0 * b0 * v0;
        P *= dA;
        d0 = d1; v0 = v1; b0 = b1;
        d1 = d2; v1 = v2; b1 = b2;
    }
    chunkP[(long)c * 16384 + gid] = P;
    chunkH[(long)c * 16384 + gid] = h;
}

// ---- pass B (hin in-place; depth-2 prefetch) --------------------------------
__global__ __launch_bounds__(256)
void scan_partB(float* __restrict__ chunkP, const float* __restrict__ chunkH)
{
    int gid = blockIdx.x * 256 + threadIdx.x;
    float P0 = chunkP[gid];
    float Q0 = chunkH[gid];
    float P1 = chunkP[16384L + gid];
    float Q1 = chunkH[16384L + gid];
    float H = 0.f;
    for (int c = 0; c < kNC; ++c) {
        float P2 = 0.f, Q2 = 0.f;
        if (c + 2 < kNC) {
            P2 = chunkP[(long)(c + 2) * 16384 + gid];
            Q2 = chunkH[(long)(c + 2) * 16384 + gid];
        }
        chunkP[(long)c * 16384 + gid] = H;   // hin for chunk c
        H = P0 * H + Q0;
        P0 = P1; Q0 = Q1;
        P1 = P2; Q1 = Q2;
    }
}

// ---- pass C (depth-2 prefetch; gate-silu fused via __expf; bf16 ygb) -------
__global__ __launch_bounds__(256)
void scan_partC(const float* __restrict__ delta2, const float* __restrict__ z2,
                const float* __restrict__ xp2, const float* __restrict__ zg2,
                const float* __restrict__ Df, const float* __restrict__ Db,
                const float* __restrict__ Alogf, const float* __restrict__ Alogb,
                const float* __restrict__ hin, short* __restrict__ ygb)
{
    int bx = blockIdx.x;
    int c  = blockIdx.y;
    int dir = bx >> 5, iblk = bx & 31;
    int t = threadIdx.x;
    int s = t & 15, il = t >> 4;
    int i = iblk * 16 + il;
    int gid = dir * 8192 + iblk * 256 + t;
    const float* D    = dir ? Db : Df;
    const float* Alog = dir ? Alogb : Alogf;
    float A  = expf(Alog[i * kDS + s]);
    float Dv = D[i];
    int n0 = c * kCH, n1 = n0 + kCH; if (n1 > kN) n1 = kN;
    const int cnt = n1 - n0;
    const float* dp  = delta2 + (long)dir * kN * kDI + (long)n0 * kDI + i;
    const float* zp  = z2     + (long)dir * kN * kDI + (long)n0 * kDI + i;
    const float* xpp = xp2    + (long)dir * kXPS     + (long)n0 * kXPW;
    const float* gp  = zg2    + (long)dir * kN * 2 * kDI + (long)n0 * 2 * kDI + kDI + i;
    short* yp        = ygb    + (long)dir * kN * kDI + (long)n0 * kDI + i;

    float d0 = *dp, v0 = *zp, b0 = xpp[s], c0 = xpp[kDS + s];
    float g0 = 0.f; if (s == 0) g0 = *gp;
    dp += kDI; zp += kDI; xpp += kXPW; gp += 2 * kDI;
    float d1 = 0.f, v1 = 0.f, b1 = 0.f, c1 = 0.f, g1 = 0.f;
    if (cnt > 1) {
        d1 = *dp; v1 = *zp; b1 = xpp[s]; c1 = xpp[kDS + s];
        if (s == 0) g1 = *gp;
    }

    float h = hin[(long)c * 16384 + gid];
    for (int k = 0; k < cnt; ++k) {
        dp += kDI; zp += kDI; xpp += kXPW; gp += 2 * kDI;   // now at k+2
        float d2 = 0.f, v2 = 0.f, b2 = 0.f, c2 = 0.f, g2 = 0.f;
        if (k + 2 < cnt) {
            d2 = *dp; v2 = *zp; b2 = xpp[s]; c2 = xpp[kDS + s];
            if (s == 0) g2 = *gp;
        }
        float dA = __expf(-d0 * A);
        h = dA * h + d0 * b0 * v0;
        float cc = h * c0;
        cc += __shfl_xor(cc, 1, 16);
        cc += __shfl_xor(cc, 2, 16);
        cc += __shfl_xor(cc, 4, 16);
        cc += __shfl_xor(cc, 8, 16);
        if (s == 0) {
            float sgm = 1.f / (1.f + __expf(-g0));
            float v = (cc + Dv * v0) * g0 * sgm;
            *yp = f2bf(v);
        }
        yp += kDI;
        d0 = d1; v0 = v1; b0 = b1; c0 = c1; g0 = g1;
        d1 = d2; v1 = v2; b1 = b2; c1 = c2; g1 = g2;
    }
}

// r = gemm_out + x; layernorm; write bf16 cat. x read from FORWARD fused buf.
__global__ __launch_bounds__(256)
void resid_ln_cat_kernel(const float* __restrict__ gt2, const float* __restrict__ fused,
                         const float* __restrict__ gf, const float* __restrict__ betf,
                         const float* __restrict__ gb, const float* __restrict__ betb,
                         short* __restrict__ catb)
{
    int n = blockIdx.x, dir = blockIdx.y, t = threadIdx.x;
    const float* gt = gt2 + ((long)dir * kN + n) * kCO;
    int xrow = dir ? (kN - 1 - n) : n;
    const float* x  = fused + (long)xrow * kCO;
    const float* g  = dir ? gb : gf;
    const float* be = dir ? betb : betf;
    float r = gt[t] + x[t];
    float s1 = r, s2 = r * r;
    #pragma unroll
    for (int m = 32; m >= 1; m >>= 1) {
        s1 += __shfl_xor(s1, m, 64);
        s2 += __shfl_xor(s2, m, 64);
    }
    __shared__ float red[8];
    int w = t >> 6;
    if ((t & 63) == 0) { red[w] = s1; red[4 + w] = s2; }
    __syncthreads();
    float S1 = red[0] + red[1] + red[2] + red[3];
    float S2 = red[4] + red[5] + red[6] + red[7];
    float mu  = S1 * (1.f / kCO);
    float var = S2 * (1.f / kCO) - mu * mu;
    float inv = rsqrtf(var + 1e-5f);
    float v = g[t] * (r - mu) * inv + be[t];
    int row = dir ? (kN - 1 - n) : n;
    catb[(long)row * (2 * kCO) + dir * kCO + t] = f2bf(v);
}

// bilinear 4x upsample -> bf16 into padded (150,150,256) buffer, border zeros
__global__ __launch_bounds__(256)
void upsample_kernel(const float* __restrict__ merged, short* __restrict__ up)
{
    int p = blockIdx.x;               // 0..22499 over 150x150
    int y = p / 150, x = p - y * 150;
    int c = threadIdx.x;
    if (y == 0 || y == 149 || x == 0 || x == 149) {
        up[((long)y * 150 + x) * kCO + c] = 0;
        return;
    }
    int oy = y - 1, ox = x - 1;
    float sy = (oy + 0.5f) * ((float)kHP / (float)kOH) - 0.5f;
    float sx = (ox + 0.5f) * ((float)kWP / (float)kOW) - 0.5f;
    int iy0 = (int)floorf(sy); float fy = sy - (float)iy0;
    int ix0 = (int)floorf(sx); float fx = sx - (float)ix0;
    float wy0 = 1.f - fy, wy1 = fy, wx0 = 1.f - fx, wx1 = fx;
    int iy1 = iy0 + 1, ix1 = ix0 + 1;
    if (iy0 < 0)       { iy0 = 0;       wy0 = 0.f; }
    if (iy1 > kHP - 1) { iy1 = kHP - 1; wy1 = 0.f; }
    if (ix0 < 0)       { ix0 = 0;       wx0 = 0.f; }
    if (ix1 > kWP - 1) { ix1 = kWP - 1; wx1 = 0.f; }
    float wys = wy0 + wy1; wy0 /= wys; wy1 /= wys;
    float wxs = wx0 + wx1; wx0 /= wxs; wx1 /= wxs;
    const float* M00 = merged + (long)(iy0 * kWP + ix0) * kCO;
    const float* M01 = merged + (long)(iy0 * kWP + ix1) * kCO;
    const float* M10 = merged + (long)(iy1 * kWP + ix0) * kCO;
    const float* M11 = merged + (long)(iy1 * kWP + ix1) * kCO;
    float v = wy0 * (wx0 * M00[c] + wx1 * M01[c]) + wy1 * (wx0 * M10[c] + wx1 * M11[c]);
    up[((long)y * 150 + x) * kCO + c] = f2bf(v);
}

extern "C" void kernel_launch(void* const* d_in, const int* in_sizes, int n_in,
                              void* d_out, int out_size, void* d_ws, size_t ws_size,
                              hipStream_t stream)
{
    (void)in_sizes; (void)n_in; (void)out_size; (void)ws_size;
    const float* features  = (const float*)d_in[0];
    const float* proj_w    = (const float*)d_in[1];
    const float* attn_w1   = (const float*)d_in[2];
    const float* attn_b1   = (const float*)d_in[3];
    const float* attn_w2   = (const float*)d_in[4];
    const float* attn_b2   = (const float*)d_in[5];
    const float* src_scale = (const float*)d_in[6];
    const float* f_in_w    = (const float*)d_in[7];
    const float* f_conv_w  = (const float*)d_in[8];
    const float* f_conv_b  = (const float*)d_in[9];
    const float* f_xp_w    = (const float*)d_in[10];
    const float* f_Alog    = (const float*)d_in[11];
    const float* f_D       = (const float*)d_in[12];
    const float* f_out_w   = (const float*)d_in[13];
    const float* f_ln_g    = (const float*)d_in[14];
    const float* f_ln_b    = (const float*)d_in[15];
    const float* b_in_w    = (const float*)d_in[16];
    const float* b_conv_w  = (const float*)d_in[17];
    const float* b_conv_b  = (const float*)d_in[18];
    const float* b_xp_w    = (const float*)d_in[19];
    const float* b_Alog    = (const float*)d_in[20];
    const float* b_D       = (const float*)d_in[21];
    const float* b_out_w   = (const float*)d_in[22];
    const float* b_ln_g    = (const float*)d_in[23];
    const float* b_ln_b    = (const float*)d_in[24];
    const float* merge_w   = (const float*)d_in[25];
    const float* co1_w     = (const float*)d_in[26];
    const float* co1_b     = (const float*)d_in[27];

    float* ws      = (float*)d_ws;
    float* outp    = (float*)d_out;
    float* pf      = ws + OFF_PF;
    float* colpart = ws + OFF_COLPART;
    float* wfin    = ws + OFF_WFIN;
    float* attnp   = ws + OFF_ATTNP;
    float* fused   = ws + OFF_FUSED2;
    float* zg2     = ws + OFF_ZG;
    float* z2      = ws + OFF_Z;
    float* xp2     = ws + OFF_XP;
    float* delta2  = ws + OFF_DELTA;
    float* gt2     = ws + OFF_GT;
    float* merged  = ws + OFF_MERGED;
    float* chunkP  = ws + OFF_SCANP;
    float* chunkH  = ws + OFF_SCANH;
    short* featb   = (short*)(ws + OFF_FEATB);
    short* projwb  = (short*)(ws + OFF_PROJWB);
    short* in_wt   = (short*)(ws + OFF_INWT);
    short* xp_wt   = (short*)(ws + OFF_XPWT);
    short* out_wt  = (short*)(ws + OFF_OUTWT);
    short* mrg_wt  = (short*)(ws + OFF_MERGEWT);
    short* fusedb2 = (short*)(ws + OFF_FUSEDB);
    short* z2b     = (short*)(ws + OFF_Z2B);
    short* ygb     = (short*)(ws + OFF_YGB);
    short* catb    = (short*)(ws + OFF_CAT);
    short* upb     = (short*)(ws + OFF_UPB);
    short* wconvb  = (short*)(ws + OFF_WCONVB);

    // 0. bf16 casts for proj
    cast8_kernel<<<dim3(6161), 256, 0, stream>>>(features, featb, 1577088L);
    cast8_kernel<<<dim3(1152), 256, 0, stream>>>(proj_w, projwb, 294912L);
    // 1. pf[s] = feats[s] @ proj_w[s]^T
    proj_mfma_kernel<<<dim3(528), 256, 0, stream>>>(featb, projwb, pf);
    // 2. weight transposes
    transpose_cast_kernel<<<dim3(8, 32, 2), 256, 0, stream>>>(f_in_w, b_in_w, in_wt, 256, 1024);
    transpose_cast_kernel<<<dim3(16, 18, 2), 256, 0, stream>>>(f_xp_w, b_xp_w, xp_wt, 512, 545);
    transpose_cast_kernel<<<dim3(16, 8, 1), 256, 0, stream>>>(merge_w, merge_w, mrg_wt, 512, 256);
    // 3. column sums + attention weights
    colmean_kernel<<<dim3(6, 11), 256, 0, stream>>>(pf, colpart);
    attn_part1<<<dim3(12), 384, 0, stream>>>(colpart, attn_w1, attnp);
    attn_part2<<<1, 384, 0, stream>>>(attnp, attn_b1, attn_w2, attn_b2, src_scale, wfin);
    // 4. fuse sources (f32 forward + bf16 fwd+rev)
    fuse_kernel<<<dim3(1369), 256, 0, stream>>>(pf, wfin, fused, fusedb2);
    // 4b. out_w transpose
    transpose_cast_kernel<<<dim3(16, 8, 2), 256, 0, stream>>>(f_out_w, b_out_w, out_wt, 512, 256);
    // 5. zg = fused @ in_w
    mfma_nt<<<dim3(22, 16, 2), 256, 0, stream>>>(
        fusedb2, (long)kN * kCO, in_wt, (long)2 * kDI * kCO,
        zg2, (long)kN * 2 * kDI, kN, 2 * kDI, kCO);
    // 6. causal dwconv + silu
    dwconv_kernel<<<dim3(2738, 2), 256, 0, stream>>>(zg2, f_conv_w, f_conv_b,
                                                     b_conv_w, b_conv_b, z2, z2b);
    // 7. xp = z @ xp_w
    mfma_nt<<<dim3(22, 9, 2), 256, 0, stream>>>(
        z2b, (long)kN * kDI, xp_wt, (long)kXPW * kDI,
        xp2, kXPS, kN, kXPW, kDI);
    // 8. delta
    delta_kernel<<<dim3(2738, 2), 256, 0, stream>>>(xp2, delta2);
    // 9. chunk-parallel selective scan (48 chunks, depth-2 prefetch)
    scan_partA<<<dim3(64, kNC), 256, 0, stream>>>(delta2, z2, xp2, f_Alog, b_Alog,
                                                  chunkP, chunkH);
    scan_partB<<<dim3(64), 256, 0, stream>>>(chunkP, chunkH);
    scan_partC<<<dim3(64, kNC), 256, 0, stream>>>(delta2, z2, xp2, zg2, f_D, b_D,
                                                  f_Alog, b_Alog, chunkP, ygb);
    // 10. gt = yg @ out_w
    mfma_nt<<<dim3(22, 4, 2), 256, 0, stream>>>(
        ygb, (long)kN * kDI, out_wt, (long)kCO * kDI,
        gt2, (long)kN * kCO, kN, kCO, kDI);
    // 11. residual + LN + cat
    resid_ln_cat_kernel<<<dim3(1369, 2), 256, 0, stream>>>(gt2, fused, f_ln_g, f_ln_b,
                                                           b_ln_g, b_ln_b, catb);
    // 12. merged = cat @ merge_w
    mfma_nt<<<dim3(22, 4, 1), 256, 0, stream>>>(
        catb, 0, mrg_wt, 0,
        merged, 0, kN, kCO, 2 * kCO);
    // 13. conv weight -> bf16 transposed
    transpose_cast_kernel<<<dim3(72, 8, 1), 256, 0, stream>>>(co1_w, co1_w, wconvb, 2304, 256);
    // 14. bilinear upsample (border zeros fused)
    upsample_kernel<<<dim3(150 * 150), 256, 0, stream>>>(merged, upb);
    // 15. 3x3 conv (round-17 proven: LDS dbuf, depth-2 prefetch, lgkm barriers)
    conv_mfma_kernel<<<dim3(686), 256, 0, stream>>>(upb, wconvb, co1_b, outp);
}

// Round 20
// 279.956 us; speedup vs baseline: 1.1148x; 1.0080x over previous
//
#include <hip/hip_runtime.h>
#include <math.h>

// ---------------------------------------------------------------------------
// Upnet_v3 pipeline, round 20:
//  - proj: stages DIRECTLY from f32 (cvt fused into LDS write); both cast8
//    dispatches deleted (~75MB HBM). Geometry unchanged (64x64, 528 blocks,
//    s-grouped XCD swizzle -> feature-panel re-reads are L2 hits).
//  - all 5 weight transposes in ONE batched dispatch (job table); wconvb
//    relocated to the always-free ex-ybuf region so it can run up-front.
// ---------------------------------------------------------------------------

namespace {
constexpr int kS   = 6;
constexpr int kHP  = 37;
constexpr int kWP  = 37;
constexpr int kN   = 1369;      // HP*WP
constexpr int kCIN = 1536;
constexpr int kCO  = 256;
constexpr int kDS  = 16;
constexpr int kDI  = 512;
constexpr int kHID = 384;
constexpr int kOH  = 148;
constexpr int kOW  = 148;
constexpr int kNP  = kOH * kOW; // 21904
constexpr int kXPW = 545;       // 2*DS + DI + 1
constexpr long kXPS = 746112;   // padded kN*kXPW per dir
constexpr int kNC  = 48;        // scan chunks
constexpr int kCH  = 29;        // chunk length (48*29 = 1392 >= 1369)

// ---- workspace ledger (f32 units, total <= 13,911,040 = 55.6 MB) ----------
constexpr long OFF_PF      = 0;
constexpr long OFF_Z2B     = 0;
constexpr long OFF_YGB     = 0;
constexpr long OFF_UPB     = 0;
constexpr long OFF_SCANP   = 700928;    // chunkP 48*16384 (hin in-place)
constexpr long OFF_SCANH   = 1487360;   // chunkH (ends 2,273,792)
constexpr long OFF_COLPART = 2102784;
constexpr long OFF_WFIN    = 2119680;
constexpr long OFF_ATTNP   = 2119696;
constexpr long OFF_INWT    = 2200000;
constexpr long OFF_FUSEDB  = 2462144;
constexpr long OFF_ZG      = 2820624;
constexpr long OFF_Z       = 5760000;
constexpr long OFF_XP      = 7161856;
constexpr long OFF_DELTA   = 8654080;   // ends 10,055,936
constexpr long OFF_OUTWT   = 10055936;  // out_wt bf16 (ends 10,187,008)
constexpr long OFF_WCONVB  = 10500000;  // conv w^T bf16 294,912 f32 (ends 10,794,912; always-free region)
constexpr long OFF_GT      = 11457792;
constexpr long OFF_XPWT    = 11457792;
constexpr long OFF_FUSED2  = 12158720;  // f32 fused FORWARD only
constexpr long OFF_CAT     = 12859648;
constexpr long OFF_MERGEWT = 13210112;
constexpr long OFF_MERGED  = 13560576;
} // namespace

typedef __attribute__((ext_vector_type(8))) short bf16x8;
typedef __attribute__((ext_vector_type(4))) float f32x4;

__device__ __forceinline__ short f2bf(float x) {
    unsigned u = __builtin_bit_cast(unsigned, x);
    unsigned r = u + 0x7fffu + ((u >> 16) & 1u);
    return (short)(r >> 16);
}

__device__ __forceinline__ bf16x8 cvt8(float4 x, float4 y) {
    union { short s[8]; bf16x8 v; } u;
    u.s[0] = f2bf(x.x); u.s[1] = f2bf(x.y); u.s[2] = f2bf(x.z); u.s[3] = f2bf(x.w);
    u.s[4] = f2bf(y.x); u.s[5] = f2bf(y.y); u.s[6] = f2bf(y.z); u.s[7] = f2bf(y.w);
    return u.v;
}

// ---------------------------------------------------------------------------
// batched weight transpose+cast: 5 jobs in one dispatch (job table).
// job layout (block ranges):
//   [0,512)     in_wt   K=256  N=1024 tiles 8x32  dirs 2
//   [512,1088)  xp_wt   K=512  N=545  tiles 16x18 dirs 2
//   [1088,1216) mrg_wt  K=512  N=256  tiles 16x8  dir 0
//   [1216,1472) out_wt  K=512  N=256  tiles 16x8  dirs 2
//   [1472,2048) wconvb  K=2304 N=256  tiles 72x8  dir 0
// ---------------------------------------------------------------------------
__global__ __launch_bounds__(256)
void batched_transpose_kernel(
    const float* __restrict__ f_in_w, const float* __restrict__ b_in_w, short* __restrict__ in_wt,
    const float* __restrict__ f_xp_w, const float* __restrict__ b_xp_w, short* __restrict__ xp_wt,
    const float* __restrict__ merge_w, short* __restrict__ mrg_wt,
    const float* __restrict__ f_out_w, const float* __restrict__ b_out_w, short* __restrict__ out_wt,
    const float* __restrict__ co1_w, short* __restrict__ wconvb)
{
    const int bid = blockIdx.x;
    const float* w; short* o; int K, N, tk, tn;
    if (bid < 512) {
        int dir = bid >> 8, r = bid & 255;
        K = 256; N = 1024;
        w = dir ? b_in_w : f_in_w; o = in_wt + (long)dir * K * N;
        tk = r >> 5; tn = r & 31;
    } else if (bid < 1088) {
        int r = bid - 512; int dir = r / 288; r -= dir * 288;
        K = 512; N = 545;
        w = dir ? b_xp_w : f_xp_w; o = xp_wt + (long)dir * K * N;
        tk = r / 18; tn = r - tk * 18;
    } else if (bid < 1216) {
        int r = bid - 1088;
        K = 512; N = 256; w = merge_w; o = mrg_wt;
        tk = r >> 3; tn = r & 7;
    } else if (bid < 1472) {
        int r = bid - 1216; int dir = r >> 7; r &= 127;
        K = 512; N = 256;
        w = dir ? b_out_w : f_out_w; o = out_wt + (long)dir * K * N;
        tk = r >> 3; tn = r & 7;
    } else {
        int r = bid - 1472;
        K = 2304; N = 256; w = co1_w; o = wconvb;
        tk = r >> 3; tn = r & 7;
    }
    const int k0 = tk * 32, n0 = tn * 32;
    __shared__ float tile[32][33];
    const int tx = threadIdx.x & 31, ty = threadIdx.x >> 5; // 32 x 8
    #pragma unroll
    for (int r = 0; r < 32; r += 8) {
        int k = k0 + ty + r, n = n0 + tx;
        tile[ty + r][tx] = (k < K && n < N) ? w[(long)k * N + n] : 0.f;
    }
    __syncthreads();
    #pragma unroll
    for (int r = 0; r < 32; r += 8) {
        int n = n0 + ty + r, k = k0 + tx;
        if (n < N && k < K) o[(long)n * K + k] = f2bf(tile[tx][ty + r]);
    }
}

// ---------------------------------------------------------------------------
// generic bf16 MFMA GEMM, NT form, LDS dbuf, K-step 64 (unchanged)
// ---------------------------------------------------------------------------
__global__ __launch_bounds__(256)
void mfma_nt(const short* __restrict__ A, long sA,
             const short* __restrict__ B, long sB,
             float* __restrict__ C, long sC,
             int M, int N, int K)
{
    __shared__ short smem[2][8192];  // per buf bytes: A [0,8192), B [8192,16384)
    const int bz = blockIdx.z;
    const short* Ab = A + (long)bz * sA;
    const short* Bb = B + (long)bz * sB;
    float* Cb = C + (long)bz * sC;
    const int t = threadIdx.x, w = t >> 6, l = t & 63;
    const int lr = l & 15, sg = l >> 4;
    const int m0 = blockIdx.x * 64, n0 = blockIdx.y * 64;

    const int srow = t >> 3, qa = t & 7;   // 32 base rows x 8 k-segs
    long gA[2]; int woffA[2];
    #pragma unroll
    for (int j = 0; j < 2; ++j) {
        int ar = srow + j * 32;
        int am = m0 + ar; if (am >= M) am = M - 1;
        gA[j] = (long)am * K + qa * 8;
        woffA[j] = ar * 128 + ((qa ^ (ar & 7)) << 4);
    }
    long gB[2]; int woffB[2];
    #pragma unroll
    for (int j = 0; j < 2; ++j) {
        int br = srow + j * 32;
        int bn = n0 + br; if (bn >= N) bn = N - 1;
        gB[j] = (long)bn * K + qa * 8;
        woffB[j] = 8192 + br * 128 + ((qa ^ (br & 7)) << 4);
    }

    int aoff[2][2], boff[2][2];
    #pragma unroll
    for (int mi = 0; mi < 2; ++mi) {
        int r = (w >> 1) * 32 + mi * 16 + lr;
        #pragma unroll
        for (int kk = 0; kk < 2; ++kk)
            aoff[mi][kk] = r * 128 + (((kk * 4 + sg) ^ (r & 7)) << 4);
    }
    #pragma unroll
    for (int ni = 0; ni < 2; ++ni) {
        int r = (w & 1) * 32 + ni * 16 + lr;
        #pragma unroll
        for (int kk = 0; kk < 2; ++kk)
            boff[ni][kk] = 8192 + r * 128 + (((kk * 4 + sg) ^ (r & 7)) << 4);
    }

    f32x4 acc[2][2] = {};
    const int NT = K >> 6;
    {
        char* lb = (char*)&smem[0][0];
        #pragma unroll
        for (int j = 0; j < 2; ++j)
            *(bf16x8*)(lb + woffA[j]) = *(const bf16x8*)(Ab + gA[j]);
        #pragma unroll
        for (int j = 0; j < 2; ++j)
            *(bf16x8*)(lb + woffB[j]) = *(const bf16x8*)(Bb + gB[j]);
    }
    __syncthreads();
    for (int tt = 0; tt < NT; ++tt) {
        bf16x8 nsa[2], nsb[2];
        if (tt + 1 < NT) {
            long o = (long)(tt + 1) * 64;
            #pragma unroll
            for (int j = 0; j < 2; ++j) nsa[j] = *(const bf16x8*)(Ab + gA[j] + o);
            #pragma unroll
            for (int j = 0; j < 2; ++j) nsb[j] = *(const bf16x8*)(Bb + gB[j] + o);
        }
        char* lb = (char*)&smem[tt & 1][0];
        #pragma unroll
        for (int kk = 0; kk < 2; ++kk) {
            bf16x8 a[2], b[2];
            #pragma unroll
            for (int mi = 0; mi < 2; ++mi) a[mi] = *(const bf16x8*)(lb + aoff[mi][kk]);
            #pragma unroll
            for (int ni = 0; ni < 2; ++ni) b[ni] = *(const bf16x8*)(lb + boff[ni][kk]);
            #pragma unroll
            for (int mi = 0; mi < 2; ++mi)
                #pragma unroll
                for (int ni = 0; ni < 2; ++ni)
                    acc[mi][ni] = __builtin_amdgcn_mfma_f32_16x16x32_bf16(a[mi], b[ni], acc[mi][ni], 0, 0, 0);
        }
        if (tt + 1 < NT) {
            char* nb = (char*)&smem[(tt + 1) & 1][0];
            #pragma unroll
            for (int j = 0; j < 2; ++j) *(bf16x8*)(nb + woffA[j]) = nsa[j];
            #pragma unroll
            for (int j = 0; j < 2; ++j) *(bf16x8*)(nb + woffB[j]) = nsb[j];
        }
        __syncthreads();
    }
    const int q = l >> 4;
    const int wm0 = m0 + (w >> 1) * 32, wn0 = n0 + (w & 1) * 32;
    #pragma unroll
    for (int mi = 0; mi < 2; ++mi)
        #pragma unroll
        for (int ni = 0; ni < 2; ++ni)
            #pragma unroll
            for (int r = 0; r < 4; ++r) {
                int m = wm0 + mi * 16 + q * 4 + r;
                int n = wn0 + ni * 16 + lr;
                if (m < M && n < N)
                    Cb[(long)m * N + n] = acc[mi][ni][r];
            }
}

// ---------------------------------------------------------------------------
// proj MFMA: bf16 64x64 tile, K-step 64, s-grouped XCD swizzle; stages
// DIRECTLY from f32 (cvt fused into LDS write). cast8 passes deleted.
// ---------------------------------------------------------------------------
__global__ __launch_bounds__(256)
void proj_mfma_kernel(const float* __restrict__ Af, const float* __restrict__ Bf,
                      float* __restrict__ pf)
{
    __shared__ short smem[2][8192];
    const int bid = blockIdx.x;                     // 0..527
    const int slot = (bid & 7) * 66 + (bid >> 3);   // bijective, XCD-chunked
    const int s = slot / 88, rem = slot - s * 88;
    const int m0 = (rem >> 2) * 64, n0 = (rem & 3) * 64;
    const float* A = Af + (long)s * kN * kCIN;
    const float* B = Bf + (long)s * kCO * kCIN;
    float* C = pf + (long)s * kN * kCO;
    const int t = threadIdx.x, w = t >> 6, l = t & 63;
    const int lr = l & 15, sg = l >> 4;

    const int srow = t >> 3, qa = t & 7;
    long gA[2]; int woffA[2];
    #pragma unroll
    for (int j = 0; j < 2; ++j) {
        int ar = srow + j * 32;
        int am = m0 + ar; if (am >= kN) am = kN - 1;
        gA[j] = (long)am * kCIN + qa * 8;
        woffA[j] = ar * 128 + ((qa ^ (ar & 7)) << 4);
    }
    long gB[2]; int woffB[2];
    #pragma unroll
    for (int j = 0; j < 2; ++j) {
        int br = srow + j * 32;
        gB[j] = (long)(n0 + br) * kCIN + qa * 8;
        woffB[j] = 8192 + br * 128 + ((qa ^ (br & 7)) << 4);
    }

    int aoff[2][2], boff[2][2];
    #pragma unroll
    for (int mi = 0; mi < 2; ++mi) {
        int r = (w >> 1) * 32 + mi * 16 + lr;
        #pragma unroll
        for (int kk = 0; kk < 2; ++kk)
            aoff[mi][kk] = r * 128 + (((kk * 4 + sg) ^ (r & 7)) << 4);
    }
    #pragma unroll
    for (int ni = 0; ni < 2; ++ni) {
        int r = (w & 1) * 32 + ni * 16 + lr;
        #pragma unroll
        for (int kk = 0; kk < 2; ++kk)
            boff[ni][kk] = 8192 + r * 128 + (((kk * 4 + sg) ^ (r & 7)) << 4);
    }

    f32x4 acc[2][2] = {};
    const int NT = kCIN >> 6;  // 24
    {
        char* lb = (char*)&smem[0][0];
        #pragma unroll
        for (int j = 0; j < 2; ++j) {
            float4 x = *(const float4*)(A + gA[j]);
            float4 y = *(const float4*)(A + gA[j] + 4);
            *(bf16x8*)(lb + woffA[j]) = cvt8(x, y);
        }
        #pragma unroll
        for (int j = 0; j < 2; ++j) {
            float4 x = *(const float4*)(B + gB[j]);
            float4 y = *(const float4*)(B + gB[j] + 4);
            *(bf16x8*)(lb + woffB[j]) = cvt8(x, y);
        }
    }
    __syncthreads();
    for (int tt = 0; tt < NT; ++tt) {
        float4 na0[2], na1[2], nb0[2], nb1[2];
        if (tt + 1 < NT) {
            long o = (long)(tt + 1) * 64;
            #pragma unroll
            for (int j = 0; j < 2; ++j) {
                na0[j] = *(const float4*)(A + gA[j] + o);
                na1[j] = *(const float4*)(A + gA[j] + o + 4);
            }
            #pragma unroll
            for (int j = 0; j < 2; ++j) {
                nb0[j] = *(const float4*)(B + gB[j] + o);
                nb1[j] = *(const float4*)(B + gB[j] + o + 4);
            }
        }
        char* lb = (char*)&smem[tt & 1][0];
        #pragma unroll
        for (int kk = 0; kk < 2; ++kk) {
            bf16x8 a[2], b[2];
            #pragma unroll
            for (int mi = 0; mi < 2; ++mi) a[mi] = *(const bf16x8*)(lb + aoff[mi][kk]);
            #pragma unroll
            for (int ni = 0; ni < 2; ++ni) b[ni] = *(const bf16x8*)(lb + boff[ni][kk]);
            #pragma unroll
            for (int mi = 0; mi < 2; ++mi)
                #pragma unroll
                for (int ni = 0; ni < 2; ++ni)
                    acc[mi][ni] = __builtin_amdgcn_mfma_f32_16x16x32_bf16(a[mi], b[ni], acc[mi][ni], 0, 0, 0);
        }
        if (tt + 1 < NT) {
            char* nb = (char*)&smem[(tt + 1) & 1][0];
            #pragma unroll
            for (int j = 0; j < 2; ++j) *(bf16x8*)(nb + woffA[j]) = cvt8(na0[j], na1[j]);
            #pragma unroll
            for (int j = 0; j < 2; ++j) *(bf16x8*)(nb + woffB[j]) = cvt8(nb0[j], nb1[j]);
        }
        __syncthreads();
    }
    const int q = l >> 4;
    const int wm0 = m0 + (w >> 1) * 32, wn0 = n0 + (w & 1) * 32;
    #pragma unroll
    for (int mi = 0; mi < 2; ++mi)
        #pragma unroll
        for (int ni = 0; ni < 2; ++ni)
            #pragma unroll
            for (int r = 0; r < 4; ++r) {
                int m = wm0 + mi * 16 + q * 4 + r;
                if (m < kN)
                    C[(long)m * kCO + wn0 + ni * 16 + lr] = acc[mi][ni][r];
            }
}

// ---------------------------------------------------------------------------
// conv3x3 MFMA: 64px x 128co, K-step 64, depth-2 prefetch, lgkmcnt-only
// barriers, setprio, bijective XCD-chunked swizzle (round-17 proven version)
// ---------------------------------------------------------------------------
__global__ __launch_bounds__(256)
void conv_mfma_kernel(const short* __restrict__ up, const short* __restrict__ wt,
                      const float* __restrict__ bias, float* __restrict__ out)
{
    __shared__ short smem[2][12288];   // per buf: A bytes [0,8192), B [8192,24576)
    const int t = threadIdx.x, w = t >> 6, l = t & 63;
    const int lr = l & 15, sg = l >> 4;
    // bijective XCD-chunked swizzle: nwg=686, q=85, r=6
    const int bid = blockIdx.x;
    const int xcd = bid & 7, slot = bid >> 3;
    const int wgid = (xcd < 6 ? xcd * 86 : 6 * 86 + (xcd - 6) * 85) + slot;
    const int pm0 = (wgid >> 1) * 64;
    const int bn0 = (wgid & 1) * 128;

    const int srow = t >> 3, qa = t & 7;
    long gA[2]; int woffA[2];
    #pragma unroll
    for (int j = 0; j < 2; ++j) {
        int ar = srow + j * 32;
        int p = pm0 + ar; if (p >= kNP) p = kNP - 1;
        int oy = p / kOW, ox = p - oy * kOW;
        gA[j] = ((long)oy * 150 + ox) * kCO + qa * 8;
        woffA[j] = ar * 128 + ((qa ^ (ar & 7)) << 4);
    }
    long gB[4]; int woffB[4];
    #pragma unroll
    for (int j = 0; j < 4; ++j) {
        int br = srow + j * 32;
        gB[j] = (long)(bn0 + br) * 2304 + qa * 8;
        woffB[j] = 8192 + br * 128 + ((qa ^ (br & 7)) << 4);
    }

    int aoff[2][2], boff[4][2];
    #pragma unroll
    for (int mi = 0; mi < 2; ++mi) {
        int r = (w >> 1) * 32 + mi * 16 + lr;
        #pragma unroll
        for (int kk = 0; kk < 2; ++kk)
            aoff[mi][kk] = r * 128 + (((kk * 4 + sg) ^ (r & 7)) << 4);
    }
    #pragma unroll
    for (int ni = 0; ni < 4; ++ni) {
        int r = (w & 1) * 64 + ni * 16 + lr;
        #pragma unroll
        for (int kk = 0; kk < 2; ++kk)
            boff[ni][kk] = 8192 + r * 128 + (((kk * 4 + sg) ^ (r & 7)) << 4);
    }

    f32x4 acc[2][4] = {};
    const int NT = 36;

#define CONV_BAR() { \
        asm volatile("s_waitcnt lgkmcnt(0)" ::: "memory"); \
        __builtin_amdgcn_sched_barrier(0); \
        __builtin_amdgcn_s_barrier(); }

#define CONV_TADDR(tn, ta, tb) { \
        int _tap = (tn) >> 2, _c0 = ((tn) & 3) << 6; \
        int _ky = _tap / 3, _kx = _tap - _ky * 3; \
        ta = ((long)_ky * 150 + _kx) * kCO + _c0; \
        tb = (long)(tn) * 64; }

#define CONV_LOAD(Pa_, Pb_, tn) { \
        long _ta, _tb; CONV_TADDR(tn, _ta, _tb); \
        _Pragma("unroll") \
        for (int j = 0; j < 2; ++j) Pa_[j] = *(const bf16x8*)(up + gA[j] + _ta); \
        _Pragma("unroll") \
        for (int j = 0; j < 4; ++j) Pb_[j] = *(const bf16x8*)(wt + gB[j] + _tb); }

#define CONV_WRITE(buf, Pa_, Pb_) { \
        char* _nb = (char*)&smem[buf][0]; \
        _Pragma("unroll") \
        for (int j = 0; j < 2; ++j) *(bf16x8*)(_nb + woffA[j]) = Pa_[j]; \
        _Pragma("unroll") \
        for (int j = 0; j < 4; ++j) *(bf16x8*)(_nb + woffB[j]) = Pb_[j]; }

#define CONV_COMPUTE(buf) { \
        char* _lb = (char*)&smem[buf][0]; \
        _Pragma("unroll") \
        for (int kk = 0; kk < 2; ++kk) { \
            bf16x8 _a[2], _b[4]; \
            _Pragma("unroll") \
            for (int mi = 0; mi < 2; ++mi) _a[mi] = *(const bf16x8*)(_lb + aoff[mi][kk]); \
            _Pragma("unroll") \
            for (int ni = 0; ni < 4; ++ni) _b[ni] = *(const bf16x8*)(_lb + boff[ni][kk]); \
            __builtin_amdgcn_s_setprio(1); \
            _Pragma("unroll") \
            for (int mi = 0; mi < 2; ++mi) \
                _Pragma("unroll") \
                for (int ni = 0; ni < 4; ++ni) \
                    acc[mi][ni] = __builtin_amdgcn_mfma_f32_16x16x32_bf16(_a[mi], _b[ni], acc[mi][ni], 0, 0, 0); \
            __builtin_amdgcn_s_setprio(0); \
        } }

    bf16x8 PaA[2], PaB[4];
    bf16x8 PbA[2], PbB[4];

    CONV_LOAD(PaA, PaB, 0);
    CONV_WRITE(0, PaA, PaB);
    CONV_LOAD(PbA, PbB, 1);
    CONV_BAR();

    for (int tt = 0; tt < NT; tt += 2) {
        if (tt + 2 < NT) CONV_LOAD(PaA, PaB, tt + 2);
        CONV_COMPUTE(0);
        CONV_WRITE(1, PbA, PbB);
        CONV_BAR();
        if (tt + 3 < NT) CONV_LOAD(PbA, PbB, tt + 3);
        CONV_COMPUTE(1);
        if (tt + 2 < NT) CONV_WRITE(0, PaA, PaB);
        CONV_BAR();
    }
#undef CONV_BAR
#undef CONV_TADDR
#undef CONV_LOAD
#undef CONV_WRITE
#undef CONV_COMPUTE

    const int q = l >> 4;
    const int m0 = pm0 + (w >> 1) * 32;
    const int n0 = bn0 + (w & 1) * 64;
    #pragma unroll
    for (int mi = 0; mi < 2; ++mi)
        #pragma unroll
        for (int ni = 0; ni < 4; ++ni) {
            const int co = n0 + ni * 16 + lr;
            const float bv = bias[co];
            #pragma unroll
            for (int r = 0; r < 4; ++r) {
                int p = m0 + mi * 16 + q * 4 + r;
                if (p < kNP)
                    out[(long)co * kNP + p] = acc[mi][ni][r] + bv;
            }
        }
}

// partial column sums of pf over n
__global__ __launch_bounds__(256)
void colmean_kernel(const float* __restrict__ pf, float* __restrict__ colpart)
{
    int s = blockIdx.x, ch = blockIdx.y, o = threadIdx.x;
    int n0 = ch * 128, n1 = n0 + 128 > kN ? kN : n0 + 128;
    float a = 0.f;
    for (int n = n0; n < n1; ++n) a += pf[((long)s * kN + n) * kCO + o];
    colpart[ch * kS * kCO + s * kCO + o] = a;
}

// attn stage 1
__global__ __launch_bounds__(384)
void attn_part1(const float* __restrict__ colpart, const float* __restrict__ w1,
                float* __restrict__ partial)
{
    __shared__ float cm[128];
    int b = blockIdx.x, t = threadIdx.x;
    int c0 = b * 128;
    if (t < 128) {
        float a = 0.f;
        #pragma unroll
        for (int ch = 0; ch < 11; ++ch) a += colpart[ch * kS * kCO + c0 + t];
        cm[t] = a * (1.f / kN);
    }
    __syncthreads();
    float acc = 0.f;
    #pragma unroll 4
    for (int c = 0; c < 128; ++c) acc += cm[c] * w1[(long)(c0 + c) * kHID + t];
    partial[b * kHID + t] = acc;
}

// attn stage 2
__global__ __launch_bounds__(384)
void attn_part2(const float* __restrict__ partial, const float* __restrict__ b1,
                const float* __restrict__ w2, const float* __restrict__ b2,
                const float* __restrict__ ss, float* __restrict__ wfin)
{
    __shared__ float h[kHID];
    __shared__ float logits[8];
    int t = threadIdx.x;
    float acc = b1[t];
    #pragma unroll
    for (int b = 0; b < 12; ++b) acc += partial[b * kHID + t];
    h[t] = fmaxf(acc, 0.f);
    __syncthreads();
    if (t < kS) {
        float lg = b2[t];
        for (int j = 0; j < kHID; ++j) lg += h[j] * w2[j * kS + t];
        logits[t] = lg;
    }
    __syncthreads();
    if (t == 0) {
        float w[kS], mx = -1e30f, sum = 0.f;
        for (int s = 0; s < kS; ++s) mx = fmaxf(mx, logits[s]);
        for (int s = 0; s < kS; ++s) { w[s] = expf(logits[s] - mx); sum += w[s]; }
        for (int s = 0; s < kS; ++s) w[s] /= sum;
        mx = -1e30f;
        for (int s = 0; s < kS; ++s) { w[s] *= ss[s]; mx = fmaxf(mx, w[s]); }
        sum = 0.f;
        float e[kS];
        for (int s = 0; s < kS; ++s) { e[s] = expf(w[s] - mx); sum += e[s]; }
        for (int s = 0; s < kS; ++s) wfin[s] = e[s] / sum;
    }
}

// fused = sum_s wfin[s]*pf[s]; writes f32 FORWARD only + bf16 fwd+rev
__global__ __launch_bounds__(256)
void fuse_kernel(const float* __restrict__ pf, const float* __restrict__ wfin,
                 float* __restrict__ fused, short* __restrict__ fusedb2)
{
    long idx = (long)blockIdx.x * 256 + threadIdx.x;
    if (idx >= (long)kN * kCO) return;
    float acc = 0.f;
    #pragma unroll
    for (int s = 0; s < kS; ++s) acc += wfin[s] * pf[(long)s * kN * kCO + idx];
    long n = idx / kCO; int c = (int)(idx % kCO);
    long ridx = (long)kN * kCO + (kN - 1 - n) * kCO + c;
    short bv = f2bf(acc);
    fused[idx] = acc;
    fusedb2[idx] = bv;
    fusedb2[ridx] = bv;
}

// causal depthwise conv (K=4) + silu; writes f32 z2 and bf16 z2b
__global__ __launch_bounds__(256)
void dwconv_kernel(const float* __restrict__ zg2,
                   const float* __restrict__ wf, const float* __restrict__ bf,
                   const float* __restrict__ wb, const float* __restrict__ bb,
                   float* __restrict__ z2, short* __restrict__ z2b)
{
    long idx = (long)blockIdx.x * 256 + threadIdx.x;
    int dir = blockIdx.y;
    if (idx >= (long)kN * kDI) return;
    long n = idx >> 9; int i = (int)(idx & (kDI - 1));
    const float* zg = zg2 + (long)dir * kN * 2 * kDI;
    const float* w  = dir ? wb : wf;
    const float* b  = dir ? bb : bf;
    float acc = b[i];
    #pragma unroll
    for (int k = 0; k < 4; ++k) {
        long m = n - 3 + k;
        if (m >= 0) acc += w[k * kDI + i] * zg[m * 2 * kDI + i];
    }
    float sg = 1.f / (1.f + expf(-acc));
    float v = acc * sg;
    z2 [(long)dir * kN * kDI + idx] = v;
    z2b[(long)dir * kN * kDI + idx] = f2bf(v);
}

// delta = softplus(xp[:,32+i] + xp[:,544])  -- once per (n,i)
__global__ __launch_bounds__(256)
void delta_kernel(const float* __restrict__ xp2, float* __restrict__ delta2)
{
    long idx = (long)blockIdx.x * 256 + threadIdx.x;
    int dir = blockIdx.y;
    if (idx >= (long)kN * kDI) return;
    long n = idx >> 9; int i = (int)(idx & (kDI - 1));
    const float* xp = xp2 + (long)dir * kXPS + n * kXPW;
    float x = xp[2 * kDS + i] + xp[kXPW - 1];
    float sp = fmaxf(x, 0.f) + log1pf(expf(-fabsf(x)));
    delta2[(long)dir * kN * kDI + idx] = sp;
}

// ---- chunk-parallel scan: pass A (depth-2 register prefetch) ---------------
__global__ __launch_bounds__(256)
void scan_partA(const float* __restrict__ delta2, const float* __restrict__ z2,
                const float* __restrict__ xp2,
                const float* __restrict__ Alogf, const float* __restrict__ Alogb,
                float* __restrict__ chunkP, float* __restrict__ chunkH)
{
    int bx = blockIdx.x;
    int c  = blockIdx.y;
    int dir = bx >> 5, iblk = bx & 31;
    int t = threadIdx.x;
    int s = t & 15, il = t >> 4;
    int i = iblk * 16 + il;
    int gid = dir * 8192 + iblk * 256 + t;
    const float* Alog = dir ? Alogb : Alogf;
    float A = expf(Alog[i * kDS + s]);
    int n0 = c * kCH, n1 = n0 + kCH; if (n1 > kN) n1 = kN;
    const int cnt = n1 - n0;
    const float* dp = delta2 + (long)dir * kN * kDI + (long)n0 * kDI + i;
    const float* zp = z2     + (long)dir * kN * kDI + (long)n0 * kDI + i;
    const float* xpp = xp2   + (long)dir * kXPS     + (long)n0 * kXPW;

    float d0 = *dp, v0 = *zp, b0 = xpp[s];
    dp += kDI; zp += kDI; xpp += kXPW;
    float d1 = 0.f, v1 = 0.f, b1 = 0.f;
    if (cnt > 1) { d1 = *dp; v1 = *zp; b1 = xpp[s]; }

    float h = 0.f, P = 1.f;
    for (int k = 0; k < cnt; ++k) {
        dp += kDI; zp += kDI; xpp += kXPW;   // now at k+2
        float d2 = 0.f, v2 = 0.f, b2 = 0.f;
        if (k + 2 < cnt) { d2 = *dp; v2 = *zp; b2 = xpp[s]; }
        float dA = __expf(-d0 * A);
        h = dA * h + d0 * b0 * v0;
        P *= dA;
        d0 = d1; v0 = v1; b0 = b1;
        d1 = d2; v1 = v2; b1 = b2;
    }
    chunkP[(long)c * 16384 + gid] = P;
    chunkH[(long)c * 16384 + gid] = h;
}

// ---- pass B (hin in-place; depth-2 prefetch) --------------------------------
__global__ __launch_bounds__(256)
void scan_partB(float* __restrict__ chunkP, const float* __restrict__ chunkH)
{
    int gid = blockIdx.x * 256 + threadIdx.x;
    float P0 = chunkP[gid];
    float Q0 = chunkH[gid];
    float P1 = chunkP[16384L + gid];
    float Q1 = chunkH[16384L + gid];
    float H = 0.f;
    for (int c = 0; c < kNC; ++c) {
        float P2 = 0.f, Q2 = 0.f;
        if (c + 2 < kNC) {
            P2 = chunkP[(long)(c + 2) * 16384 + gid];
            Q2 = chunkH[(long)(c + 2) * 16384 + gid];
        }
        chunkP[(long)c * 16384 + gid] = H;   // hin for chunk c
        H = P0 * H + Q0;
        P0 = P1; Q0 = Q1;
        P1 = P2; Q1 = Q2;
    }
}

// ---- pass C (depth-2 prefetch; gate-silu fused via __expf; bf16 ygb) -------
__global__ __launch_bounds__(256)
void scan_partC(const float* __restrict__ delta2, const float* __restrict__ z2,
                const float* __restrict__ xp2, const float* __restrict__ zg2,
                const float* __restrict__ Df, const float* __restrict__ Db,
                const float* __restrict__ Alogf, const float* __restrict__ Alogb,
                const float* __restrict__ hin, short* __restrict__ ygb)
{
    int bx = blockIdx.x;
    int c  = blockIdx.y;
    int dir = bx >> 5, iblk = bx & 31;
    int t = threadIdx.x;
    int s = t & 15, il = t >> 4;
    int i = iblk * 16 + il;
    int gid = dir * 8192 + iblk * 256 + t;
    const float* D    = dir ? Db : Df;
    const float* Alog = dir ? Alogb : Alogf;
    float A  = expf(Alog[i * kDS + s]);
    float Dv = D[i];
    int n0 = c * kCH, n1 = n0 + kCH; if (n1 > kN) n1 = kN;
    const int cnt = n1 - n0;
    const float* dp  = delta2 + (long)dir * kN * kDI + (long)n0 * kDI + i;
    const float* zp  = z2     + (long)dir * kN * kDI + (long)n0 * kDI + i;
    const float* xpp = xp2    + (long)dir * kXPS     + (long)n0 * kXPW;
    const float* gp  = zg2    + (long)dir * kN * 2 * kDI + (long)n0 * 2 * kDI + kDI + i;
    short* yp        = ygb    + (long)dir * kN * kDI + (long)n0 * kDI + i;

    float d0 = *dp, v0 = *zp, b0 = xpp[s], c0 = xpp[kDS + s];
    float g0 = 0.f; if (s == 0) g0 = *gp;
    dp += kDI; zp += kDI; xpp += kXPW; gp += 2 * kDI;
    float d1 = 0.f, v1 = 0.f, b1 = 0.f, c1 = 0.f, g1 = 0.f;
    if (cnt > 1) {
        d1 = *dp; v1 = *zp; b1 = xpp[s]; c1 = xpp[kDS + s];
        if (s == 0) g1 = *gp;
    }

    float h = hin[(long)c * 16384 + gid];
    for (int k = 0; k < cnt; ++k) {
        dp += kDI; zp += kDI; xpp += kXPW; gp += 2 * kDI;   // now at k+2
        float d2 = 0.f, v2 = 0.f, b2 = 0.f, c2 = 0.f, g2 = 0.f;
        if (k + 2 < cnt) {
            d2 = *dp; v2 = *zp; b2 = xpp[s]; c2 = xpp[kDS + s];
            if (s == 0) g2 = *gp;
        }
        float dA = __expf(-d0 * A);
        h = dA * h + d0 * b0 * v0;
        float cc = h * c0;
        cc += __shfl_xor(cc, 1, 16);
        cc += __shfl_xor(cc, 2, 16);
        cc += __shfl_xor(cc, 4, 16);
        cc += __shfl_xor(cc, 8, 16);
        if (s == 0) {
            float sgm = 1.f / (1.f + __expf(-g0));
            float v = (cc + Dv * v0) * g0 * sgm;
            *yp = f2bf(v);
        }
        yp += kDI;
        d0 = d1; v0 = v1; b0 = b1; c0 = c1; g0 = g1;
        d1 = d2; v1 = v2; b1 = b2; c1 = c2; g1 = g2;
    }
}

// r = gemm_out + x; layernorm; write bf16 cat. x read from FORWARD fused buf.
__global__ __launch_bounds__(256)
void resid_ln_cat_kernel(const float* __restrict__ gt2, const float* __restrict__ fused,
                         const float* __restrict__ gf, const float* __restrict__ betf,
                         const float* __restrict__ gb, const float* __restrict__ betb,
                         short* __restrict__ catb)
{
    int n = blockIdx.x, dir = blockIdx.y, t = threadIdx.x;
    const float* gt = gt2 + ((long)dir * kN + n) * kCO;
    int xrow = dir ? (kN - 1 - n) : n;
    const float* x  = fused + (long)xrow * kCO;
    const float* g  = dir ? gb : gf;
    const float* be = dir ? betb : betf;
    float r = gt[t] + x[t];
    float s1 = r, s2 = r * r;
    #pragma unroll
    for (int m = 32; m >= 1; m >>= 1) {
        s1 += __shfl_xor(s1, m, 64);
        s2 += __shfl_xor(s2, m, 64);
    }
    __shared__ float red[8];
    int w = t >> 6;
    if ((t & 63) == 0) { red[w] = s1; red[4 + w] = s2; }
    __syncthreads();
    float S1 = red[0] + red[1] + red[2] + red[3];
    float S2 = red[4] + red[5] + red[6] + red[7];
    float mu  = S1 * (1.f / kCO);
    float var = S2 * (1.f / kCO) - mu * mu;
    float inv = rsqrtf(var + 1e-5f);
    float v = g[t] * (r - mu) * inv + be[t];
    int row = dir ? (kN - 1 - n) : n;
    catb[(long)row * (2 * kCO) + dir * kCO + t] = f2bf(v);
}

// bilinear 4x upsample -> bf16 into padded (150,150,256) buffer, border zeros
__global__ __launch_bounds__(256)
void upsample_kernel(const float* __restrict__ merged, short* __restrict__ up)
{
    int p = blockIdx.x;               // 0..22499 over 150x150
    int y = p / 150, x = p - y * 150;
    int c = threadIdx.x;
    if (y == 0 || y == 149 || x == 0 || x == 149) {
        up[((long)y * 150 + x) * kCO + c] = 0;
        return;
    }
    int oy = y - 1, ox = x - 1;
    float sy = (oy + 0.5f) * ((float)kHP / (float)kOH) - 0.5f;
    float sx = (ox + 0.5f) * ((float)kWP / (float)kOW) - 0.5f;
    int iy0 = (int)floorf(sy); float fy = sy - (float)iy0;
    int ix0 = (int)floorf(sx); float fx = sx - (float)ix0;
    float wy0 = 1.f - fy, wy1 = fy, wx0 = 1.f - fx, wx1 = fx;
    int iy1 = iy0 + 1, ix1 = ix0 + 1;
    if (iy0 < 0)       { iy0 = 0;       wy0 = 0.f; }
    if (iy1 > kHP - 1) { iy1 = kHP - 1; wy1 = 0.f; }
    if (ix0 < 0)       { ix0 = 0;       wx0 = 0.f; }
    if (ix1 > kWP - 1) { ix1 = kWP - 1; wx1 = 0.f; }
    float wys = wy0 + wy1; wy0 /= wys; wy1 /= wys;
    float wxs = wx0 + wx1; wx0 /= wxs; wx1 /= wxs;
    const float* M00 = merged + (long)(iy0 * kWP + ix0) * kCO;
    const float* M01 = merged + (long)(iy0 * kWP + ix1) * kCO;
    const float* M10 = merged + (long)(iy1 * kWP + ix0) * kCO;
    const float* M11 = merged + (long)(iy1 * kWP + ix1) * kCO;
    float v = wy0 * (wx0 * M00[c] + wx1 * M01[c]) + wy1 * (wx0 * M10[c] + wx1 * M11[c]);
    up[((long)y * 150 + x) * kCO + c] = f2bf(v);
}

extern "C" void kernel_launch(void* const* d_in, const int* in_sizes, int n_in,
                              void* d_out, int out_size, void* d_ws, size_t ws_size,
                              hipStream_t stream)
{
    (void)in_sizes; (void)n_in; (void)out_size; (void)ws_size;
    const float* features  = (const float*)d_in[0];
    const float* proj_w    = (const float*)d_in[1];
    const float* attn_w1   = (const float*)d_in[2];
    const float* attn_b1   = (const float*)d_in[3];
    const float* attn_w2   = (const float*)d_in[4];
    const float* attn_b2   = (const float*)d_in[5];
    const float* src_scale = (const float*)d_in[6];
    const float* f_in_w    = (const float*)d_in[7];
    const float* f_conv_w  = (const float*)d_in[8];
    const float* f_conv_b  = (const float*)d_in[9];
    const float* f_xp_w    = (const float*)d_in[10];
    const float* f_Alog    = (const float*)d_in[11];
    const float* f_D       = (const float*)d_in[12];
    const float* f_out_w   = (const float*)d_in[13];
    const float* f_ln_g    = (const float*)d_in[14];
    const float* f_ln_b    = (const float*)d_in[15];
    const float* b_in_w    = (const float*)d_in[16];
    const float* b_conv_w  = (const float*)d_in[17];
    const float* b_conv_b  = (const float*)d_in[18];
    const float* b_xp_w    = (const float*)d_in[19];
    const float* b_Alog    = (const float*)d_in[20];
    const float* b_D       = (const float*)d_in[21];
    const float* b_out_w   = (const float*)d_in[22];
    const float* b_ln_g    = (const float*)d_in[23];
    const float* b_ln_b    = (const float*)d_in[24];
    const float* merge_w   = (const float*)d_in[25];
    const float* co1_w     = (const float*)d_in[26];
    const float* co1_b     = (const float*)d_in[27];

    float* ws      = (float*)d_ws;
    float* outp    = (float*)d_out;
    float* pf      = ws + OFF_PF;
    float* colpart = ws + OFF_COLPART;
    float* wfin    = ws + OFF_WFIN;
    float* attnp   = ws + OFF_ATTNP;
    float* fused   = ws + OFF_FUSED2;
    float* zg2     = ws + OFF_ZG;
    float* z2      = ws + OFF_Z;
    float* xp2     = ws + OFF_XP;
    float* delta2  = ws + OFF_DELTA;
    float* gt2     = ws + OFF_GT;
    float* merged  = ws + OFF_MERGED;
    float* chunkP  = ws + OFF_SCANP;
    float* chunkH  = ws + OFF_SCANH;
    short* in_wt   = (short*)(ws + OFF_INWT);
    short* xp_wt   = (short*)(ws + OFF_XPWT);
    short* out_wt  = (short*)(ws + OFF_OUTWT);
    short* mrg_wt  = (short*)(ws + OFF_MERGEWT);
    short* fusedb2 = (short*)(ws + OFF_FUSEDB);
    short* z2b     = (short*)(ws + OFF_Z2B);
    short* ygb     = (short*)(ws + OFF_YGB);
    short* catb    = (short*)(ws + OFF_CAT);
    short* upb     = (short*)(ws + OFF_UPB);
    short* wconvb  = (short*)(ws + OFF_WCONVB);

    // 1. ALL weight transposes in one dispatch (incl. conv wt, now in free region)
    batched_transpose_kernel<<<dim3(2048), 256, 0, stream>>>(
        f_in_w, b_in_w, in_wt, f_xp_w, b_xp_w, xp_wt,
        merge_w, mrg_wt, f_out_w, b_out_w, out_wt, co1_w, wconvb);
    // 2. pf[s] = feats[s] @ proj_w[s]^T  (f32-direct staging, cvt fused)
    proj_mfma_kernel<<<dim3(528), 256, 0, stream>>>(features, proj_w, pf);
    // 3. column sums + attention weights
    colmean_kernel<<<dim3(6, 11), 256, 0, stream>>>(pf, colpart);
    attn_part1<<<dim3(12), 384, 0, stream>>>(colpart, attn_w1, attnp);
    attn_part2<<<1, 384, 0, stream>>>(attnp, attn_b1, attn_w2, attn_b2, src_scale, wfin);
    // 4. fuse sources (f32 forward + bf16 fwd+rev)
    fuse_kernel<<<dim3(1369), 256, 0, stream>>>(pf, wfin, fused, fusedb2);
    // 5. zg = fused @ in_w
    mfma_nt<<<dim3(22, 16, 2), 256, 0, stream>>>(
        fusedb2, (long)kN * kCO, in_wt, (long)2 * kDI * kCO,
        zg2, (long)kN * 2 * kDI, kN, 2 * kDI, kCO);
    // 6. causal dwconv + silu
    dwconv_kernel<<<dim3(2738, 2), 256, 0, stream>>>(zg2, f_conv_w, f_conv_b,
                                                     b_conv_w, b_conv_b, z2, z2b);
    // 7. xp = z @ xp_w
    mfma_nt<<<dim3(22, 9, 2), 256, 0, stream>>>(
        z2b, (long)kN * kDI, xp_wt, (long)kXPW * kDI,
        xp2, kXPS, kN, kXPW, kDI);
    // 8. delta
    delta_kernel<<<dim3(2738, 2), 256, 0, stream>>>(xp2, delta2);
    // 9. chunk-parallel selective scan (48 chunks, depth-2 prefetch)
    scan_partA<<<dim3(64, kNC), 256, 0, stream>>>(delta2, z2, xp2, f_Alog, b_Alog,
                                                  chunkP, chunkH);
    scan_partB<<<dim3(64), 256, 0, stream>>>(chunkP, chunkH);
    scan_partC<<<dim3(64, kNC), 256, 0, stream>>>(delta2, z2, xp2, zg2, f_D, b_D,
                                                  f_Alog, b_Alog, chunkP, ygb);
    // 10. gt = yg @ out_w
    mfma_nt<<<dim3(22, 4, 2), 256, 0, stream>>>(
        ygb, (long)kN * kDI, out_wt, (long)kCO * kDI,
        gt2, (long)kN * kCO, kN, kCO, kDI);
    // 11. residual + LN + cat
    resid_ln_cat_kernel<<<dim3(1369, 2), 256, 0, stream>>>(gt2, fused, f_ln_g, f_ln_b,
                                                           b_ln_g, b_ln_b, catb);
    // 12. merged = cat @ merge_w
    mfma_nt<<<dim3(22, 4, 1), 256, 0, stream>>>(
        catb, 0, mrg_wt, 0,
        merged, 0, kN, kCO, 2 * kCO);
    // 13. bilinear upsample (border zeros fused)
    upsample_kernel<<<dim3(150 * 150), 256, 0, stream>>>(merged, upb);
    // 14. 3x3 conv (round-17 proven: LDS dbuf, depth-2 prefetch, lgkm barriers)
    conv_mfma_kernel<<<dim3(686), 256, 0, stream>>>(upb, wconvb, co1_b, outp);
}

// Round 21
// 265.230 us; speedup vs baseline: 1.1767x; 1.0555x over previous
//
#include <hip/hip_runtime.h>
#include <math.h>

// ---------------------------------------------------------------------------
// Upnet_v3 pipeline, round 21:
//  - proj: conv-proven schedule ported -- depth-2 f32 prefetch (loads for
//    step t+2 before step t's MFMAs; cvt+LDS-write of t+1 after), lgkm-only
//    barriers, setprio. Geometry unchanged (64x64, 528 blocks, XCD swizzle).
//  - everything else unchanged from round 20 (279.96us baseline).
// ---------------------------------------------------------------------------

namespace {
constexpr int kS   = 6;
constexpr int kHP  = 37;
constexpr int kWP  = 37;
constexpr int kN   = 1369;      // HP*WP
constexpr int kCIN = 1536;
constexpr int kCO  = 256;
constexpr int kDS  = 16;
constexpr int kDI  = 512;
constexpr int kHID = 384;
constexpr int kOH  = 148;
constexpr int kOW  = 148;
constexpr int kNP  = kOH * kOW; // 21904
constexpr int kXPW = 545;       // 2*DS + DI + 1
constexpr long kXPS = 746112;   // padded kN*kXPW per dir
constexpr int kNC  = 48;        // scan chunks
constexpr int kCH  = 29;        // chunk length (48*29 = 1392 >= 1369)

// ---- workspace ledger (f32 units, total <= 13,911,040 = 55.6 MB) ----------
constexpr long OFF_PF      = 0;
constexpr long OFF_Z2B     = 0;
constexpr long OFF_YGB     = 0;
constexpr long OFF_UPB     = 0;
constexpr long OFF_SCANP   = 700928;    // chunkP 48*16384 (hin in-place)
constexpr long OFF_SCANH   = 1487360;   // chunkH (ends 2,273,792)
constexpr long OFF_COLPART = 2102784;
constexpr long OFF_WFIN    = 2119680;
constexpr long OFF_ATTNP   = 2119696;
constexpr long OFF_INWT    = 2200000;
constexpr long OFF_FUSEDB  = 2462144;
constexpr long OFF_ZG      = 2820624;
constexpr long OFF_Z       = 5760000;
constexpr long OFF_XP      = 7161856;
constexpr long OFF_DELTA   = 8654080;   // ends 10,055,936
constexpr long OFF_OUTWT   = 10055936;  // out_wt bf16
constexpr long OFF_WCONVB  = 10500000;  // conv w^T bf16 (always-free region)
constexpr long OFF_GT      = 11457792;
constexpr long OFF_XPWT    = 11457792;
constexpr long OFF_FUSED2  = 12158720;  // f32 fused FORWARD only
constexpr long OFF_CAT     = 12859648;
constexpr long OFF_MERGEWT = 13210112;
constexpr long OFF_MERGED  = 13560576;
} // namespace

typedef __attribute__((ext_vector_type(8))) short bf16x8;
typedef __attribute__((ext_vector_type(4))) float f32x4;

__device__ __forceinline__ short f2bf(float x) {
    unsigned u = __builtin_bit_cast(unsigned, x);
    unsigned r = u + 0x7fffu + ((u >> 16) & 1u);
    return (short)(r >> 16);
}

__device__ __forceinline__ bf16x8 cvt8(float4 x, float4 y) {
    union { short s[8]; bf16x8 v; } u;
    u.s[0] = f2bf(x.x); u.s[1] = f2bf(x.y); u.s[2] = f2bf(x.z); u.s[3] = f2bf(x.w);
    u.s[4] = f2bf(y.x); u.s[5] = f2bf(y.y); u.s[6] = f2bf(y.z); u.s[7] = f2bf(y.w);
    return u.v;
}

// ---------------------------------------------------------------------------
// batched weight transpose+cast: 5 jobs in one dispatch (job table).
// ---------------------------------------------------------------------------
__global__ __launch_bounds__(256)
void batched_transpose_kernel(
    const float* __restrict__ f_in_w, const float* __restrict__ b_in_w, short* __restrict__ in_wt,
    const float* __restrict__ f_xp_w, const float* __restrict__ b_xp_w, short* __restrict__ xp_wt,
    const float* __restrict__ merge_w, short* __restrict__ mrg_wt,
    const float* __restrict__ f_out_w, const float* __restrict__ b_out_w, short* __restrict__ out_wt,
    const float* __restrict__ co1_w, short* __restrict__ wconvb)
{
    const int bid = blockIdx.x;
    const float* w; short* o; int K, N, tk, tn;
    if (bid < 512) {
        int dir = bid >> 8, r = bid & 255;
        K = 256; N = 1024;
        w = dir ? b_in_w : f_in_w; o = in_wt + (long)dir * K * N;
        tk = r >> 5; tn = r & 31;
    } else if (bid < 1088) {
        int r = bid - 512; int dir = r / 288; r -= dir * 288;
        K = 512; N = 545;
        w = dir ? b_xp_w : f_xp_w; o = xp_wt + (long)dir * K * N;
        tk = r / 18; tn = r - tk * 18;
    } else if (bid < 1216) {
        int r = bid - 1088;
        K = 512; N = 256; w = merge_w; o = mrg_wt;
        tk = r >> 3; tn = r & 7;
    } else if (bid < 1472) {
        int r = bid - 1216; int dir = r >> 7; r &= 127;
        K = 512; N = 256;
        w = dir ? b_out_w : f_out_w; o = out_wt + (long)dir * K * N;
        tk = r >> 3; tn = r & 7;
    } else {
        int r = bid - 1472;
        K = 2304; N = 256; w = co1_w; o = wconvb;
        tk = r >> 3; tn = r & 7;
    }
    const int k0 = tk * 32, n0 = tn * 32;
    __shared__ float tile[32][33];
    const int tx = threadIdx.x & 31, ty = threadIdx.x >> 5; // 32 x 8
    #pragma unroll
    for (int r = 0; r < 32; r += 8) {
        int k = k0 + ty + r, n = n0 + tx;
        tile[ty + r][tx] = (k < K && n < N) ? w[(long)k * N + n] : 0.f;
    }
    __syncthreads();
    #pragma unroll
    for (int r = 0; r < 32; r += 8) {
        int n = n0 + ty + r, k = k0 + tx;
        if (n < N && k < K) o[(long)n * K + k] = f2bf(tile[tx][ty + r]);
    }
}

// ---------------------------------------------------------------------------
// generic bf16 MFMA GEMM, NT form, LDS dbuf, K-step 64 (unchanged)
// ---------------------------------------------------------------------------
__global__ __launch_bounds__(256)
void mfma_nt(const short* __restrict__ A, long sA,
             const short* __restrict__ B, long sB,
             float* __restrict__ C, long sC,
             int M, int N, int K)
{
    __shared__ short smem[2][8192];  // per buf bytes: A [0,8192), B [8192,16384)
    const int bz = blockIdx.z;
    const short* Ab = A + (long)bz * sA;
    const short* Bb = B + (long)bz * sB;
    float* Cb = C + (long)bz * sC;
    const int t = threadIdx.x, w = t >> 6, l = t & 63;
    const int lr = l & 15, sg = l >> 4;
    const int m0 = blockIdx.x * 64, n0 = blockIdx.y * 64;

    const int srow = t >> 3, qa = t & 7;   // 32 base rows x 8 k-segs
    long gA[2]; int woffA[2];
    #pragma unroll
    for (int j = 0; j < 2; ++j) {
        int ar = srow + j * 32;
        int am = m0 + ar; if (am >= M) am = M - 1;
        gA[j] = (long)am * K + qa * 8;
        woffA[j] = ar * 128 + ((qa ^ (ar & 7)) << 4);
    }
    long gB[2]; int woffB[2];
    #pragma unroll
    for (int j = 0; j < 2; ++j) {
        int br = srow + j * 32;
        int bn = n0 + br; if (bn >= N) bn = N - 1;
        gB[j] = (long)bn * K + qa * 8;
        woffB[j] = 8192 + br * 128 + ((qa ^ (br & 7)) << 4);
    }

    int aoff[2][2], boff[2][2];
    #pragma unroll
    for (int mi = 0; mi < 2; ++mi) {
        int r = (w >> 1) * 32 + mi * 16 + lr;
        #pragma unroll
        for (int kk = 0; kk < 2; ++kk)
            aoff[mi][kk] = r * 128 + (((kk * 4 + sg) ^ (r & 7)) << 4);
    }
    #pragma unroll
    for (int ni = 0; ni < 2; ++ni) {
        int r = (w & 1) * 32 + ni * 16 + lr;
        #pragma unroll
        for (int kk = 0; kk < 2; ++kk)
            boff[ni][kk] = 8192 + r * 128 + (((kk * 4 + sg) ^ (r & 7)) << 4);
    }

    f32x4 acc[2][2] = {};
    const int NT = K >> 6;
    {
        char* lb = (char*)&smem[0][0];
        #pragma unroll
        for (int j = 0; j < 2; ++j)
            *(bf16x8*)(lb + woffA[j]) = *(const bf16x8*)(Ab + gA[j]);
        #pragma unroll
        for (int j = 0; j < 2; ++j)
            *(bf16x8*)(lb + woffB[j]) = *(const bf16x8*)(Bb + gB[j]);
    }
    __syncthreads();
    for (int tt = 0; tt < NT; ++tt) {
        bf16x8 nsa[2], nsb[2];
        if (tt + 1 < NT) {
            long o = (long)(tt + 1) * 64;
            #pragma unroll
            for (int j = 0; j < 2; ++j) nsa[j] = *(const bf16x8*)(Ab + gA[j] + o);
            #pragma unroll
            for (int j = 0; j < 2; ++j) nsb[j] = *(const bf16x8*)(Bb + gB[j] + o);
        }
        char* lb = (char*)&smem[tt & 1][0];
        #pragma unroll
        for (int kk = 0; kk < 2; ++kk) {
            bf16x8 a[2], b[2];
            #pragma unroll
            for (int mi = 0; mi < 2; ++mi) a[mi] = *(const bf16x8*)(lb + aoff[mi][kk]);
            #pragma unroll
            for (int ni = 0; ni < 2; ++ni) b[ni] = *(const bf16x8*)(lb + boff[ni][kk]);
            #pragma unroll
            for (int mi = 0; mi < 2; ++mi)
                #pragma unroll
                for (int ni = 0; ni < 2; ++ni)
                    acc[mi][ni] = __builtin_amdgcn_mfma_f32_16x16x32_bf16(a[mi], b[ni], acc[mi][ni], 0, 0, 0);
        }
        if (tt + 1 < NT) {
            char* nb = (char*)&smem[(tt + 1) & 1][0];
            #pragma unroll
            for (int j = 0; j < 2; ++j) *(bf16x8*)(nb + woffA[j]) = nsa[j];
            #pragma unroll
            for (int j = 0; j < 2; ++j) *(bf16x8*)(nb + woffB[j]) = nsb[j];
        }
        __syncthreads();
    }
    const int q = l >> 4;
    const int wm0 = m0 + (w >> 1) * 32, wn0 = n0 + (w & 1) * 32;
    #pragma unroll
    for (int mi = 0; mi < 2; ++mi)
        #pragma unroll
        for (int ni = 0; ni < 2; ++ni)
            #pragma unroll
            for (int r = 0; r < 4; ++r) {
                int m = wm0 + mi * 16 + q * 4 + r;
                int n = wn0 + ni * 16 + lr;
                if (m < M && n < N)
                    Cb[(long)m * N + n] = acc[mi][ni][r];
            }
}

// ---------------------------------------------------------------------------
// proj MFMA: 64x64, K-step 64, XCD swizzle; f32-direct staging with DEPTH-2
// prefetch + lgkm-only barriers + setprio (conv-proven schedule).
// ---------------------------------------------------------------------------
__global__ __launch_bounds__(256)
void proj_mfma_kernel(const float* __restrict__ Af, const float* __restrict__ Bf,
                      float* __restrict__ pf)
{
    __shared__ short smem[2][8192];
    const int bid = blockIdx.x;                     // 0..527
    const int slot = (bid & 7) * 66 + (bid >> 3);   // bijective, XCD-chunked
    const int s = slot / 88, rem = slot - s * 88;
    const int m0 = (rem >> 2) * 64, n0 = (rem & 3) * 64;
    const float* A = Af + (long)s * kN * kCIN;
    const float* B = Bf + (long)s * kCO * kCIN;
    float* C = pf + (long)s * kN * kCO;
    const int t = threadIdx.x, w = t >> 6, l = t & 63;
    const int lr = l & 15, sg = l >> 4;

    const int srow = t >> 3, qa = t & 7;
    long gA[2]; int woffA[2];
    #pragma unroll
    for (int j = 0; j < 2; ++j) {
        int ar = srow + j * 32;
        int am = m0 + ar; if (am >= kN) am = kN - 1;
        gA[j] = (long)am * kCIN + qa * 8;
        woffA[j] = ar * 128 + ((qa ^ (ar & 7)) << 4);
    }
    long gB[2]; int woffB[2];
    #pragma unroll
    for (int j = 0; j < 2; ++j) {
        int br = srow + j * 32;
        gB[j] = (long)(n0 + br) * kCIN + qa * 8;
        woffB[j] = 8192 + br * 128 + ((qa ^ (br & 7)) << 4);
    }

    int aoff[2][2], boff[2][2];
    #pragma unroll
    for (int mi = 0; mi < 2; ++mi) {
        int r = (w >> 1) * 32 + mi * 16 + lr;
        #pragma unroll
        for (int kk = 0; kk < 2; ++kk)
            aoff[mi][kk] = r * 128 + (((kk * 4 + sg) ^ (r & 7)) << 4);
    }
    #pragma unroll
    for (int ni = 0; ni < 2; ++ni) {
        int r = (w & 1) * 32 + ni * 16 + lr;
        #pragma unroll
        for (int kk = 0; kk < 2; ++kk)
            boff[ni][kk] = 8192 + r * 128 + (((kk * 4 + sg) ^ (r & 7)) << 4);
    }

    f32x4 acc[2][2] = {};
    const int NT = kCIN >> 6;  // 24 (even)

#define PROJ_BAR() { \
        asm volatile("s_waitcnt lgkmcnt(0)" ::: "memory"); \
        __builtin_amdgcn_sched_barrier(0); \
        __builtin_amdgcn_s_barrier(); }

#define PROJ_LOAD(Sa0_, Sa1_, Sb0_, Sb1_, tn) { \
        long _o = (long)(tn) * 64; \
        _Pragma("unroll") \
        for (int j = 0; j < 2; ++j) { \
            Sa0_[j] = *(const float4*)(A + gA[j] + _o); \
            Sa1_[j] = *(const float4*)(A + gA[j] + _o + 4); \
        } \
        _Pragma("unroll") \
        for (int j = 0; j < 2; ++j) { \
            Sb0_[j] = *(const float4*)(B + gB[j] + _o); \
            Sb1_[j] = *(const float4*)(B + gB[j] + _o + 4); \
        } }

#define PROJ_WRITE(buf, Sa0_, Sa1_, Sb0_, Sb1_) { \
        char* _nb = (char*)&smem[buf][0]; \
        _Pragma("unroll") \
        for (int j = 0; j < 2; ++j) *(bf16x8*)(_nb + woffA[j]) = cvt8(Sa0_[j], Sa1_[j]); \
        _Pragma("unroll") \
        for (int j = 0; j < 2; ++j) *(bf16x8*)(_nb + woffB[j]) = cvt8(Sb0_[j], Sb1_[j]); }

#define PROJ_COMPUTE(buf) { \
        char* _lb = (char*)&smem[buf][0]; \
        _Pragma("unroll") \
        for (int kk = 0; kk < 2; ++kk) { \
            bf16x8 _a[2], _b[2]; \
            _Pragma("unroll") \
            for (int mi = 0; mi < 2; ++mi) _a[mi] = *(const bf16x8*)(_lb + aoff[mi][kk]); \
            _Pragma("unroll") \
            for (int ni = 0; ni < 2; ++ni) _b[ni] = *(const bf16x8*)(_lb + boff[ni][kk]); \
            __builtin_amdgcn_s_setprio(1); \
            _Pragma("unroll") \
            for (int mi = 0; mi < 2; ++mi) \
                _Pragma("unroll") \
                for (int ni = 0; ni < 2; ++ni) \
                    acc[mi][ni] = __builtin_amdgcn_mfma_f32_16x16x32_bf16(_a[mi], _b[ni], acc[mi][ni], 0, 0, 0); \
            __builtin_amdgcn_s_setprio(0); \
        } }

    float4 SaA0[2], SaA1[2], SaB0[2], SaB1[2];   // reg set A
    float4 SbA0[2], SbA1[2], SbB0[2], SbB1[2];   // reg set B

    // prologue: tile0 -> LDS0 (via Sa), issue tile1 -> Sb
    PROJ_LOAD(SaA0, SaA1, SaB0, SaB1, 0);
    PROJ_WRITE(0, SaA0, SaA1, SaB0, SaB1);
    PROJ_LOAD(SbA0, SbA1, SbB0, SbB1, 1);
    PROJ_BAR();

    for (int tt = 0; tt < NT; tt += 2) {
        if (tt + 2 < NT) PROJ_LOAD(SaA0, SaA1, SaB0, SaB1, tt + 2);
        PROJ_COMPUTE(0);
        PROJ_WRITE(1, SbA0, SbA1, SbB0, SbB1);
        PROJ_BAR();
        if (tt + 3 < NT) PROJ_LOAD(SbA0, SbA1, SbB0, SbB1, tt + 3);
        PROJ_COMPUTE(1);
        if (tt + 2 < NT) PROJ_WRITE(0, SaA0, SaA1, SaB0, SaB1);
        PROJ_BAR();
    }
#undef PROJ_BAR
#undef PROJ_LOAD
#undef PROJ_WRITE
#undef PROJ_COMPUTE

    const int q = l >> 4;
    const int wm0 = m0 + (w >> 1) * 32, wn0 = n0 + (w & 1) * 32;
    #pragma unroll
    for (int mi = 0; mi < 2; ++mi)
        #pragma unroll
        for (int ni = 0; ni < 2; ++ni)
            #pragma unroll
            for (int r = 0; r < 4; ++r) {
                int m = wm0 + mi * 16 + q * 4 + r;
                if (m < kN)
                    C[(long)m * kCO + wn0 + ni * 16 + lr] = acc[mi][ni][r];
            }
}

// ---------------------------------------------------------------------------
// conv3x3 MFMA: 64px x 128co, K-step 64, depth-2 prefetch, lgkmcnt-only
// barriers, setprio, bijective XCD-chunked swizzle (round-17 proven version)
// ---------------------------------------------------------------------------
__global__ __launch_bounds__(256)
void conv_mfma_kernel(const short* __restrict__ up, const short* __restrict__ wt,
                      const float* __restrict__ bias, float* __restrict__ out)
{
    __shared__ short smem[2][12288];   // per buf: A bytes [0,8192), B [8192,24576)
    const int t = threadIdx.x, w = t >> 6, l = t & 63;
    const int lr = l & 15, sg = l >> 4;
    // bijective XCD-chunked swizzle: nwg=686, q=85, r=6
    const int bid = blockIdx.x;
    const int xcd = bid & 7, slot = bid >> 3;
    const int wgid = (xcd < 6 ? xcd * 86 : 6 * 86 + (xcd - 6) * 85) + slot;
    const int pm0 = (wgid >> 1) * 64;
    const int bn0 = (wgid & 1) * 128;

    const int srow = t >> 3, qa = t & 7;
    long gA[2]; int woffA[2];
    #pragma unroll
    for (int j = 0; j < 2; ++j) {
        int ar = srow + j * 32;
        int p = pm0 + ar; if (p >= kNP) p = kNP - 1;
        int oy = p / kOW, ox = p - oy * kOW;
        gA[j] = ((long)oy * 150 + ox) * kCO + qa * 8;
        woffA[j] = ar * 128 + ((qa ^ (ar & 7)) << 4);
    }
    long gB[4]; int woffB[4];
    #pragma unroll
    for (int j = 0; j < 4; ++j) {
        int br = srow + j * 32;
        gB[j] = (long)(bn0 + br) * 2304 + qa * 8;
        woffB[j] = 8192 + br * 128 + ((qa ^ (br & 7)) << 4);
    }

    int aoff[2][2], boff[4][2];
    #pragma unroll
    for (int mi = 0; mi < 2; ++mi) {
        int r = (w >> 1) * 32 + mi * 16 + lr;
        #pragma unroll
        for (int kk = 0; kk < 2; ++kk)
            aoff[mi][kk] = r * 128 + (((kk * 4 + sg) ^ (r & 7)) << 4);
    }
    #pragma unroll
    for (int ni = 0; ni < 4; ++ni) {
        int r = (w & 1) * 64 + ni * 16 + lr;
        #pragma unroll
        for (int kk = 0; kk < 2; ++kk)
            boff[ni][kk] = 8192 + r * 128 + (((kk * 4 + sg) ^ (r & 7)) << 4);
    }

    f32x4 acc[2][4] = {};
    const int NT = 36;

#define CONV_BAR() { \
        asm volatile("s_waitcnt lgkmcnt(0)" ::: "memory"); \
        __builtin_amdgcn_sched_barrier(0); \
        __builtin_amdgcn_s_barrier(); }

#define CONV_TADDR(tn, ta, tb) { \
        int _tap = (tn) >> 2, _c0 = ((tn) & 3) << 6; \
        int _ky = _tap / 3, _kx = _tap - _ky * 3; \
        ta = ((long)_ky * 150 + _kx) * kCO + _c0; \
        tb = (long)(tn) * 64; }

#define CONV_LOAD(Pa_, Pb_, tn) { \
        long _ta, _tb; CONV_TADDR(tn, _ta, _tb); \
        _Pragma("unroll") \
        for (int j = 0; j < 2; ++j) Pa_[j] = *(const bf16x8*)(up + gA[j] + _ta); \
        _Pragma("unroll") \
        for (int j = 0; j < 4; ++j) Pb_[j] = *(const bf16x8*)(wt + gB[j] + _tb); }

#define CONV_WRITE(buf, Pa_, Pb_) { \
        char* _nb = (char*)&smem[buf][0]; \
        _Pragma("unroll") \
        for (int j = 0; j < 2; ++j) *(bf16x8*)(_nb + woffA[j]) = Pa_[j]; \
        _Pragma("unroll") \
        for (int j = 0; j < 4; ++j) *(bf16x8*)(_nb + woffB[j]) = Pb_[j]; }

#define CONV_COMPUTE(buf) { \
        char* _lb = (char*)&smem[buf][0]; \
        _Pragma("unroll") \
        for (int kk = 0; kk < 2; ++kk) { \
            bf16x8 _a[2], _b[4]; \
            _Pragma("unroll") \
            for (int mi = 0; mi < 2; ++mi) _a[mi] = *(const bf16x8*)(_lb + aoff[mi][kk]); \
            _Pragma("unroll") \
            for (int ni = 0; ni < 4; ++ni) _b[ni] = *(const bf16x8*)(_lb + boff[ni][kk]); \
            __builtin_amdgcn_s_setprio(1); \
            _Pragma("unroll") \
            for (int mi = 0; mi < 2; ++mi) \
                _Pragma("unroll") \
                for (int ni = 0; ni < 4; ++ni) \
                    acc[mi][ni] = __builtin_amdgcn_mfma_f32_16x16x32_bf16(_a[mi], _b[ni], acc[mi][ni], 0, 0, 0); \
            __builtin_amdgcn_s_setprio(0); \
        } }

    bf16x8 PaA[2], PaB[4];
    bf16x8 PbA[2], PbB[4];

    CONV_LOAD(PaA, PaB, 0);
    CONV_WRITE(0, PaA, PaB);
    CONV_LOAD(PbA, PbB, 1);
    CONV_BAR();

    for (int tt = 0; tt < NT; tt += 2) {
        if (tt + 2 < NT) CONV_LOAD(PaA, PaB, tt + 2);
        CONV_COMPUTE(0);
        CONV_WRITE(1, PbA, PbB);
        CONV_BAR();
        if (tt + 3 < NT) CONV_LOAD(PbA, PbB, tt + 3);
        CONV_COMPUTE(1);
        if (tt + 2 < NT) CONV_WRITE(0, PaA, PaB);
        CONV_BAR();
    }
#undef CONV_BAR
#undef CONV_TADDR
#undef CONV_LOAD
#undef CONV_WRITE
#undef CONV_COMPUTE

    const int q = l >> 4;
    const int m0 = pm0 + (w >> 1) * 32;
    const int n0 = bn0 + (w & 1) * 64;
    #pragma unroll
    for (int mi = 0; mi < 2; ++mi)
        #pragma unroll
        for (int ni = 0; ni < 4; ++ni) {
            const int co = n0 + ni * 16 + lr;
            const float bv = bias[co];
            #pragma unroll
            for (int r = 0; r < 4; ++r) {
                int p = m0 + mi * 16 + q * 4 + r;
                if (p < kNP)
                    out[(long)co * kNP + p] = acc[mi][ni][r] + bv;
            }
        }
}

// partial column sums of pf over n
__global__ __launch_bounds__(256)
void colmean_kernel(const float* __restrict__ pf, float* __restrict__ colpart)
{
    int s = blockIdx.x, ch = blockIdx.y, o = threadIdx.x;
    int n0 = ch * 128, n1 = n0 + 128 > kN ? kN : n0 + 128;
    float a = 0.f;
    for (int n = n0; n < n1; ++n) a += pf[((long)s * kN + n) * kCO + o];
    colpart[ch * kS * kCO + s * kCO + o] = a;
}

// attn stage 1
__global__ __launch_bounds__(384)
void attn_part1(const float* __restrict__ colpart, const float* __restrict__ w1,
                float* __restrict__ partial)
{
    __shared__ float cm[128];
    int b = blockIdx.x, t = threadIdx.x;
    int c0 = b * 128;
    if (t < 128) {
        float a = 0.f;
        #pragma unroll
        for (int ch = 0; ch < 11; ++ch) a += colpart[ch * kS * kCO + c0 + t];
        cm[t] = a * (1.f / kN);
    }
    __syncthreads();
    float acc = 0.f;
    #pragma unroll 4
    for (int c = 0; c < 128; ++c) acc += cm[c] * w1[(long)(c0 + c) * kHID + t];
    partial[b * kHID + t] = acc;
}

// attn stage 2
__global__ __launch_bounds__(384)
void attn_part2(const float* __restrict__ partial, const float* __restrict__ b1,
                const float* __restrict__ w2, const float* __restrict__ b2,
                const float* __restrict__ ss, float* __restrict__ wfin)
{
    __shared__ float h[kHID];
    __shared__ float logits[8];
    int t = threadIdx.x;
    float acc = b1[t];
    #pragma unroll
    for (int b = 0; b < 12; ++b) acc += partial[b * kHID + t];
    h[t] = fmaxf(acc, 0.f);
    __syncthreads();
    if (t < kS) {
        float lg = b2[t];
        for (int j = 0; j < kHID; ++j) lg += h[j] * w2[j * kS + t];
        logits[t] = lg;
    }
    __syncthreads();
    if (t == 0) {
        float w[kS], mx = -1e30f, sum = 0.f;
        for (int s = 0; s < kS; ++s) mx = fmaxf(mx, logits[s]);
        for (int s = 0; s < kS; ++s) { w[s] = expf(logits[s] - mx); sum += w[s]; }
        for (int s = 0; s < kS; ++s) w[s] /= sum;
        mx = -1e30f;
        for (int s = 0; s < kS; ++s) { w[s] *= ss[s]; mx = fmaxf(mx, w[s]); }
        sum = 0.f;
        float e[kS];
        for (int s = 0; s < kS; ++s) { e[s] = expf(w[s] - mx); sum += e[s]; }
        for (int s = 0; s < kS; ++s) wfin[s] = e[s] / sum;
    }
}

// fused = sum_s wfin[s]*pf[s]; writes f32 FORWARD only + bf16 fwd+rev
__global__ __launch_bounds__(256)
void fuse_kernel(const float* __restrict__ pf, const float* __restrict__ wfin,
                 float* __restrict__ fused, short* __restrict__ fusedb2)
{
    long idx = (long)blockIdx.x * 256 + threadIdx.x;
    if (idx >= (long)kN * kCO) return;
    float acc = 0.f;
    #pragma unroll
    for (int s = 0; s < kS; ++s) acc += wfin[s] * pf[(long)s * kN * kCO + idx];
    long n = idx / kCO; int c = (int)(idx % kCO);
    long ridx = (long)kN * kCO + (kN - 1 - n) * kCO + c;
    short bv = f2bf(acc);
    fused[idx] = acc;
    fusedb2[idx] = bv;
    fusedb2[ridx] = bv;
}

// causal depthwise conv (K=4) + silu; writes f32 z2 and bf16 z2b
__global__ __launch_bounds__(256)
void dwconv_kernel(const float* __restrict__ zg2,
                   const float* __restrict__ wf, const float* __restrict__ bf,
                   const float* __restrict__ wb, const float* __restrict__ bb,
                   float* __restrict__ z2, short* __restrict__ z2b)
{
    long idx = (long)blockIdx.x * 256 + threadIdx.x;
    int dir = blockIdx.y;
    if (idx >= (long)kN * kDI) return;
    long n = idx >> 9; int i = (int)(idx & (kDI - 1));
    const float* zg = zg2 + (long)dir * kN * 2 * kDI;
    const float* w  = dir ? wb : wf;
    const float* b  = dir ? bb : bf;
    float acc = b[i];
    #pragma unroll
    for (int k = 0; k < 4; ++k) {
        long m = n - 3 + k;
        if (m >= 0) acc += w[k * kDI + i] * zg[m * 2 * kDI + i];
    }
    float sg = 1.f / (1.f + expf(-acc));
    float v = acc * sg;
    z2 [(long)dir * kN * kDI + idx] = v;
    z2b[(long)dir * kN * kDI + idx] = f2bf(v);
}

// delta = softplus(xp[:,32+i] + xp[:,544])  -- once per (n,i)
__global__ __launch_bounds__(256)
void delta_kernel(const float* __restrict__ xp2, float* __restrict__ delta2)
{
    long idx = (long)blockIdx.x * 256 + threadIdx.x;
    int dir = blockIdx.y;
    if (idx >= (long)kN * kDI) return;
    long n = idx >> 9; int i = (int)(idx & (kDI - 1));
    const float* xp = xp2 + (long)dir * kXPS + n * kXPW;
    float x = xp[2 * kDS + i] + xp[kXPW - 1];
    float sp = fmaxf(x, 0.f) + log1pf(expf(-fabsf(x)));
    delta2[(long)dir * kN * kDI + idx] = sp;
}

// ---- chunk-parallel scan: pass A (depth-2 register prefetch) ---------------
__global__ __launch_bounds__(256)
void scan_partA(const float* __restrict__ delta2, const float* __restrict__ z2,
                const float* __restrict__ xp2,
                const float* __restrict__ Alogf, const float* __restrict__ Alogb,
                float* __restrict__ chunkP, float* __restrict__ chunkH)
{
    int bx = blockIdx.x;
    int c  = blockIdx.y;
    int dir = bx >> 5, iblk = bx & 31;
    int t = threadIdx.x;
    int s = t & 15, il = t >> 4;
    int i = iblk * 16 + il;
    int gid = dir * 8192 + iblk * 256 + t;
    const float* Alog = dir ? Alogb : Alogf;
    float A = expf(Alog[i * kDS + s]);
    int n0 = c * kCH, n1 = n0 + kCH; if (n1 > kN) n1 = kN;
    const int cnt = n1 - n0;
    const float* dp = delta2 + (long)dir * kN * kDI + (long)n0 * kDI + i;
    const float* zp = z2     + (long)dir * kN * kDI + (long)n0 * kDI + i;
    const float* xpp = xp2   + (long)dir * kXPS     + (long)n0 * kXPW;

    float d0 = *dp, v0 = *zp, b0 = xpp[s];
    dp += kDI; zp += kDI; xpp += kXPW;
    float d1 = 0.f, v1 = 0.f, b1 = 0.f;
    if (cnt > 1) { d1 = *dp; v1 = *zp; b1 = xpp[s]; }

    float h = 0.f, P = 1.f;
    for (int k = 0; k < cnt; ++k) {
        dp += kDI; zp += kDI; xpp += kXPW;   // now at k+2
        float d2 = 0.f, v2 = 0.f, b2 = 0.f;
        if (k + 2 < cnt) { d2 = *dp; v2 = *zp; b2 = xpp[s]; }
        float dA = __expf(-d0 * A);
        h = dA * h + d0 * b0 * v0;
        P *= dA;
        d0 = d1; v0 = v1; b0 = b1;
        d1 = d2; v1 = v2; b1 = b2;
    }
    chunkP[(long)c * 16384 + gid] = P;
    chunkH[(long)c * 16384 + gid] = h;
}

// ---- pass B (hin in-place; depth-2 prefetch) --------------------------------
__global__ __launch_bounds__(256)
void scan_partB(float* __restrict__ chunkP, const float* __restrict__ chunkH)
{
    int gid = blockIdx.x * 256 + threadIdx.x;
    float P0 = chunkP[gid];
    float Q0 = chunkH[gid];
    float P1 = chunkP[16384L + gid];
    float Q1 = chunkH[16384L + gid];
    float H = 0.f;
    for (int c = 0; c < kNC; ++c) {
        float P2 = 0.f, Q2 = 0.f;
        if (c + 2 < kNC) {
            P2 = chunkP[(long)(c + 2) * 16384 + gid];
            Q2 = chunkH[(long)(c + 2) * 16384 + gid];
        }
        chunkP[(long)c * 16384 + gid] = H;   // hin for chunk c
        H = P0 * H + Q0;
        P0 = P1; Q0 = Q1;
        P1 = P2; Q1 = Q2;
    }
}

// ---- pass C (depth-2 prefetch; gate-silu fused via __expf; bf16 ygb) -------
__global__ __launch_bounds__(256)
void scan_partC(const float* __restrict__ delta2, const float* __restrict__ z2,
                const float* __restrict__ xp2, const float* __restrict__ zg2,
                const float* __restrict__ Df, const float* __restrict__ Db,
                const float* __restrict__ Alogf, const float* __restrict__ Alogb,
                const float* __restrict__ hin, short* __restrict__ ygb)
{
    int bx = blockIdx.x;
    int c  = blockIdx.y;
    int dir = bx >> 5, iblk = bx & 31;
    int t = threadIdx.x;
    int s = t & 15, il = t >> 4;
    int i = iblk * 16 + il;
    int gid = dir * 8192 + iblk * 256 + t;
    const float* D    = dir ? Db : Df;
    const float* Alog = dir ? Alogb : Alogf;
    float A  = expf(Alog[i * kDS + s]);
    float Dv = D[i];
    int n0 = c * kCH, n1 = n0 + kCH; if (n1 > kN) n1 = kN;
    const int cnt = n1 - n0;
    const float* dp  = delta2 + (long)dir * kN * kDI + (long)n0 * kDI + i;
    const float* zp  = z2     + (long)dir * kN * kDI + (long)n0 * kDI + i;
    const float* xpp = xp2    + (long)dir * kXPS     + (long)n0 * kXPW;
    const float* gp  = zg2    + (long)dir * kN * 2 * kDI + (long)n0 * 2 * kDI + kDI + i;
    short* yp        = ygb    + (long)dir * kN * kDI + (long)n0 * kDI + i;

    float d0 = *dp, v0 = *zp, b0 = xpp[s], c0 = xpp[kDS + s];
    float g0 = 0.f; if (s == 0) g0 = *gp;
    dp += kDI; zp += kDI; xpp += kXPW; gp += 2 * kDI;
    float d1 = 0.f, v1 = 0.f, b1 = 0.f, c1 = 0.f, g1 = 0.f;
    if (cnt > 1) {
        d1 = *dp; v1 = *zp; b1 = xpp[s]; c1 = xpp[kDS + s];
        if (s == 0) g1 = *gp;
    }

    float h = hin[(long)c * 16384 + gid];
    for (int k = 0; k < cnt; ++k) {
        dp += kDI; zp += kDI; xpp += kXPW; gp += 2 * kDI;   // now at k+2
        float d2 = 0.f, v2 = 0.f, b2 = 0.f, c2 = 0.f, g2 = 0.f;
        if (k + 2 < cnt) {
            d2 = *dp; v2 = *zp; b2 = xpp[s]; c2 = xpp[kDS + s];
            if (s == 0) g2 = *gp;
        }
        float dA = __expf(-d0 * A);
        h = dA * h + d0 * b0 * v0;
        float cc = h * c0;
        cc += __shfl_xor(cc, 1, 16);
        cc += __shfl_xor(cc, 2, 16);
        cc += __shfl_xor(cc, 4, 16);
        cc += __shfl_xor(cc, 8, 16);
        if (s == 0) {
            float sgm = 1.f / (1.f + __expf(-g0));
            float v = (cc + Dv * v0) * g0 * sgm;
            *yp = f2bf(v);
        }
        yp += kDI;
        d0 = d1; v0 = v1; b0 = b1; c0 = c1; g0 = g1;
        d1 = d2; v1 = v2; b1 = b2; c1 = c2; g1 = g2;
    }
}

// r = gemm_out + x; layernorm; write bf16 cat. x read from FORWARD fused buf.
__global__ __launch_bounds__(256)
void resid_ln_cat_kernel(const float* __restrict__ gt2, const float* __restrict__ fused,
                         const float* __restrict__ gf, const float* __restrict__ betf,
                         const float* __restrict__ gb, const float* __restrict__ betb,
                         short* __restrict__ catb)
{
    int n = blockIdx.x, dir = blockIdx.y, t = threadIdx.x;
    const float* gt = gt2 + ((long)dir * kN + n) * kCO;
    int xrow = dir ? (kN - 1 - n) : n;
    const float* x  = fused + (long)xrow * kCO;
    const float* g  = dir ? gb : gf;
    const float* be = dir ? betb : betf;
    float r = gt[t] + x[t];
    float s1 = r, s2 = r * r;
    #pragma unroll
    for (int m = 32; m >= 1; m >>= 1) {
        s1 += __shfl_xor(s1, m, 64);
        s2 += __shfl_xor(s2, m, 64);
    }
    __shared__ float red[8];
    int w = t >> 6;
    if ((t & 63) == 0) { red[w] = s1; red[4 + w] = s2; }
    __syncthreads();
    float S1 = red[0] + red[1] + red[2] + red[3];
    float S2 = red[4] + red[5] + red[6] + red[7];
    float mu  = S1 * (1.f / kCO);
    float var = S2 * (1.f / kCO) - mu * mu;
    float inv = rsqrtf(var + 1e-5f);
    float v = g[t] * (r - mu) * inv + be[t];
    int row = dir ? (kN - 1 - n) : n;
    catb[(long)row * (2 * kCO) + dir * kCO + t] = f2bf(v);
}

// bilinear 4x upsample -> bf16 into padded (150,150,256) buffer, border zeros
__global__ __launch_bounds__(256)
void upsample_kernel(const float* __restrict__ merged, short* __restrict__ up)
{
    int p = blockIdx.x;               // 0..22499 over 150x150
    int y = p / 150, x = p - y * 150;
    int c = threadIdx.x;
    if (y == 0 || y == 149 || x == 0 || x == 149) {
        up[((long)y * 150 + x) * kCO + c] = 0;
        return;
    }
    int oy = y - 1, ox = x - 1;
    float sy = (oy + 0.5f) * ((float)kHP / (float)kOH) - 0.5f;
    float sx = (ox + 0.5f) * ((float)kWP / (float)kOW) - 0.5f;
    int iy0 = (int)floorf(sy); float fy = sy - (float)iy0;
    int ix0 = (int)floorf(sx); float fx = sx - (float)ix0;
    float wy0 = 1.f - fy, wy1 = fy, wx0 = 1.f - fx, wx1 = fx;
    int iy1 = iy0 + 1, ix1 = ix0 + 1;
    if (iy0 < 0)       { iy0 = 0;       wy0 = 0.f; }
    if (iy1 > kHP - 1) { iy1 = kHP - 1; wy1 = 0.f; }
    if (ix0 < 0)       { ix0 = 0;       wx0 = 0.f; }
    if (ix1 > kWP - 1) { ix1 = kWP - 1; wx1 = 0.f; }
    float wys = wy0 + wy1; wy0 /= wys; wy1 /= wys;
    float wxs = wx0 + wx1; wx0 /= wxs; wx1 /= wxs;
    const float* M00 = merged + (long)(iy0 * kWP + ix0) * kCO;
    const float* M01 = merged + (long)(iy0 * kWP + ix1) * kCO;
    const float* M10 = merged + (long)(iy1 * kWP + ix0) * kCO;
    const float* M11 = merged + (long)(iy1 * kWP + ix1) * kCO;
    float v = wy0 * (wx0 * M00[c] + wx1 * M01[c]) + wy1 * (wx0 * M10[c] + wx1 * M11[c]);
    up[((long)y * 150 + x) * kCO + c] = f2bf(v);
}

extern "C" void kernel_launch(void* const* d_in, const int* in_sizes, int n_in,
                              void* d_out, int out_size, void* d_ws, size_t ws_size,
                              hipStream_t stream)
{
    (void)in_sizes; (void)n_in; (void)out_size; (void)ws_size;
    const float* features  = (const float*)d_in[0];
    const float* proj_w    = (const float*)d_in[1];
    const float* attn_w1   = (const float*)d_in[2];
    const float* attn_b1   = (const float*)d_in[3];
    const float* attn_w2   = (const float*)d_in[4];
    const float* attn_b2   = (const float*)d_in[5];
    const float* src_scale = (const float*)d_in[6];
    const float* f_in_w    = (const float*)d_in[7];
    const float* f_conv_w  = (const float*)d_in[8];
    const float* f_conv_b  = (const float*)d_in[9];
    const float* f_xp_w    = (const float*)d_in[10];
    const float* f_Alog    = (const float*)d_in[11];
    const float* f_D       = (const float*)d_in[12];
    const float* f_out_w   = (const float*)d_in[13];
    const float* f_ln_g    = (const float*)d_in[14];
    const float* f_ln_b    = (const float*)d_in[15];
    const float* b_in_w    = (const float*)d_in[16];
    const float* b_conv_w  = (const float*)d_in[17];
    const float* b_conv_b  = (const float*)d_in[18];
    const float* b_xp_w    = (const float*)d_in[19];
    const float* b_Alog    = (const float*)d_in[20];
    const float* b_D       = (const float*)d_in[21];
    const float* b_out_w   = (const float*)d_in[22];
    const float* b_ln_g    = (const float*)d_in[23];
    const float* b_ln_b    = (const float*)d_in[24];
    const float* merge_w   = (const float*)d_in[25];
    const float* co1_w     = (const float*)d_in[26];
    const float* co1_b     = (const float*)d_in[27];

    float* ws      = (float*)d_ws;
    float* outp    = (float*)d_out;
    float* pf      = ws + OFF_PF;
    float* colpart = ws + OFF_COLPART;
    float* wfin    = ws + OFF_WFIN;
    float* attnp   = ws + OFF_ATTNP;
    float* fused   = ws + OFF_FUSED2;
    float* zg2     = ws + OFF_ZG;
    float* z2      = ws + OFF_Z;
    float* xp2     = ws + OFF_XP;
    float* delta2  = ws + OFF_DELTA;
    float* gt2     = ws + OFF_GT;
    float* merged  = ws + OFF_MERGED;
    float* chunkP  = ws + OFF_SCANP;
    float* chunkH  = ws + OFF_SCANH;
    short* in_wt   = (short*)(ws + OFF_INWT);
    short* xp_wt   = (short*)(ws + OFF_XPWT);
    short* out_wt  = (short*)(ws + OFF_OUTWT);
    short* mrg_wt  = (short*)(ws + OFF_MERGEWT);
    short* fusedb2 = (short*)(ws + OFF_FUSEDB);
    short* z2b     = (short*)(ws + OFF_Z2B);
    short* ygb     = (short*)(ws + OFF_YGB);
    short* catb    = (short*)(ws + OFF_CAT);
    short* upb     = (short*)(ws + OFF_UPB);
    short* wconvb  = (short*)(ws + OFF_WCONVB);

    // 1. ALL weight transposes in one dispatch
    batched_transpose_kernel<<<dim3(2048), 256, 0, stream>>>(
        f_in_w, b_in_w, in_wt, f_xp_w, b_xp_w, xp_wt,
        merge_w, mrg_wt, f_out_w, b_out_w, out_wt, co1_w, wconvb);
    // 2. pf[s] = feats[s] @ proj_w[s]^T  (f32-direct, depth-2 prefetch)
    proj_mfma_kernel<<<dim3(528), 256, 0, stream>>>(features, proj_w, pf);
    // 3. column sums + attention weights
    colmean_kernel<<<dim3(6, 11), 256, 0, stream>>>(pf, colpart);
    attn_part1<<<dim3(12), 384, 0, stream>>>(colpart, attn_w1, attnp);
    attn_part2<<<1, 384, 0, stream>>>(attnp, attn_b1, attn_w2, attn_b2, src_scale, wfin);
    // 4. fuse sources (f32 forward + bf16 fwd+rev)
    fuse_kernel<<<dim3(1369), 256, 0, stream>>>(pf, wfin, fused, fusedb2);
    // 5. zg = fused @ in_w
    mfma_nt<<<dim3(22, 16, 2), 256, 0, stream>>>(
        fusedb2, (long)kN * kCO, in_wt, (long)2 * kDI * kCO,
        zg2, (long)kN * 2 * kDI, kN, 2 * kDI, kCO);
    // 6. causal dwconv + silu
    dwconv_kernel<<<dim3(2738, 2), 256, 0, stream>>>(zg2, f_conv_w, f_conv_b,
                                                     b_conv_w, b_conv_b, z2, z2b);
    // 7. xp = z @ xp_w
    mfma_nt<<<dim3(22, 9, 2), 256, 0, stream>>>(
        z2b, (long)kN * kDI, xp_wt, (long)kXPW * kDI,
        xp2, kXPS, kN, kXPW, kDI);
    // 8. delta
    delta_kernel<<<dim3(2738, 2), 256, 0, stream>>>(xp2, delta2);
    // 9. chunk-parallel selective scan (48 chunks, depth-2 prefetch)
    scan_partA<<<dim3(64, kNC), 256, 0, stream>>>(delta2, z2, xp2, f_Alog, b_Alog,
                                                  chunkP, chunkH);
    scan_partB<<<dim3(64), 256, 0, stream>>>(chunkP, chunkH);
    scan_partC<<<dim3(64, kNC), 256, 0, stream>>>(delta2, z2, xp2, zg2, f_D, b_D,
                                                  f_Alog, b_Alog, chunkP, ygb);
    // 10. gt = yg @ out_w
    mfma_nt<<<dim3(22, 4, 2), 256, 0, stream>>>(
        ygb, (long)kN * kDI, out_wt, (long)kCO * kDI,
        gt2, (long)kN * kCO, kN, kCO, kDI);
    // 11. residual + LN + cat
    resid_ln_cat_kernel<<<dim3(1369, 2), 256, 0, stream>>>(gt2, fused, f_ln_g, f_ln_b,
                                                           b_ln_g, b_ln_b, catb);
    // 12. merged = cat @ merge_w
    mfma_nt<<<dim3(22, 4, 1), 256, 0, stream>>>(
        catb, 0, mrg_wt, 0,
        merged, 0, kN, kCO, 2 * kCO);
    // 13. bilinear upsample (border zeros fused)
    upsample_kernel<<<dim3(150 * 150), 256, 0, stream>>>(merged, upb);
    // 14. 3x3 conv (round-17 proven: LDS dbuf, depth-2 prefetch, lgkm barriers)
    conv_mfma_kernel<<<dim3(686), 256, 0, stream>>>(upb, wconvb, co1_b, outp);
}

// Round 22
// 262.825 us; speedup vs baseline: 1.1875x; 1.0092x over previous
//
#include <hip/hip_runtime.h>
#include <math.h>

// ---------------------------------------------------------------------------
// Upnet_v3 pipeline, round 22:
//  - mfma_nt (in-proj / xp / out / merge GEMMs): depth-2 prefetch + lgkm-only
//    barriers + setprio ported (same schedule that won in conv r17, proj r21).
//  - everything else unchanged from round 21 (265.2us baseline).
// ---------------------------------------------------------------------------

namespace {
constexpr int kS   = 6;
constexpr int kHP  = 37;
constexpr int kWP  = 37;
constexpr int kN   = 1369;      // HP*WP
constexpr int kCIN = 1536;
constexpr int kCO  = 256;
constexpr int kDS  = 16;
constexpr int kDI  = 512;
constexpr int kHID = 384;
constexpr int kOH  = 148;
constexpr int kOW  = 148;
constexpr int kNP  = kOH * kOW; // 21904
constexpr int kXPW = 545;       // 2*DS + DI + 1
constexpr long kXPS = 746112;   // padded kN*kXPW per dir
constexpr int kNC  = 48;        // scan chunks
constexpr int kCH  = 29;        // chunk length (48*29 = 1392 >= 1369)

// ---- workspace ledger (f32 units, total <= 13,911,040 = 55.6 MB) ----------
constexpr long OFF_PF      = 0;
constexpr long OFF_Z2B     = 0;
constexpr long OFF_YGB     = 0;
constexpr long OFF_UPB     = 0;
constexpr long OFF_SCANP   = 700928;    // chunkP 48*16384 (hin in-place)
constexpr long OFF_SCANH   = 1487360;   // chunkH (ends 2,273,792)
constexpr long OFF_COLPART = 2102784;
constexpr long OFF_WFIN    = 2119680;
constexpr long OFF_ATTNP   = 2119696;
constexpr long OFF_INWT    = 2200000;
constexpr long OFF_FUSEDB  = 2462144;
constexpr long OFF_ZG      = 2820624;
constexpr long OFF_Z       = 5760000;
constexpr long OFF_XP      = 7161856;
constexpr long OFF_DELTA   = 8654080;   // ends 10,055,936
constexpr long OFF_OUTWT   = 10055936;  // out_wt bf16
constexpr long OFF_WCONVB  = 10500000;  // conv w^T bf16 (always-free region)
constexpr long OFF_GT      = 11457792;
constexpr long OFF_XPWT    = 11457792;
constexpr long OFF_FUSED2  = 12158720;  // f32 fused FORWARD only
constexpr long OFF_CAT     = 12859648;
constexpr long OFF_MERGEWT = 13210112;
constexpr long OFF_MERGED  = 13560576;
} // namespace

typedef __attribute__((ext_vector_type(8))) short bf16x8;
typedef __attribute__((ext_vector_type(4))) float f32x4;

__device__ __forceinline__ short f2bf(float x) {
    unsigned u = __builtin_bit_cast(unsigned, x);
    unsigned r = u + 0x7fffu + ((u >> 16) & 1u);
    return (short)(r >> 16);
}

__device__ __forceinline__ bf16x8 cvt8(float4 x, float4 y) {
    union { short s[8]; bf16x8 v; } u;
    u.s[0] = f2bf(x.x); u.s[1] = f2bf(x.y); u.s[2] = f2bf(x.z); u.s[3] = f2bf(x.w);
    u.s[4] = f2bf(y.x); u.s[5] = f2bf(y.y); u.s[6] = f2bf(y.z); u.s[7] = f2bf(y.w);
    return u.v;
}

// ---------------------------------------------------------------------------
// batched weight transpose+cast: 5 jobs in one dispatch (job table).
// ---------------------------------------------------------------------------
__global__ __launch_bounds__(256)
void batched_transpose_kernel(
    const float* __restrict__ f_in_w, const float* __restrict__ b_in_w, short* __restrict__ in_wt,
    const float* __restrict__ f_xp_w, const float* __restrict__ b_xp_w, short* __restrict__ xp_wt,
    const float* __restrict__ merge_w, short* __restrict__ mrg_wt,
    const float* __restrict__ f_out_w, const float* __restrict__ b_out_w, short* __restrict__ out_wt,
    const float* __restrict__ co1_w, short* __restrict__ wconvb)
{
    const int bid = blockIdx.x;
    const float* w; short* o; int K, N, tk, tn;
    if (bid < 512) {
        int dir = bid >> 8, r = bid & 255;
        K = 256; N = 1024;
        w = dir ? b_in_w : f_in_w; o = in_wt + (long)dir * K * N;
        tk = r >> 5; tn = r & 31;
    } else if (bid < 1088) {
        int r = bid - 512; int dir = r / 288; r -= dir * 288;
        K = 512; N = 545;
        w = dir ? b_xp_w : f_xp_w; o = xp_wt + (long)dir * K * N;
        tk = r / 18; tn = r - tk * 18;
    } else if (bid < 1216) {
        int r = bid - 1088;
        K = 512; N = 256; w = merge_w; o = mrg_wt;
        tk = r >> 3; tn = r & 7;
    } else if (bid < 1472) {
        int r = bid - 1216; int dir = r >> 7; r &= 127;
        K = 512; N = 256;
        w = dir ? b_out_w : f_out_w; o = out_wt + (long)dir * K * N;
        tk = r >> 3; tn = r & 7;
    } else {
        int r = bid - 1472;
        K = 2304; N = 256; w = co1_w; o = wconvb;
        tk = r >> 3; tn = r & 7;
    }
    const int k0 = tk * 32, n0 = tn * 32;
    __shared__ float tile[32][33];
    const int tx = threadIdx.x & 31, ty = threadIdx.x >> 5; // 32 x 8
    #pragma unroll
    for (int r = 0; r < 32; r += 8) {
        int k = k0 + ty + r, n = n0 + tx;
        tile[ty + r][tx] = (k < K && n < N) ? w[(long)k * N + n] : 0.f;
    }
    __syncthreads();
    #pragma unroll
    for (int r = 0; r < 32; r += 8) {
        int n = n0 + ty + r, k = k0 + tx;
        if (n < N && k < K) o[(long)n * K + k] = f2bf(tile[tx][ty + r]);
    }
}

// ---------------------------------------------------------------------------
// generic bf16 MFMA GEMM, NT form, LDS dbuf, K-step 64, DEPTH-2 prefetch +
// lgkm-only barriers + setprio (conv/proj-proven schedule). NT must be even.
// ---------------------------------------------------------------------------
__global__ __launch_bounds__(256)
void mfma_nt(const short* __restrict__ A, long sA,
             const short* __restrict__ B, long sB,
             float* __restrict__ C, long sC,
             int M, int N, int K)
{
    __shared__ short smem[2][8192];  // per buf bytes: A [0,8192), B [8192,16384)
    const int bz = blockIdx.z;
    const short* Ab = A + (long)bz * sA;
    const short* Bb = B + (long)bz * sB;
    float* Cb = C + (long)bz * sC;
    const int t = threadIdx.x, w = t >> 6, l = t & 63;
    const int lr = l & 15, sg = l >> 4;
    const int m0 = blockIdx.x * 64, n0 = blockIdx.y * 64;

    const int srow = t >> 3, qa = t & 7;   // 32 base rows x 8 k-segs
    long gA[2]; int woffA[2];
    #pragma unroll
    for (int j = 0; j < 2; ++j) {
        int ar = srow + j * 32;
        int am = m0 + ar; if (am >= M) am = M - 1;
        gA[j] = (long)am * K + qa * 8;
        woffA[j] = ar * 128 + ((qa ^ (ar & 7)) << 4);
    }
    long gB[2]; int woffB[2];
    #pragma unroll
    for (int j = 0; j < 2; ++j) {
        int br = srow + j * 32;
        int bn = n0 + br; if (bn >= N) bn = N - 1;
        gB[j] = (long)bn * K + qa * 8;
        woffB[j] = 8192 + br * 128 + ((qa ^ (br & 7)) << 4);
    }

    int aoff[2][2], boff[2][2];
    #pragma unroll
    for (int mi = 0; mi < 2; ++mi) {
        int r = (w >> 1) * 32 + mi * 16 + lr;
        #pragma unroll
        for (int kk = 0; kk < 2; ++kk)
            aoff[mi][kk] = r * 128 + (((kk * 4 + sg) ^ (r & 7)) << 4);
    }
    #pragma unroll
    for (int ni = 0; ni < 2; ++ni) {
        int r = (w & 1) * 32 + ni * 16 + lr;
        #pragma unroll
        for (int kk = 0; kk < 2; ++kk)
            boff[ni][kk] = 8192 + r * 128 + (((kk * 4 + sg) ^ (r & 7)) << 4);
    }

    f32x4 acc[2][2] = {};
    const int NT = K >> 6;   // even for all uses (4 or 8)

#define GN_BAR() { \
        asm volatile("s_waitcnt lgkmcnt(0)" ::: "memory"); \
        __builtin_amdgcn_sched_barrier(0); \
        __builtin_amdgcn_s_barrier(); }

#define GN_LOAD(Pa_, Pb_, tn) { \
        long _o = (long)(tn) * 64; \
        _Pragma("unroll") \
        for (int j = 0; j < 2; ++j) Pa_[j] = *(const bf16x8*)(Ab + gA[j] + _o); \
        _Pragma("unroll") \
        for (int j = 0; j < 2; ++j) Pb_[j] = *(const bf16x8*)(Bb + gB[j] + _o); }

#define GN_WRITE(buf, Pa_, Pb_) { \
        char* _nb = (char*)&smem[buf][0]; \
        _Pragma("unroll") \
        for (int j = 0; j < 2; ++j) *(bf16x8*)(_nb + woffA[j]) = Pa_[j]; \
        _Pragma("unroll") \
        for (int j = 0; j < 2; ++j) *(bf16x8*)(_nb + woffB[j]) = Pb_[j]; }

#define GN_COMPUTE(buf) { \
        char* _lb = (char*)&smem[buf][0]; \
        _Pragma("unroll") \
        for (int kk = 0; kk < 2; ++kk) { \
            bf16x8 _a[2], _b[2]; \
            _Pragma("unroll") \
            for (int mi = 0; mi < 2; ++mi) _a[mi] = *(const bf16x8*)(_lb + aoff[mi][kk]); \
            _Pragma("unroll") \
            for (int ni = 0; ni < 2; ++ni) _b[ni] = *(const bf16x8*)(_lb + boff[ni][kk]); \
            __builtin_amdgcn_s_setprio(1); \
            _Pragma("unroll") \
            for (int mi = 0; mi < 2; ++mi) \
                _Pragma("unroll") \
                for (int ni = 0; ni < 2; ++ni) \
                    acc[mi][ni] = __builtin_amdgcn_mfma_f32_16x16x32_bf16(_a[mi], _b[ni], acc[mi][ni], 0, 0, 0); \
            __builtin_amdgcn_s_setprio(0); \
        } }

    bf16x8 PaA[2], PaB[2];
    bf16x8 PbA[2], PbB[2];

    GN_LOAD(PaA, PaB, 0);
    GN_WRITE(0, PaA, PaB);
    GN_LOAD(PbA, PbB, 1);
    GN_BAR();

    for (int tt = 0; tt < NT; tt += 2) {
        if (tt + 2 < NT) GN_LOAD(PaA, PaB, tt + 2);
        GN_COMPUTE(0);
        GN_WRITE(1, PbA, PbB);
        GN_BAR();
        if (tt + 3 < NT) GN_LOAD(PbA, PbB, tt + 3);
        GN_COMPUTE(1);
        if (tt + 2 < NT) GN_WRITE(0, PaA, PaB);
        GN_BAR();
    }
#undef GN_BAR
#undef GN_LOAD
#undef GN_WRITE
#undef GN_COMPUTE

    const int q = l >> 4;
    const int wm0 = m0 + (w >> 1) * 32, wn0 = n0 + (w & 1) * 32;
    #pragma unroll
    for (int mi = 0; mi < 2; ++mi)
        #pragma unroll
        for (int ni = 0; ni < 2; ++ni)
            #pragma unroll
            for (int r = 0; r < 4; ++r) {
                int m = wm0 + mi * 16 + q * 4 + r;
                int n = wn0 + ni * 16 + lr;
                if (m < M && n < N)
                    Cb[(long)m * N + n] = acc[mi][ni][r];
            }
}

// ---------------------------------------------------------------------------
// proj MFMA: 64x64, K-step 64, XCD swizzle; f32-direct staging with DEPTH-2
// prefetch + lgkm-only barriers + setprio (round-21 proven version)
// ---------------------------------------------------------------------------
__global__ __launch_bounds__(256)
void proj_mfma_kernel(const float* __restrict__ Af, const float* __restrict__ Bf,
                      float* __restrict__ pf)
{
    __shared__ short smem[2][8192];
    const int bid = blockIdx.x;                     // 0..527
    const int slot = (bid & 7) * 66 + (bid >> 3);   // bijective, XCD-chunked
    const int s = slot / 88, rem = slot - s * 88;
    const int m0 = (rem >> 2) * 64, n0 = (rem & 3) * 64;
    const float* A = Af + (long)s * kN * kCIN;
    const float* B = Bf + (long)s * kCO * kCIN;
    float* C = pf + (long)s * kN * kCO;
    const int t = threadIdx.x, w = t >> 6, l = t & 63;
    const int lr = l & 15, sg = l >> 4;

    const int srow = t >> 3, qa = t & 7;
    long gA[2]; int woffA[2];
    #pragma unroll
    for (int j = 0; j < 2; ++j) {
        int ar = srow + j * 32;
        int am = m0 + ar; if (am >= kN) am = kN - 1;
        gA[j] = (long)am * kCIN + qa * 8;
        woffA[j] = ar * 128 + ((qa ^ (ar & 7)) << 4);
    }
    long gB[2]; int woffB[2];
    #pragma unroll
    for (int j = 0; j < 2; ++j) {
        int br = srow + j * 32;
        gB[j] = (long)(n0 + br) * kCIN + qa * 8;
        woffB[j] = 8192 + br * 128 + ((qa ^ (br & 7)) << 4);
    }

    int aoff[2][2], boff[2][2];
    #pragma unroll
    for (int mi = 0; mi < 2; ++mi) {
        int r = (w >> 1) * 32 + mi * 16 + lr;
        #pragma unroll
        for (int kk = 0; kk < 2; ++kk)
            aoff[mi][kk] = r * 128 + (((kk * 4 + sg) ^ (r & 7)) << 4);
    }
    #pragma unroll
    for (int ni = 0; ni < 2; ++ni) {
        int r = (w & 1) * 32 + ni * 16 + lr;
        #pragma unroll
        for (int kk = 0; kk < 2; ++kk)
            boff[ni][kk] = 8192 + r * 128 + (((kk * 4 + sg) ^ (r & 7)) << 4);
    }

    f32x4 acc[2][2] = {};
    const int NT = kCIN >> 6;  // 24 (even)

#define PROJ_BAR() { \
        asm volatile("s_waitcnt lgkmcnt(0)" ::: "memory"); \
        __builtin_amdgcn_sched_barrier(0); \
        __builtin_amdgcn_s_barrier(); }

#define PROJ_LOAD(Sa0_, Sa1_, Sb0_, Sb1_, tn) { \
        long _o = (long)(tn) * 64; \
        _Pragma("unroll") \
        for (int j = 0; j < 2; ++j) { \
            Sa0_[j] = *(const float4*)(A + gA[j] + _o); \
            Sa1_[j] = *(const float4*)(A + gA[j] + _o + 4); \
        } \
        _Pragma("unroll") \
        for (int j = 0; j < 2; ++j) { \
            Sb0_[j] = *(const float4*)(B + gB[j] + _o); \
            Sb1_[j] = *(const float4*)(B + gB[j] + _o + 4); \
        } }

#define PROJ_WRITE(buf, Sa0_, Sa1_, Sb0_, Sb1_) { \
        char* _nb = (char*)&smem[buf][0]; \
        _Pragma("unroll") \
        for (int j = 0; j < 2; ++j) *(bf16x8*)(_nb + woffA[j]) = cvt8(Sa0_[j], Sa1_[j]); \
        _Pragma("unroll") \
        for (int j = 0; j < 2; ++j) *(bf16x8*)(_nb + woffB[j]) = cvt8(Sb0_[j], Sb1_[j]); }

#define PROJ_COMPUTE(buf) { \
        char* _lb = (char*)&smem[buf][0]; \
        _Pragma("unroll") \
        for (int kk = 0; kk < 2; ++kk) { \
            bf16x8 _a[2], _b[2]; \
            _Pragma("unroll") \
            for (int mi = 0; mi < 2; ++mi) _a[mi] = *(const bf16x8*)(_lb + aoff[mi][kk]); \
            _Pragma("unroll") \
            for (int ni = 0; ni < 2; ++ni) _b[ni] = *(const bf16x8*)(_lb + boff[ni][kk]); \
            __builtin_amdgcn_s_setprio(1); \
            _Pragma("unroll") \
            for (int mi = 0; mi < 2; ++mi) \
                _Pragma("unroll") \
                for (int ni = 0; ni < 2; ++ni) \
                    acc[mi][ni] = __builtin_amdgcn_mfma_f32_16x16x32_bf16(_a[mi], _b[ni], acc[mi][ni], 0, 0, 0); \
            __builtin_amdgcn_s_setprio(0); \
        } }

    float4 SaA0[2], SaA1[2], SaB0[2], SaB1[2];
    float4 SbA0[2], SbA1[2], SbB0[2], SbB1[2];

    PROJ_LOAD(SaA0, SaA1, SaB0, SaB1, 0);
    PROJ_WRITE(0, SaA0, SaA1, SaB0, SaB1);
    PROJ_LOAD(SbA0, SbA1, SbB0, SbB1, 1);
    PROJ_BAR();

    for (int tt = 0; tt < NT; tt += 2) {
        if (tt + 2 < NT) PROJ_LOAD(SaA0, SaA1, SaB0, SaB1, tt + 2);
        PROJ_COMPUTE(0);
        PROJ_WRITE(1, SbA0, SbA1, SbB0, SbB1);
        PROJ_BAR();
        if (tt + 3 < NT) PROJ_LOAD(SbA0, SbA1, SbB0, SbB1, tt + 3);
        PROJ_COMPUTE(1);
        if (tt + 2 < NT) PROJ_WRITE(0, SaA0, SaA1, SaB0, SaB1);
        PROJ_BAR();
    }
#undef PROJ_BAR
#undef PROJ_LOAD
#undef PROJ_WRITE
#undef PROJ_COMPUTE

    const int q = l >> 4;
    const int wm0 = m0 + (w >> 1) * 32, wn0 = n0 + (w & 1) * 32;
    #pragma unroll
    for (int mi = 0; mi < 2; ++mi)
        #pragma unroll
        for (int ni = 0; ni < 2; ++ni)
            #pragma unroll
            for (int r = 0; r < 4; ++r) {
                int m = wm0 + mi * 16 + q * 4 + r;
                if (m < kN)
                    C[(long)m * kCO + wn0 + ni * 16 + lr] = acc[mi][ni][r];
            }
}

// ---------------------------------------------------------------------------
// conv3x3 MFMA: 64px x 128co, K-step 64, depth-2 prefetch, lgkmcnt-only
// barriers, setprio, bijective XCD-chunked swizzle (round-17 proven version)
// ---------------------------------------------------------------------------
__global__ __launch_bounds__(256)
void conv_mfma_kernel(const short* __restrict__ up, const short* __restrict__ wt,
                      const float* __restrict__ bias, float* __restrict__ out)
{
    __shared__ short smem[2][12288];   // per buf: A bytes [0,8192), B [8192,24576)
    const int t = threadIdx.x, w = t >> 6, l = t & 63;
    const int lr = l & 15, sg = l >> 4;
    // bijective XCD-chunked swizzle: nwg=686, q=85, r=6
    const int bid = blockIdx.x;
    const int xcd = bid & 7, slot = bid >> 3;
    const int wgid = (xcd < 6 ? xcd * 86 : 6 * 86 + (xcd - 6) * 85) + slot;
    const int pm0 = (wgid >> 1) * 64;
    const int bn0 = (wgid & 1) * 128;

    const int srow = t >> 3, qa = t & 7;
    long gA[2]; int woffA[2];
    #pragma unroll
    for (int j = 0; j < 2; ++j) {
        int ar = srow + j * 32;
        int p = pm0 + ar; if (p >= kNP) p = kNP - 1;
        int oy = p / kOW, ox = p - oy * kOW;
        gA[j] = ((long)oy * 150 + ox) * kCO + qa * 8;
        woffA[j] = ar * 128 + ((qa ^ (ar & 7)) << 4);
    }
    long gB[4]; int woffB[4];
    #pragma unroll
    for (int j = 0; j < 4; ++j) {
        int br = srow + j * 32;
        gB[j] = (long)(bn0 + br) * 2304 + qa * 8;
        woffB[j] = 8192 + br * 128 + ((qa ^ (br & 7)) << 4);
    }

    int aoff[2][2], boff[4][2];
    #pragma unroll
    for (int mi = 0; mi < 2; ++mi) {
        int r = (w >> 1) * 32 + mi * 16 + lr;
        #pragma unroll
        for (int kk = 0; kk < 2; ++kk)
            aoff[mi][kk] = r * 128 + (((kk * 4 + sg) ^ (r & 7)) << 4);
    }
    #pragma unroll
    for (int ni = 0; ni < 4; ++ni) {
        int r = (w & 1) * 64 + ni * 16 + lr;
        #pragma unroll
        for (int kk = 0; kk < 2; ++kk)
            boff[ni][kk] = 8192 + r * 128 + (((kk * 4 + sg) ^ (r & 7)) << 4);
    }

    f32x4 acc[2][4] = {};
    const int NT = 36;

#define CONV_BAR() { \
        asm volatile("s_waitcnt lgkmcnt(0)" ::: "memory"); \
        __builtin_amdgcn_sched_barrier(0); \
        __builtin_amdgcn_s_barrier(); }

#define CONV_TADDR(tn, ta, tb) { \
        int _tap = (tn) >> 2, _c0 = ((tn) & 3) << 6; \
        int _ky = _tap / 3, _kx = _tap - _ky * 3; \
        ta = ((long)_ky * 150 + _kx) * kCO + _c0; \
        tb = (long)(tn) * 64; }

#define CONV_LOAD(Pa_, Pb_, tn) { \
        long _ta, _tb; CONV_TADDR(tn, _ta, _tb); \
        _Pragma("unroll") \
        for (int j = 0; j < 2; ++j) Pa_[j] = *(const bf16x8*)(up + gA[j] + _ta); \
        _Pragma("unroll") \
        for (int j = 0; j < 4; ++j) Pb_[j] = *(const bf16x8*)(wt + gB[j] + _tb); }

#define CONV_WRITE(buf, Pa_, Pb_) { \
        char* _nb = (char*)&smem[buf][0]; \
        _Pragma("unroll") \
        for (int j = 0; j < 2; ++j) *(bf16x8*)(_nb + woffA[j]) = Pa_[j]; \
        _Pragma("unroll") \
        for (int j = 0; j < 4; ++j) *(bf16x8*)(_nb + woffB[j]) = Pb_[j]; }

#define CONV_COMPUTE(buf) { \
        char* _lb = (char*)&smem[buf][0]; \
        _Pragma("unroll") \
        for (int kk = 0; kk < 2; ++kk) { \
            bf16x8 _a[2], _b[4]; \
            _Pragma("unroll") \
            for (int mi = 0; mi < 2; ++mi) _a[mi] = *(const bf16x8*)(_lb + aoff[mi][kk]); \
            _Pragma("unroll") \
            for (int ni = 0; ni < 4; ++ni) _b[ni] = *(const bf16x8*)(_lb + boff[ni][kk]); \
            __builtin_amdgcn_s_setprio(1); \
            _Pragma("unroll") \
            for (int mi = 0; mi < 2; ++mi) \
                _Pragma("unroll") \
                for (int ni = 0; ni < 4; ++ni) \
                    acc[mi][ni] = __builtin_amdgcn_mfma_f32_16x16x32_bf16(_a[mi], _b[ni], acc[mi][ni], 0, 0, 0); \
            __builtin_amdgcn_s_setprio(0); \
        } }

    bf16x8 PaA[2], PaB[4];
    bf16x8 PbA[2], PbB[4];

    CONV_LOAD(PaA, PaB, 0);
    CONV_WRITE(0, PaA, PaB);
    CONV_LOAD(PbA, PbB, 1);
    CONV_BAR();

    for (int tt = 0; tt < NT; tt += 2) {
        if (tt + 2 < NT) CONV_LOAD(PaA, PaB, tt + 2);
        CONV_COMPUTE(0);
        CONV_WRITE(1, PbA, PbB);
        CONV_BAR();
        if (tt + 3 < NT) CONV_LOAD(PbA, PbB, tt + 3);
        CONV_COMPUTE(1);
        if (tt + 2 < NT) CONV_WRITE(0, PaA, PaB);
        CONV_BAR();
    }
#undef CONV_BAR
#undef CONV_TADDR
#undef CONV_LOAD
#undef CONV_WRITE
#undef CONV_COMPUTE

    const int q = l >> 4;
    const int m0 = pm0 + (w >> 1) * 32;
    const int n0 = bn0 + (w & 1) * 64;
    #pragma unroll
    for (int mi = 0; mi < 2; ++mi)
        #pragma unroll
        for (int ni = 0; ni < 4; ++ni) {
            const int co = n0 + ni * 16 + lr;
            const float bv = bias[co];
            #pragma unroll
            for (int r = 0; r < 4; ++r) {
                int p = m0 + mi * 16 + q * 4 + r;
                if (p < kNP)
                    out[(long)co * kNP + p] = acc[mi][ni][r] + bv;
            }
        }
}

// partial column sums of pf over n
__global__ __launch_bounds__(256)
void colmean_kernel(const float* __restrict__ pf, float* __restrict__ colpart)
{
    int s = blockIdx.x, ch = blockIdx.y, o = threadIdx.x;
    int n0 = ch * 128, n1 = n0 + 128 > kN ? kN : n0 + 128;
    float a = 0.f;
    for (int n = n0; n < n1; ++n) a += pf[((long)s * kN + n) * kCO + o];
    colpart[ch * kS * kCO + s * kCO + o] = a;
}

// attn stage 1
__global__ __launch_bounds__(384)
void attn_part1(const float* __restrict__ colpart, const float* __restrict__ w1,
                float* __restrict__ partial)
{
    __shared__ float cm[128];
    int b = blockIdx.x, t = threadIdx.x;
    int c0 = b * 128;
    if (t < 128) {
        float a = 0.f;
        #pragma unroll
        for (int ch = 0; ch < 11; ++ch) a += colpart[ch * kS * kCO + c0 + t];
        cm[t] = a * (1.f / kN);
    }
    __syncthreads();
    float acc = 0.f;
    #pragma unroll 4
    for (int c = 0; c < 128; ++c) acc += cm[c] * w1[(long)(c0 + c) * kHID + t];
    partial[b * kHID + t] = acc;
}

// attn stage 2
__global__ __launch_bounds__(384)
void attn_part2(const float* __restrict__ partial, const float* __restrict__ b1,
                const float* __restrict__ w2, const float* __restrict__ b2,
                const float* __restrict__ ss, float* __restrict__ wfin)
{
    __shared__ float h[kHID];
    __shared__ float logits[8];
    int t = threadIdx.x;
    float acc = b1[t];
    #pragma unroll
    for (int b = 0; b < 12; ++b) acc += partial[b * kHID + t];
    h[t] = fmaxf(acc, 0.f);
    __syncthreads();
    if (t < kS) {
        float lg = b2[t];
        for (int j = 0; j < kHID; ++j) lg += h[j] * w2[j * kS + t];
        logits[t] = lg;
    }
    __syncthreads();
    if (t == 0) {
        float w[kS], mx = -1e30f, sum = 0.f;
        for (int s = 0; s < kS; ++s) mx = fmaxf(mx, logits[s]);
        for (int s = 0; s < kS; ++s) { w[s] = expf(logits[s] - mx); sum += w[s]; }
        for (int s = 0; s < kS; ++s) w[s] /= sum;
        mx = -1e30f;
        for (int s = 0; s < kS; ++s) { w[s] *= ss[s]; mx = fmaxf(mx, w[s]); }
        sum = 0.f;
        float e[kS];
        for (int s = 0; s < kS; ++s) { e[s] = expf(w[s] - mx); sum += e[s]; }
        for (int s = 0; s < kS; ++s) wfin[s] = e[s] / sum;
    }
}

// fused = sum_s wfin[s]*pf[s]; writes f32 FORWARD only + bf16 fwd+rev
__global__ __launch_bounds__(256)
void fuse_kernel(const float* __restrict__ pf, const float* __restrict__ wfin,
                 float* __restrict__ fused, short* __restrict__ fusedb2)
{
    long idx = (long)blockIdx.x * 256 + threadIdx.x;
    if (idx >= (long)kN * kCO) return;
    float acc = 0.f;
    #pragma unroll
    for (int s = 0; s < kS; ++s) acc += wfin[s] * pf[(long)s * kN * kCO + idx];
    long n = idx / kCO; int c = (int)(idx % kCO);
    long ridx = (long)kN * kCO + (kN - 1 - n) * kCO + c;
    short bv = f2bf(acc);
    fused[idx] = acc;
    fusedb2[idx] = bv;
    fusedb2[ridx] = bv;
}

// causal depthwise conv (K=4) + silu; writes f32 z2 and bf16 z2b
__global__ __launch_bounds__(256)
void dwconv_kernel(const float* __restrict__ zg2,
                   const float* __restrict__ wf, const float* __restrict__ bf,
                   const float* __restrict__ wb, const float* __restrict__ bb,
                   float* __restrict__ z2, short* __restrict__ z2b)
{
    long idx = (long)blockIdx.x * 256 + threadIdx.x;
    int dir = blockIdx.y;
    if (idx >= (long)kN * kDI) return;
    long n = idx >> 9; int i = (int)(idx & (kDI - 1));
    const float* zg = zg2 + (long)dir * kN * 2 * kDI;
    const float* w  = dir ? wb : wf;
    const float* b  = dir ? bb : bf;
    float acc = b[i];
    #pragma unroll
    for (int k = 0; k < 4; ++k) {
        long m = n - 3 + k;
        if (m >= 0) acc += w[k * kDI + i] * zg[m * 2 * kDI + i];
    }
    float sg = 1.f / (1.f + expf(-acc));
    float v = acc * sg;
    z2 [(long)dir * kN * kDI + idx] = v;
    z2b[(long)dir * kN * kDI + idx] = f2bf(v);
}

// delta = softplus(xp[:,32+i] + xp[:,544])  -- once per (n,i)
__global__ __launch_bounds__(256)
void delta_kernel(const float* __restrict__ xp2, float* __restrict__ delta2)
{
    long idx = (long)blockIdx.x * 256 + threadIdx.x;
    int dir = blockIdx.y;
    if (idx >= (long)kN * kDI) return;
    long n = idx >> 9; int i = (int)(idx & (kDI - 1));
    const float* xp = xp2 + (long)dir * kXPS + n * kXPW;
    float x = xp[2 * kDS + i] + xp[kXPW - 1];
    float sp = fmaxf(x, 0.f) + log1pf(expf(-fabsf(x)));
    delta2[(long)dir * kN * kDI + idx] = sp;
}

// ---- chunk-parallel scan: pass A (depth-2 register prefetch) ---------------
__global__ __launch_bounds__(256)
void scan_partA(const float* __restrict__ delta2, const float* __restrict__ z2,
                const float* __restrict__ xp2,
                const float* __restrict__ Alogf, const float* __restrict__ Alogb,
                float* __restrict__ chunkP, float* __restrict__ chunkH)
{
    int bx = blockIdx.x;
    int c  = blockIdx.y;
    int dir = bx >> 5, iblk = bx & 31;
    int t = threadIdx.x;
    int s = t & 15, il = t >> 4;
    int i = iblk * 16 + il;
    int gid = dir * 8192 + iblk * 256 + t;
    const float* Alog = dir ? Alogb : Alogf;
    float A = expf(Alog[i * kDS + s]);
    int n0 = c * kCH, n1 = n0 + kCH; if (n1 > kN) n1 = kN;
    const int cnt = n1 - n0;
    const float* dp = delta2 + (long)dir * kN * kDI + (long)n0 * kDI + i;
    const float* zp = z2     + (long)dir * kN * kDI + (long)n0 * kDI + i;
    const float* xpp = xp2   + (long)dir * kXPS     + (long)n0 * kXPW;

    float d0 = *dp, v0 = *zp, b0 = xpp[s];
    dp += kDI; zp += kDI; xpp += kXPW;
    float d1 = 0.f, v1 = 0.f, b1 = 0.f;
    if (cnt > 1) { d1 = *dp; v1 = *zp; b1 = xpp[s]; }

    float h = 0.f, P = 1.f;
    for (int k = 0; k < cnt; ++k) {
        dp += kDI; zp += kDI; xpp += kXPW;   // now at k+2
        float d2 = 0.f, v2 = 0.f, b2 = 0.f;
        if (k + 2 < cnt) { d2 = *dp; v2 = *zp; b2 = xpp[s]; }
        float dA = __expf(-d0 * A);
        h = dA * h + d0 * b0 * v0;
        P *= dA;
        d0 = d1; v0 = v1; b0 = b1;
        d1 = d2; v1 = v2; b1 = b2;
    }
    chunkP[(long)c * 16384 + gid] = P;
    chunkH[(long)c * 16384 + gid] = h;
}

// ---- pass B (hin in-place; depth-2 prefetch) --------------------------------
__global__ __launch_bounds__(256)
void scan_partB(float* __restrict__ chunkP, const float* __restrict__ chunkH)
{
    int gid = blockIdx.x * 256 + threadIdx.x;
    float P0 = chunkP[gid];
    float Q0 = chunkH[gid];
    float P1 = chunkP[16384L + gid];
    float Q1 = chunkH[16384L + gid];
    float H = 0.f;
    for (int c = 0; c < kNC; ++c) {
        float P2 = 0.f, Q2 = 0.f;
        if (c + 2 < kNC) {
            P2 = chunkP[(long)(c + 2) * 16384 + gid];
            Q2 = chunkH[(long)(c + 2) * 16384 + gid];
        }
        chunkP[(long)c * 16384 + gid] = H;   // hin for chunk c
        H = P0 * H + Q0;
        P0 = P1; Q0 = Q1;
        P1 = P2; Q1 = Q2;
    }
}

// ---- pass C (depth-2 prefetch; gate-silu fused via __expf; bf16 ygb) -------
__global__ __launch_bounds__(256)
void scan_partC(const float* __restrict__ delta2, const float* __restrict__ z2,
                const float* __restrict__ xp2, const float* __restrict__ zg2,
                const float* __restrict__ Df, const float* __restrict__ Db,
                const float* __restrict__ Alogf, const float* __restrict__ Alogb,
                const float* __restrict__ hin, short* __restrict__ ygb)
{
    int bx = blockIdx.x;
    int c  = blockIdx.y;
    int dir = bx >> 5, iblk = bx & 31;
    int t = threadIdx.x;
    int s = t & 15, il = t >> 4;
    int i = iblk * 16 + il;
    int gid = dir * 8192 + iblk * 256 + t;
    const float* D    = dir ? Db : Df;
    const float* Alog = dir ? Alogb : Alogf;
    float A  = expf(Alog[i * kDS + s]);
    float Dv = D[i];
    int n0 = c * kCH, n1 = n0 + kCH; if (n1 > kN) n1 = kN;
    const int cnt = n1 - n0;
    const float* dp  = delta2 + (long)dir * kN * kDI + (long)n0 * kDI + i;
    const float* zp  = z2     + (long)dir * kN * kDI + (long)n0 * kDI + i;
    const float* xpp = xp2    + (long)dir * kXPS     + (long)n0 * kXPW;
    const float* gp  = zg2    + (long)dir * kN * 2 * kDI + (long)n0 * 2 * kDI + kDI + i;
    short* yp        = ygb    + (long)dir * kN * kDI + (long)n0 * kDI + i;

    float d0 = *dp, v0 = *zp, b0 = xpp[s], c0 = xpp[kDS + s];
    float g0 = 0.f; if (s == 0) g0 = *gp;
    dp += kDI; zp += kDI; xpp += kXPW; gp += 2 * kDI;
    float d1 = 0.f, v1 = 0.f, b1 = 0.f, c1 = 0.f, g1 = 0.f;
    if (cnt > 1) {
        d1 = *dp; v1 = *zp; b1 = xpp[s]; c1 = xpp[kDS + s];
        if (s == 0) g1 = *gp;
    }

    float h = hin[(long)c * 16384 + gid];
    for (int k = 0; k < cnt; ++k) {
        dp += kDI; zp += kDI; xpp += kXPW; gp += 2 * kDI;   // now at k+2
        float d2 = 0.f, v2 = 0.f, b2 = 0.f, c2 = 0.f, g2 = 0.f;
        if (k + 2 < cnt) {
            d2 = *dp; v2 = *zp; b2 = xpp[s]; c2 = xpp[kDS + s];
            if (s == 0) g2 = *gp;
        }
        float dA = __expf(-d0 * A);
        h = dA * h + d0 * b0 * v0;
        float cc = h * c0;
        cc += __shfl_xor(cc, 1, 16);
        cc += __shfl_xor(cc, 2, 16);
        cc += __shfl_xor(cc, 4, 16);
        cc += __shfl_xor(cc, 8, 16);
        if (s == 0) {
            float sgm = 1.f / (1.f + __expf(-g0));
            float v = (cc + Dv * v0) * g0 * sgm;
            *yp = f2bf(v);
        }
        yp += kDI;
        d0 = d1; v0 = v1; b0 = b1; c0 = c1; g0 = g1;
        d1 = d2; v1 = v2; b1 = b2; c1 = c2; g1 = g2;
    }
}

// r = gemm_out + x; layernorm; write bf16 cat. x read from FORWARD fused buf.
__global__ __launch_bounds__(256)
void resid_ln_cat_kernel(const float* __restrict__ gt2, const float* __restrict__ fused,
                         const float* __restrict__ gf, const float* __restrict__ betf,
                         const float* __restrict__ gb, const float* __restrict__ betb,
                         short* __restrict__ catb)
{
    int n = blockIdx.x, dir = blockIdx.y, t = threadIdx.x;
    const float* gt = gt2 + ((long)dir * kN + n) * kCO;
    int xrow = dir ? (kN - 1 - n) : n;
    const float* x  = fused + (long)xrow * kCO;
    const float* g  = dir ? gb : gf;
    const float* be = dir ? betb : betf;
    float r = gt[t] + x[t];
    float s1 = r, s2 = r * r;
    #pragma unroll
    for (int m = 32; m >= 1; m >>= 1) {
        s1 += __shfl_xor(s1, m, 64);
        s2 += __shfl_xor(s2, m, 64);
    }
    __shared__ float red[8];
    int w = t >> 6;
    if ((t & 63) == 0) { red[w] = s1; red[4 + w] = s2; }
    __syncthreads();
    float S1 = red[0] + red[1] + red[2] + red[3];
    float S2 = red[4] + red[5] + red[6] + red[7];
    float mu  = S1 * (1.f / kCO);
    float var = S2 * (1.f / kCO) - mu * mu;
    float inv = rsqrtf(var + 1e-5f);
    float v = g[t] * (r - mu) * inv + be[t];
    int row = dir ? (kN - 1 - n) : n;
    catb[(long)row * (2 * kCO) + dir * kCO + t] = f2bf(v);
}

// bilinear 4x upsample -> bf16 into padded (150,150,256) buffer, border zeros
__global__ __launch_bounds__(256)
void upsample_kernel(const float* __restrict__ merged, short* __restrict__ up)
{
    int p = blockIdx.x;               // 0..22499 over 150x150
    int y = p / 150, x = p - y * 150;
    int c = threadIdx.x;
    if (y == 0 || y == 149 || x == 0 || x == 149) {
        up[((long)y * 150 + x) * kCO + c] = 0;
        return;
    }
    int oy = y - 1, ox = x - 1;
    float sy = (oy + 0.5f) * ((float)kHP / (float)kOH) - 0.5f;
    float sx = (ox + 0.5f) * ((float)kWP / (float)kOW) - 0.5f;
    int iy0 = (int)floorf(sy); float fy = sy - (float)iy0;
    int ix0 = (int)floorf(sx); float fx = sx - (float)ix0;
    float wy0 = 1.f - fy, wy1 = fy, wx0 = 1.f - fx, wx1 = fx;
    int iy1 = iy0 + 1, ix1 = ix0 + 1;
    if (iy0 < 0)       { iy0 = 0;       wy0 = 0.f; }
    if (iy1 > kHP - 1) { iy1 = kHP - 1; wy1 = 0.f; }
    if (ix0 < 0)       { ix0 = 0;       wx0 = 0.f; }
    if (ix1 > kWP - 1) { ix1 = kWP - 1; wx1 = 0.f; }
    float wys = wy0 + wy1; wy0 /= wys; wy1 /= wys;
    float wxs = wx0 + wx1; wx0 /= wxs; wx1 /= wxs;
    const float* M00 = merged + (long)(iy0 * kWP + ix0) * kCO;
    const float* M01 = merged + (long)(iy0 * kWP + ix1) * kCO;
    const float* M10 = merged + (long)(iy1 * kWP + ix0) * kCO;
    const float* M11 = merged + (long)(iy1 * kWP + ix1) * kCO;
    float v = wy0 * (wx0 * M00[c] + wx1 * M01[c]) + wy1 * (wx0 * M10[c] + wx1 * M11[c]);
    up[((long)y * 150 + x) * kCO + c] = f2bf(v);
}

extern "C" void kernel_launch(void* const* d_in, const int* in_sizes, int n_in,
                              void* d_out, int out_size, void* d_ws, size_t ws_size,
                              hipStream_t stream)
{
    (void)in_sizes; (void)n_in; (void)out_size; (void)ws_size;
    const float* features  = (const float*)d_in[0];
    const float* proj_w    = (const float*)d_in[1];
    const float* attn_w1   = (const float*)d_in[2];
    const float* attn_b1   = (const float*)d_in[3];
    const float* attn_w2   = (const float*)d_in[4];
    const float* attn_b2   = (const float*)d_in[5];
    const float* src_scale = (const float*)d_in[6];
    const float* f_in_w    = (const float*)d_in[7];
    const float* f_conv_w  = (const float*)d_in[8];
    const float* f_conv_b  = (const float*)d_in[9];
    const float* f_xp_w    = (const float*)d_in[10];
    const float* f_Alog    = (const float*)d_in[11];
    const float* f_D       = (const float*)d_in[12];
    const float* f_out_w   = (const float*)d_in[13];
    const float* f_ln_g    = (const float*)d_in[14];
    const float* f_ln_b    = (const float*)d_in[15];
    const float* b_in_w    = (const float*)d_in[16];
    const float* b_conv_w  = (const float*)d_in[17];
    const float* b_conv_b  = (const float*)d_in[18];
    const float* b_xp_w    = (const float*)d_in[19];
    const float* b_Alog    = (const float*)d_in[20];
    const float* b_D       = (const float*)d_in[21];
    const float* b_out_w   = (const float*)d_in[22];
    const float* b_ln_g    = (const float*)d_in[23];
    const float* b_ln_b    = (const float*)d_in[24];
    const float* merge_w   = (const float*)d_in[25];
    const float* co1_w     = (const float*)d_in[26];
    const float* co1_b     = (const float*)d_in[27];

    float* ws      = (float*)d_ws;
    float* outp    = (float*)d_out;
    float* pf      = ws + OFF_PF;
    float* colpart = ws + OFF_COLPART;
    float* wfin    = ws + OFF_WFIN;
    float* attnp   = ws + OFF_ATTNP;
    float* fused   = ws + OFF_FUSED2;
    float* zg2     = ws + OFF_ZG;
    float* z2      = ws + OFF_Z;
    float* xp2     = ws + OFF_XP;
    float* delta2  = ws + OFF_DELTA;
    float* gt2     = ws + OFF_GT;
    float* merged  = ws + OFF_MERGED;
    float* chunkP  = ws + OFF_SCANP;
    float* chunkH  = ws + OFF_SCANH;
    short* in_wt   = (short*)(ws + OFF_INWT);
    short* xp_wt   = (short*)(ws + OFF_XPWT);
    short* out_wt  = (short*)(ws + OFF_OUTWT);
    short* mrg_wt  = (short*)(ws + OFF_MERGEWT);
    short* fusedb2 = (short*)(ws + OFF_FUSEDB);
    short* z2b     = (short*)(ws + OFF_Z2B);
    short* ygb     = (short*)(ws + OFF_YGB);
    short* catb    = (short*)(ws + OFF_CAT);
    short* upb     = (short*)(ws + OFF_UPB);
    short* wconvb  = (short*)(ws + OFF_WCONVB);

    // 1. ALL weight transposes in one dispatch
    batched_transpose_kernel<<<dim3(2048), 256, 0, stream>>>(
        f_in_w, b_in_w, in_wt, f_xp_w, b_xp_w, xp_wt,
        merge_w, mrg_wt, f_out_w, b_out_w, out_wt, co1_w, wconvb);
    // 2. pf[s] = feats[s] @ proj_w[s]^T  (f32-direct, depth-2 prefetch)
    proj_mfma_kernel<<<dim3(528), 256, 0, stream>>>(features, proj_w, pf);
    // 3. column sums + attention weights
    colmean_kernel<<<dim3(6, 11), 256, 0, stream>>>(pf, colpart);
    attn_part1<<<dim3(12), 384, 0, stream>>>(colpart, attn_w1, attnp);
    attn_part2<<<1, 384, 0, stream>>>(attnp, attn_b1, attn_w2, attn_b2, src_scale, wfin);
    // 4. fuse sources (f32 forward + bf16 fwd+rev)
    fuse_kernel<<<dim3(1369), 256, 0, stream>>>(pf, wfin, fused, fusedb2);
    // 5. zg = fused @ in_w  (depth-2 schedule)
    mfma_nt<<<dim3(22, 16, 2), 256, 0, stream>>>(
        fusedb2, (long)kN * kCO, in_wt, (long)2 * kDI * kCO,
        zg2, (long)kN * 2 * kDI, kN, 2 * kDI, kCO);
    // 6. causal dwconv + silu
    dwconv_kernel<<<dim3(2738, 2), 256, 0, stream>>>(zg2, f_conv_w, f_conv_b,
                                                     b_conv_w, b_conv_b, z2, z2b);
    // 7. xp = z @ xp_w  (depth-2 schedule)
    mfma_nt<<<dim3(22, 9, 2), 256, 0, stream>>>(
        z2b, (long)kN * kDI, xp_wt, (long)kXPW * kDI,
        xp2, kXPS, kN, kXPW, kDI);
    // 8. delta
    delta_kernel<<<dim3(2738, 2), 256, 0, stream>>>(xp2, delta2);
    // 9. chunk-parallel selective scan (48 chunks, depth-2 prefetch)
    scan_partA<<<dim3(64, kNC), 256, 0, stream>>>(delta2, z2, xp2, f_Alog, b_Alog,
                                                  chunkP, chunkH);
    scan_partB<<<dim3(64), 256, 0, stream>>>(chunkP, chunkH);
    scan_partC<<<dim3(64, kNC), 256, 0, stream>>>(delta2, z2, xp2, zg2, f_D, b_D,
                                                  f_Alog, b_Alog, chunkP, ygb);
    // 10. gt = yg @ out_w  (depth-2 schedule)
    mfma_nt<<<dim3(22, 4, 2), 256, 0, stream>>>(
        ygb, (long)kN * kDI, out_wt, (long)kCO * kDI,
        gt2, (long)kN * kCO, kN, kCO, kDI);
    // 11. residual + LN + cat
    resid_ln_cat_kernel<<<dim3(1369, 2), 256, 0, stream>>>(gt2, fused, f_ln_g, f_ln_b,
                                                           b_ln_g, b_ln_b, catb);
    // 12. merged = cat @ merge_w  (depth-2 schedule)
    mfma_nt<<<dim3(22, 4, 1), 256, 0, stream>>>(
        catb, 0, mrg_wt, 0,
        merged, 0, kN, kCO, 2 * kCO);
    // 13. bilinear upsample (border zeros fused)
    upsample_kernel<<<dim3(150 * 150), 256, 0, stream>>>(merged, upb);
    // 14. 3x3 conv (round-17 proven: LDS dbuf, depth-2 prefetch, lgkm barriers)
    conv_mfma_kernel<<<dim3(686), 256, 0, stream>>>(upb, wconvb, co1_b, outp);
}